// Round 1
// baseline (884.093 us; speedup 1.0000x reference)
//
#include <hip/hip_runtime.h>
#include <math.h>

#define T_LEN  128
#define B_SZ   32
#define DMODEL 1024
#define H_N    8
#define DH_N   64
#define ETA_N  4
#define FD_N   256
#define R_N    4
#define PROJ_N 2656
#define EPS_F  1e-6f

__device__ __forceinline__ float sigmoidf_(float x) { return 1.0f / (1.0f + __expf(-x)); }

// C[M,N] = A[M,K] @ B[N,K]^T + bias[N]   (both row-major, K contiguous: "NT" dot-product GEMM)
// 64x64 tile, 256 threads, 4x4 register micro-tile, BK=16, padded LDS (17) to dodge bank conflicts.
// Requires M % 64 == 0 and K % 16 == 0; N is bounds-checked.
__global__ __launch_bounds__(256) void gemm_nt_bias(
    const float* __restrict__ A, const float* __restrict__ Bm,
    const float* __restrict__ bias, float* __restrict__ C,
    int M, int N, int K)
{
    __shared__ float As[64][17];
    __shared__ float Bs[64][17];
    const int tid  = threadIdx.x;
    const int row0 = blockIdx.y * 64;
    const int col0 = blockIdx.x * 64;
    const int lrow = tid >> 2;          // 0..63
    const int lk   = (tid & 3) << 2;    // 0,4,8,12
    const int tx   = tid & 15;
    const int ty   = tid >> 4;

    float acc[4][4] = {};

    const int arow = row0 + lrow;                 // always < M
    const int brow = col0 + lrow;
    const float* aptr = A + (size_t)arow * K + lk;
    const float* bptr = (brow < N) ? (Bm + (size_t)brow * K + lk) : nullptr;

    for (int k0 = 0; k0 < K; k0 += 16) {
        float4 av = *(const float4*)(aptr + k0);
        float4 bv = make_float4(0.f, 0.f, 0.f, 0.f);
        if (bptr) bv = *(const float4*)(bptr + k0);
        As[lrow][lk+0] = av.x; As[lrow][lk+1] = av.y;
        As[lrow][lk+2] = av.z; As[lrow][lk+3] = av.w;
        Bs[lrow][lk+0] = bv.x; Bs[lrow][lk+1] = bv.y;
        Bs[lrow][lk+2] = bv.z; Bs[lrow][lk+3] = bv.w;
        __syncthreads();
        #pragma unroll
        for (int kk = 0; kk < 16; ++kk) {
            float a[4], b[4];
            #pragma unroll
            for (int i = 0; i < 4; ++i) a[i] = As[ty*4+i][kk];
            #pragma unroll
            for (int j = 0; j < 4; ++j) b[j] = Bs[tx*4+j][kk];
            #pragma unroll
            for (int i = 0; i < 4; ++i)
                #pragma unroll
                for (int j = 0; j < 4; ++j)
                    acc[i][j] += a[i] * b[j];
        }
        __syncthreads();
    }

    #pragma unroll
    for (int i = 0; i < 4; ++i) {
        const int r = row0 + ty*4 + i;
        #pragma unroll
        for (int j = 0; j < 4; ++j) {
            const int c = col0 + tx*4 + j;
            if (c < N) C[(size_t)r * N + c] = acc[i][j] + bias[c];
        }
    }
}

// One block per batch element b; 1024 threads.
// Thread tid owns features fi = 2*tid, 2*tid+1 of the 2048 (h,f) key-features:
//   h = tid>>7, f0 = (2*tid)&255 (even), d = f0>>2, e0 = f0&3 in {0,2}, e1 = e0+1.
// Threads < 512 additionally own one (h,d) value lane: hv = tid>>6, dv = tid&63.
// State in registers across the T=128 sequential steps; 5 block-wide dot products
// per step via wave shuffle + LDS combine; register prefetch of next t's proj row.
__global__ __launch_bounds__(1024)
void agalite_scan(const float* __restrict__ proj,    // (T*B, PROJ)
                  const int*   __restrict__ term,    // (T, B)
                  const float* __restrict__ tick_in, // (B)
                  const float* __restrict__ fk_prev, // (B,R,H,FD)
                  const float* __restrict__ fv_prev, // (B,R,H,DH)
                  const float* __restrict__ fs_prev, // (B,H,FD)
                  float* __restrict__ attn,          // (T*B, H*DH)
                  float* __restrict__ out_fk,
                  float* __restrict__ out_fv,
                  float* __restrict__ out_fs,
                  float* __restrict__ out_tick)
{
    const int b   = blockIdx.x;
    const int tid = threadIdx.x;

    __shared__ float proj_s[2][PROJ_N];
    __shared__ float red_sc[16][4];
    __shared__ float red_nrm[16];
    __shared__ float scores_s[4];
    __shared__ float norm_s[8];

    const int h  = tid >> 7;
    const int f0 = (tid << 1) & 255;  // even
    const int d  = f0 >> 2;
    const int e0 = f0 & 3;            // 0 or 2
    const int e1 = e0 + 1;
    const int f1 = f0 + 1;

    const int hv = tid >> 6;          // valid for tid < 512
    const int dv = tid & 63;

    float fk[R_N][2];
    float fsv[2];
    #pragma unroll
    for (int r = 0; r < R_N; ++r) {
        const float* p = fk_prev + (((size_t)b * R_N + r) * H_N + h) * FD_N;
        fk[r][0] = p[f0]; fk[r][1] = p[f1];
    }
    {
        const float* p = fs_prev + ((size_t)b * H_N + h) * FD_N;
        fsv[0] = p[f0]; fsv[1] = p[f1];
    }
    float fv[R_N] = {0.f, 0.f, 0.f, 0.f};
    if (tid < 512) {
        #pragma unroll
        for (int r = 0; r < R_N; ++r)
            fv[r] = fv_prev[(((size_t)b * R_N + r) * H_N + hv) * DH_N + dv];
    }

    const float tick_b = tick_in[b];
    const float PI_F = 3.14159265358979323846f;
    const float omega[4] = {-PI_F, -PI_F/3.0f, PI_F/3.0f, PI_F};

    for (int i = tid; i < PROJ_N; i += 1024)
        proj_s[0][i] = proj[(size_t)b * PROJ_N + i];
    __syncthreads();

    for (int t = 0; t < T_LEN; ++t) {
        const int cur = t & 1, nxt = cur ^ 1;

        // prefetch next t's projection row into registers (hidden under compute)
        float pf0 = 0.f, pf1 = 0.f, pf2 = 0.f;
        if (t + 1 < T_LEN) {
            const float* src = proj + ((size_t)(t + 1) * B_SZ + b) * PROJ_N;
            pf0 = src[tid];
            pf1 = src[tid + 1024];
            if (tid + 2048 < PROJ_N) pf2 = src[tid + 2048];
        }

        const float* P = proj_s[cur];
        const float mask = 1.0f - (float)term[t * B_SZ + b];
        const float tt = (float)(t + 1) + tick_b;
        float cosr[4];
        #pragma unroll
        for (int r = 0; r < R_N; ++r) cosr[r] = cosf(tt * omega[r]);

        // kqv layout inside a row: h*320 + c*64 + d (c: 0=k,1=q,2=v,3=beta,4=gamma);
        // p123: 2560 + h*12 + c*4 + e (c: 0=p1,1=p2,2=p3)
        const int base = h * 320;
        const float kkv = P[base + d];
        const float qqv = P[base + 64 + d];
        const float ggv = P[base + 256 + d];
        const int pb = 2560 + h * 12;
        const float p1a = P[pb + e0],     p1b = P[pb + e1];
        const float p2a = P[pb + 4 + e0], p2b = P[pb + 4 + e1];
        const float p3a = P[pb + 8 + e0], p3b = P[pb + 8 + e1];

        const float rk = fmaxf(kkv, 0.f);
        const float rq = fmaxf(qqv, 0.f);
        const float sg = sigmoidf_(ggv);
        const float psi0 = rk * fmaxf(p1a, 0.f), psi1 = rk * fmaxf(p1b, 0.f);
        const float phi0 = rq * fmaxf(p2a, 0.f), phi1 = rq * fmaxf(p2b, 0.f);
        const float gf0 = sg * sigmoidf_(p3a),   gf1 = sg * sigmoidf_(p3b);
        const float kg0 = psi0 * gf0, kg1 = psi1 * gf1;
        const float dg0 = (1.f - gf0) * mask, dg1 = (1.f - gf1) * mask;

        fsv[0] = dg0 * fsv[0] + kg0;
        fsv[1] = dg1 * fsv[1] + kg1;
        float nrm_p = fsv[0] * phi0 + fsv[1] * phi1;
        float sc_p[4];
        #pragma unroll
        for (int r = 0; r < R_N; ++r) {
            fk[r][0] = dg0 * fk[r][0] + kg0 * cosr[r];
            fk[r][1] = dg1 * fk[r][1] + kg1 * cosr[r];
            sc_p[r] = fk[r][0] * phi0 + fk[r][1] * phi1;
        }

        if (tid < 512) {
            const int vb = hv * 320;
            const float vvv = P[vb + 128 + dv];
            const float bbv = sigmoidf_(P[vb + 192 + dv]);
            const float vg = vvv * bbv;
            const float db = (1.f - bbv) * mask;
            #pragma unroll
            for (int r = 0; r < R_N; ++r) fv[r] = db * fv[r] + vg * cosr[r];
        }

        // wave(64)-wide reductions of the 5 partials
        #pragma unroll
        for (int off = 32; off >= 1; off >>= 1) {
            #pragma unroll
            for (int r = 0; r < R_N; ++r) sc_p[r] += __shfl_xor(sc_p[r], off);
            nrm_p += __shfl_xor(nrm_p, off);
        }
        const int wave = tid >> 6;
        if ((tid & 63) == 0) {
            #pragma unroll
            for (int r = 0; r < R_N; ++r) red_sc[wave][r] = sc_p[r];
            red_nrm[wave] = nrm_p;
        }
        __syncthreads();                                  // [A]
        if (tid < 4) {
            float s = 0.f;
            #pragma unroll
            for (int w = 0; w < 16; ++w) s += red_sc[w][tid];
            scores_s[tid] = s;
        } else if (tid >= 8 && tid < 16) {
            const int hh = tid - 8;
            // wave w covers h = w>>1  ->  norm[h] = partials of waves 2h, 2h+1
            norm_s[hh] = red_nrm[2*hh] + red_nrm[2*hh+1];
        }
        __syncthreads();                                  // [B]

        if (tid < 512) {
            const float kv = fv[0]*scores_s[0] + fv[1]*scores_s[1]
                           + fv[2]*scores_s[2] + fv[3]*scores_s[3];
            attn[((size_t)t * B_SZ + b) * (H_N * DH_N) + tid] =
                kv / (2.0f * R_N * norm_s[hv] + EPS_F);
        }

        if (t + 1 < T_LEN) {
            proj_s[nxt][tid]        = pf0;
            proj_s[nxt][tid + 1024] = pf1;
            if (tid + 2048 < PROJ_N) proj_s[nxt][tid + 2048] = pf2;
        }
        __syncthreads();                                  // [C]
    }

    // final states (t = T-1, post-update)
    #pragma unroll
    for (int r = 0; r < R_N; ++r) {
        float* p = out_fk + (((size_t)b * R_N + r) * H_N + h) * FD_N;
        p[f0] = fk[r][0]; p[f1] = fk[r][1];
    }
    {
        float* p = out_fs + ((size_t)b * H_N + h) * FD_N;
        p[f0] = fsv[0]; p[f1] = fsv[1];
    }
    if (tid < 512) {
        #pragma unroll
        for (int r = 0; r < R_N; ++r)
            out_fv[(((size_t)b * R_N + r) * H_N + hv) * DH_N + dv] = fv[r];
    }
    if (tid == 0) out_tick[b] = tick_b + (float)T_LEN;
}

extern "C" void kernel_launch(void* const* d_in, const int* in_sizes, int n_in,
                              void* d_out, int out_size, void* d_ws, size_t ws_size,
                              hipStream_t stream)
{
    const float* inputs  = (const float*)d_in[0];
    const int*   term    = (const int*)  d_in[1];
    const float* fk_prev = (const float*)d_in[2];
    const float* fv_prev = (const float*)d_in[3];
    const float* fs_prev = (const float*)d_in[4];
    const float* tick    = (const float*)d_in[5];
    const float* Wf      = (const float*)d_in[6];
    const float* bf      = (const float*)d_in[7];
    const float* Wp      = (const float*)d_in[8];
    const float* bp      = (const float*)d_in[9];

    float* out      = (float*)d_out;
    float* out_fk   = out    + (size_t)T_LEN * B_SZ * DMODEL;          // (B,R,H,FD)
    float* out_fv   = out_fk + (size_t)B_SZ * R_N * H_N * FD_N;        // (B,R,H,DH)
    float* out_fs   = out_fv + (size_t)B_SZ * R_N * H_N * DH_N;        // (B,H,FD)
    float* out_tick = out_fs + (size_t)B_SZ * H_N * FD_N;              // (B,)

    float* all_proj = (float*)d_ws;                                    // (T*B, PROJ)
    float* attn     = all_proj + (size_t)T_LEN * B_SZ * PROJ_N;        // (T*B, 512)

    // 1) all_proj = inputs @ Wf^T + bf
    {
        dim3 grid((PROJ_N + 63) / 64, (T_LEN * B_SZ) / 64);
        gemm_nt_bias<<<grid, dim3(256), 0, stream>>>(
            inputs, Wf, bf, all_proj, T_LEN * B_SZ, PROJ_N, DMODEL);
    }

    // 2) recurrent scan + attention -> attn, final states
    agalite_scan<<<dim3(B_SZ), dim3(1024), 0, stream>>>(
        all_proj, term, tick, fk_prev, fv_prev, fs_prev,
        attn, out_fk, out_fv, out_fs, out_tick);

    // 3) out = attn @ Wp^T + bp
    {
        dim3 grid(DMODEL / 64, (T_LEN * B_SZ) / 64);
        gemm_nt_bias<<<grid, dim3(256), 0, stream>>>(
            attn, Wp, bp, out, T_LEN * B_SZ, DMODEL, H_N * DH_N);
    }
}

// Round 3
// 651.061 us; speedup vs baseline: 1.3579x; 1.3579x over previous
//
#include <hip/hip_runtime.h>
#include <hip/hip_bf16.h>
#include <math.h>

#define T_LEN  128
#define B_SZ   32
#define DMODEL 1024
#define H_N    8
#define DH_N   64
#define ETA_N  4
#define FD_N   256
#define R_N    4
#define PROJ_N 2656
#define EPS_F  1e-6f

typedef __attribute__((ext_vector_type(8))) short bf16x8;
typedef __attribute__((ext_vector_type(4))) float f32x4;

__device__ __forceinline__ float sigmoidf_(float x) { return 1.0f / (1.0f + __expf(-x)); }

// ---------------- bf16 convert (for GEMM2 weights) ----------------
__global__ void cvt_bf16(const float* __restrict__ src, __hip_bfloat16* __restrict__ dst, int n)
{
    int i = (blockIdx.x * blockDim.x + threadIdx.x) * 4;
    const int stride = gridDim.x * blockDim.x * 4;
    for (; i < n; i += stride) {
        float4 v = *(const float4*)(src + i);
        dst[i + 0] = __float2bfloat16(v.x);
        dst[i + 1] = __float2bfloat16(v.y);
        dst[i + 2] = __float2bfloat16(v.z);
        dst[i + 3] = __float2bfloat16(v.w);
    }
}

// ---------------- f32 GEMM (precision-critical projection) ----------------
// C[M,N] = A[M,K] @ Bm[N,K]^T + bias[N]. BM=BN=128, BK=16, 256 threads,
// 8x8 micro-tile/thread. LDS stored transposed [k][m] (pad 132 -> float4 reads
// are broadcast or 2-way only). Register prefetch of next k-tile.
// Requires M%128==0, K%16==0; N bounds-checked.
__global__ __launch_bounds__(256) void gemm_f32(
    const float* __restrict__ A, const float* __restrict__ Bm,
    const float* __restrict__ bias, float* __restrict__ C,
    int M, int N, int K)
{
    __shared__ __align__(16) float As[16][132];
    __shared__ __align__(16) float Bs[16][132];

    const int tid = threadIdx.x;
    const int tx  = tid & 15;          // col group
    const int ty  = tid >> 4;          // row group
    const int row0 = blockIdx.y * 128;
    const int col0 = blockIdx.x * 128;

    const int srow = tid >> 2;         // 0..63
    const int skk  = (tid & 3) * 4;    // 0,4,8,12

    const float* aptr0 = A + (size_t)(row0 + srow) * K + skk;
    const float* aptr1 = aptr0 + (size_t)64 * K;
    const int bRow0 = col0 + srow, bRow1 = bRow0 + 64;
    const float* bptr0 = Bm + (size_t)bRow0 * K + skk;
    const float* bptr1 = Bm + (size_t)bRow1 * K + skk;
    const bool bok0 = bRow0 < N, bok1 = bRow1 < N;

    float acc[8][8] = {};

    float4 a0 = *(const float4*)(aptr0);
    float4 a1 = *(const float4*)(aptr1);
    float4 b0 = bok0 ? *(const float4*)(bptr0) : make_float4(0.f,0.f,0.f,0.f);
    float4 b1 = bok1 ? *(const float4*)(bptr1) : make_float4(0.f,0.f,0.f,0.f);

    for (int k0 = 0; k0 < K; k0 += 16) {
        As[skk+0][srow]    = a0.x; As[skk+1][srow]    = a0.y;
        As[skk+2][srow]    = a0.z; As[skk+3][srow]    = a0.w;
        As[skk+0][srow+64] = a1.x; As[skk+1][srow+64] = a1.y;
        As[skk+2][srow+64] = a1.z; As[skk+3][srow+64] = a1.w;
        Bs[skk+0][srow]    = b0.x; Bs[skk+1][srow]    = b0.y;
        Bs[skk+2][srow]    = b0.z; Bs[skk+3][srow]    = b0.w;
        Bs[skk+0][srow+64] = b1.x; Bs[skk+1][srow+64] = b1.y;
        Bs[skk+2][srow+64] = b1.z; Bs[skk+3][srow+64] = b1.w;
        __syncthreads();

        if (k0 + 16 < K) {
            a0 = *(const float4*)(aptr0 + k0 + 16);
            a1 = *(const float4*)(aptr1 + k0 + 16);
            if (bok0) b0 = *(const float4*)(bptr0 + k0 + 16);
            if (bok1) b1 = *(const float4*)(bptr1 + k0 + 16);
        }

        #pragma unroll
        for (int kk = 0; kk < 16; ++kk) {
            const float4 va0 = *(const float4*)&As[kk][ty*4];
            const float4 va1 = *(const float4*)&As[kk][ty*4+64];
            const float4 vb0 = *(const float4*)&Bs[kk][tx*4];
            const float4 vb1 = *(const float4*)&Bs[kk][tx*4+64];
            const float am[8] = {va0.x,va0.y,va0.z,va0.w, va1.x,va1.y,va1.z,va1.w};
            const float bn[8] = {vb0.x,vb0.y,vb0.z,vb0.w, vb1.x,vb1.y,vb1.z,vb1.w};
            #pragma unroll
            for (int mi = 0; mi < 8; ++mi)
                #pragma unroll
                for (int nj = 0; nj < 8; ++nj)
                    acc[mi][nj] += am[mi] * bn[nj];
        }
        __syncthreads();
    }

    #pragma unroll
    for (int mi = 0; mi < 8; ++mi) {
        const int r = row0 + ty*4 + ((mi < 4) ? mi : 64 + (mi - 4));
        #pragma unroll
        for (int nj = 0; nj < 8; ++nj) {
            const int c = col0 + tx*4 + ((nj < 4) ? nj : 64 + (nj - 4));
            if (c < N) C[(size_t)r * N + c] = acc[mi][nj] + bias[c];
        }
    }
}

// ---------------- bf16 MFMA GEMM (output projection only) ----------------
// C[M,N] = A[M,K] @ Bm[N,K]^T + bias[N]; A,Bm bf16; C f32.
// BM=BN=128, BK=32, 256 threads (4 waves 2x2), 16x16x32 MFMA, 4x4 frags/wave.
__global__ __launch_bounds__(256) void gemm_mfma_f32out(
    const __hip_bfloat16* __restrict__ A,
    const __hip_bfloat16* __restrict__ Bm,
    const float* __restrict__ bias,
    float* __restrict__ C,
    int M, int N, int K)
{
    __shared__ __align__(16) __hip_bfloat16 As[128][40];
    __shared__ __align__(16) __hip_bfloat16 Bs[128][40];

    const int tid  = threadIdx.x;
    const int wave = tid >> 6;
    const int lane = tid & 63;
    const int row0 = blockIdx.y * 128;
    const int col0 = blockIdx.x * 128;

    const int wr = (wave >> 1) * 64;
    const int wc = (wave & 1) * 64;
    const int lr = lane & 15;
    const int lk = (lane >> 4) * 8;
    const int lq = (lane >> 4) * 4;

    const int srow = tid >> 2;
    const int skk  = (tid & 3) * 8;

    f32x4 acc[4][4] = {};

    for (int k0 = 0; k0 < K; k0 += 32) {
        #pragma unroll
        for (int j = 0; j < 2; ++j) {
            const int r = j * 64 + srow;
            bf16x8 va = *reinterpret_cast<const bf16x8*>(A  + (size_t)(row0 + r) * K + k0 + skk);
            bf16x8 vb = *reinterpret_cast<const bf16x8*>(Bm + (size_t)(col0 + r) * K + k0 + skk);
            *reinterpret_cast<bf16x8*>(&As[r][skk]) = va;
            *reinterpret_cast<bf16x8*>(&Bs[r][skk]) = vb;
        }
        __syncthreads();

        bf16x8 af[4], bfr[4];
        #pragma unroll
        for (int i = 0; i < 4; ++i)
            af[i] = *reinterpret_cast<const bf16x8*>(&As[wr + i*16 + lr][lk]);
        #pragma unroll
        for (int j = 0; j < 4; ++j)
            bfr[j] = *reinterpret_cast<const bf16x8*>(&Bs[wc + j*16 + lr][lk]);
        #pragma unroll
        for (int i = 0; i < 4; ++i)
            #pragma unroll
            for (int j = 0; j < 4; ++j)
                acc[i][j] = __builtin_amdgcn_mfma_f32_16x16x32_bf16(af[i], bfr[j], acc[i][j], 0, 0, 0);
        __syncthreads();
    }

    #pragma unroll
    for (int j = 0; j < 4; ++j) {
        const int col = col0 + wc + j*16 + lr;
        const float bs = bias[col];
        #pragma unroll
        for (int i = 0; i < 4; ++i) {
            const int rowb = row0 + wr + i*16 + lq;
            #pragma unroll
            for (int r = 0; r < 4; ++r)
                C[(size_t)(rowb + r) * N + col] = acc[i][j][r] + bs;
        }
    }
}

// ---------------- recurrent scan ----------------
__global__ __launch_bounds__(1024)
void agalite_scan(const float* __restrict__ proj,    // (T*B, PROJ) f32
                  const int*   __restrict__ term,
                  const float* __restrict__ tick_in,
                  const float* __restrict__ fk_prev,
                  const float* __restrict__ fv_prev,
                  const float* __restrict__ fs_prev,
                  __hip_bfloat16* __restrict__ attn, // (T*B, H*DH) bf16
                  float* __restrict__ out_fk,
                  float* __restrict__ out_fv,
                  float* __restrict__ out_fs,
                  float* __restrict__ out_tick)
{
    const int b   = blockIdx.x;
    const int tid = threadIdx.x;

    __shared__ float proj_s[2][PROJ_N];
    __shared__ float red_sc[16][4];
    __shared__ float red_nrm[16];
    __shared__ float scores_s[4];
    __shared__ float norm_s[8];

    const int h  = tid >> 7;
    const int f0 = (tid << 1) & 255;
    const int d  = f0 >> 2;
    const int e0 = f0 & 3;
    const int e1 = e0 + 1;
    const int f1 = f0 + 1;

    const int hv = tid >> 6;
    const int dv = tid & 63;

    float fk[R_N][2];
    float fsv[2];
    #pragma unroll
    for (int r = 0; r < R_N; ++r) {
        const float* p = fk_prev + (((size_t)b * R_N + r) * H_N + h) * FD_N;
        fk[r][0] = p[f0]; fk[r][1] = p[f1];
    }
    {
        const float* p = fs_prev + ((size_t)b * H_N + h) * FD_N;
        fsv[0] = p[f0]; fsv[1] = p[f1];
    }
    float fv[R_N] = {0.f, 0.f, 0.f, 0.f};
    if (tid < 512) {
        #pragma unroll
        for (int r = 0; r < R_N; ++r)
            fv[r] = fv_prev[(((size_t)b * R_N + r) * H_N + hv) * DH_N + dv];
    }

    const float tick_b = tick_in[b];
    const float PI_F = 3.14159265358979323846f;
    const float omega[4] = {-PI_F, -PI_F/3.0f, PI_F/3.0f, PI_F};

    for (int i = tid; i < PROJ_N; i += 1024)
        proj_s[0][i] = proj[(size_t)b * PROJ_N + i];
    __syncthreads();

    for (int t = 0; t < T_LEN; ++t) {
        const int cur = t & 1, nxt = cur ^ 1;

        float pf0 = 0.f, pf1 = 0.f, pf2 = 0.f;
        if (t + 1 < T_LEN) {
            const float* src = proj + ((size_t)(t + 1) * B_SZ + b) * PROJ_N;
            pf0 = src[tid];
            pf1 = src[tid + 1024];
            if (tid + 2048 < PROJ_N) pf2 = src[tid + 2048];
        }

        const float* P = proj_s[cur];
        const float mask = 1.0f - (float)term[t * B_SZ + b];
        const float tt = (float)(t + 1) + tick_b;
        float cosr[4];
        #pragma unroll
        for (int r = 0; r < R_N; ++r) cosr[r] = cosf(tt * omega[r]);

        const int base = h * 320;
        const float kkv = P[base + d];
        const float qqv = P[base + 64 + d];
        const float ggv = P[base + 256 + d];
        const int pb = 2560 + h * 12;
        const float p1a = P[pb + e0],     p1b = P[pb + e1];
        const float p2a = P[pb + 4 + e0], p2b = P[pb + 4 + e1];
        const float p3a = P[pb + 8 + e0], p3b = P[pb + 8 + e1];

        const float rk = fmaxf(kkv, 0.f);
        const float rq = fmaxf(qqv, 0.f);
        const float sg = sigmoidf_(ggv);
        const float psi0 = rk * fmaxf(p1a, 0.f), psi1 = rk * fmaxf(p1b, 0.f);
        const float phi0 = rq * fmaxf(p2a, 0.f), phi1 = rq * fmaxf(p2b, 0.f);
        const float gf0 = sg * sigmoidf_(p3a),   gf1 = sg * sigmoidf_(p3b);
        const float kg0 = psi0 * gf0, kg1 = psi1 * gf1;
        const float dg0 = (1.f - gf0) * mask, dg1 = (1.f - gf1) * mask;

        fsv[0] = dg0 * fsv[0] + kg0;
        fsv[1] = dg1 * fsv[1] + kg1;
        float nrm_p = fsv[0] * phi0 + fsv[1] * phi1;
        float sc_p[4];
        #pragma unroll
        for (int r = 0; r < R_N; ++r) {
            fk[r][0] = dg0 * fk[r][0] + kg0 * cosr[r];
            fk[r][1] = dg1 * fk[r][1] + kg1 * cosr[r];
            sc_p[r] = fk[r][0] * phi0 + fk[r][1] * phi1;
        }

        if (tid < 512) {
            const int vb = hv * 320;
            const float vvv = P[vb + 128 + dv];
            const float bbv = sigmoidf_(P[vb + 192 + dv]);
            const float vg = vvv * bbv;
            const float db = (1.f - bbv) * mask;
            #pragma unroll
            for (int r = 0; r < R_N; ++r) fv[r] = db * fv[r] + vg * cosr[r];
        }

        #pragma unroll
        for (int off = 32; off >= 1; off >>= 1) {
            #pragma unroll
            for (int r = 0; r < R_N; ++r) sc_p[r] += __shfl_xor(sc_p[r], off);
            nrm_p += __shfl_xor(nrm_p, off);
        }
        const int wave = tid >> 6;
        if ((tid & 63) == 0) {
            #pragma unroll
            for (int r = 0; r < R_N; ++r) red_sc[wave][r] = sc_p[r];
            red_nrm[wave] = nrm_p;
        }
        __syncthreads();                                  // [A]
        if (tid < 4) {
            float s = 0.f;
            #pragma unroll
            for (int w = 0; w < 16; ++w) s += red_sc[w][tid];
            scores_s[tid] = s;
        } else if (tid >= 8 && tid < 16) {
            const int hh = tid - 8;
            norm_s[hh] = red_nrm[2*hh] + red_nrm[2*hh+1];
        }
        __syncthreads();                                  // [B]

        if (tid < 512) {
            const float kv = fv[0]*scores_s[0] + fv[1]*scores_s[1]
                           + fv[2]*scores_s[2] + fv[3]*scores_s[3];
            attn[((size_t)t * B_SZ + b) * (H_N * DH_N) + tid] =
                __float2bfloat16(kv / (2.0f * R_N * norm_s[hv] + EPS_F));
        }

        if (t + 1 < T_LEN) {
            proj_s[nxt][tid]        = pf0;
            proj_s[nxt][tid + 1024] = pf1;
            if (tid + 2048 < PROJ_N) proj_s[nxt][tid + 2048] = pf2;
        }
        __syncthreads();                                  // [C]
    }

    #pragma unroll
    for (int r = 0; r < R_N; ++r) {
        float* p = out_fk + (((size_t)b * R_N + r) * H_N + h) * FD_N;
        p[f0] = fk[r][0]; p[f1] = fk[r][1];
    }
    {
        float* p = out_fs + ((size_t)b * H_N + h) * FD_N;
        p[f0] = fsv[0]; p[f1] = fsv[1];
    }
    if (tid < 512) {
        #pragma unroll
        for (int r = 0; r < R_N; ++r)
            out_fv[(((size_t)b * R_N + r) * H_N + hv) * DH_N + dv] = fv[r];
    }
    if (tid == 0) out_tick[b] = tick_b + (float)T_LEN;
}

extern "C" void kernel_launch(void* const* d_in, const int* in_sizes, int n_in,
                              void* d_out, int out_size, void* d_ws, size_t ws_size,
                              hipStream_t stream)
{
    const float* inputs  = (const float*)d_in[0];
    const int*   term    = (const int*)  d_in[1];
    const float* fk_prev = (const float*)d_in[2];
    const float* fv_prev = (const float*)d_in[3];
    const float* fs_prev = (const float*)d_in[4];
    const float* tick    = (const float*)d_in[5];
    const float* Wf      = (const float*)d_in[6];
    const float* bf      = (const float*)d_in[7];
    const float* Wp      = (const float*)d_in[8];
    const float* bp      = (const float*)d_in[9];

    float* out      = (float*)d_out;
    float* out_fk   = out    + (size_t)T_LEN * B_SZ * DMODEL;
    float* out_fv   = out_fk + (size_t)B_SZ * R_N * H_N * FD_N;
    float* out_fs   = out_fv + (size_t)B_SZ * R_N * H_N * DH_N;
    float* out_tick = out_fs + (size_t)B_SZ * H_N * FD_N;

    char* ws = (char*)d_ws;
    float* proj = (float*)ws;                                   // 4096*2656*4
    ws += (size_t)T_LEN * B_SZ * PROJ_N * 4;
    __hip_bfloat16* attn_bf = (__hip_bfloat16*)ws;              // 4096*512*2
    ws += (size_t)T_LEN * B_SZ * H_N * DH_N * 2;
    __hip_bfloat16* Wp_bf = (__hip_bfloat16*)ws;                // 1024*512*2
    ws += (size_t)DMODEL * H_N * DH_N * 2;

    const int n_wp_el = DMODEL * H_N * DH_N;  // 524288

    cvt_bf16<<<512, 256, 0, stream>>>(Wp, Wp_bf, n_wp_el);

    // 1) proj = inputs @ Wf^T + bf   (f32 — precision-critical)
    gemm_f32<<<dim3((PROJ_N + 127) / 128, (T_LEN * B_SZ) / 128), dim3(256), 0, stream>>>(
        inputs, Wf, bf, proj, T_LEN * B_SZ, PROJ_N, DMODEL);

    // 2) recurrent scan + attention
    agalite_scan<<<dim3(B_SZ), dim3(1024), 0, stream>>>(
        proj, term, tick, fk_prev, fv_prev, fs_prev,
        attn_bf, out_fk, out_fv, out_fs, out_tick);

    // 3) out = attn @ Wp^T + bp   (bf16 MFMA, f32 out)
    gemm_mfma_f32out<<<dim3(DMODEL / 128, (T_LEN * B_SZ) / 128), dim3(256), 0, stream>>>(
        attn_bf, Wp_bf, bp, out, T_LEN * B_SZ, DMODEL, H_N * DH_N);
}

// Round 4
// 503.987 us; speedup vs baseline: 1.7542x; 1.2918x over previous
//
#include <hip/hip_runtime.h>
#include <hip/hip_bf16.h>
#include <math.h>

#define T_LEN  128
#define B_SZ   32
#define DMODEL 1024
#define H_N    8
#define DH_N   64
#define ETA_N  4
#define FD_N   256
#define R_N    4
#define PROJ_N 2656
#define EPS_F  1e-6f

typedef __attribute__((ext_vector_type(8))) short bf16x8;
typedef __attribute__((ext_vector_type(4))) float f32x4;

__device__ __forceinline__ float sigmoidf_(float x) { return 1.0f / (1.0f + __expf(-x)); }

// ---------------- bf16 convert (for GEMM2 weights) ----------------
__global__ void cvt_bf16(const float* __restrict__ src, __hip_bfloat16* __restrict__ dst, int n)
{
    int i = (blockIdx.x * blockDim.x + threadIdx.x) * 4;
    const int stride = gridDim.x * blockDim.x * 4;
    for (; i < n; i += stride) {
        float4 v = *(const float4*)(src + i);
        dst[i + 0] = __float2bfloat16(v.x);
        dst[i + 1] = __float2bfloat16(v.y);
        dst[i + 2] = __float2bfloat16(v.z);
        dst[i + 3] = __float2bfloat16(v.w);
    }
}

// ---------------- f32 GEMM (precision-critical projection) ----------------
__global__ __launch_bounds__(256) void gemm_f32(
    const float* __restrict__ A, const float* __restrict__ Bm,
    const float* __restrict__ bias, float* __restrict__ C,
    int M, int N, int K)
{
    __shared__ __align__(16) float As[16][132];
    __shared__ __align__(16) float Bs[16][132];

    const int tid = threadIdx.x;
    const int tx  = tid & 15;
    const int ty  = tid >> 4;
    const int row0 = blockIdx.y * 128;
    const int col0 = blockIdx.x * 128;

    const int srow = tid >> 2;
    const int skk  = (tid & 3) * 4;

    const float* aptr0 = A + (size_t)(row0 + srow) * K + skk;
    const float* aptr1 = aptr0 + (size_t)64 * K;
    const int bRow0 = col0 + srow, bRow1 = bRow0 + 64;
    const float* bptr0 = Bm + (size_t)bRow0 * K + skk;
    const float* bptr1 = Bm + (size_t)bRow1 * K + skk;
    const bool bok0 = bRow0 < N, bok1 = bRow1 < N;

    float acc[8][8] = {};

    float4 a0 = *(const float4*)(aptr0);
    float4 a1 = *(const float4*)(aptr1);
    float4 b0 = bok0 ? *(const float4*)(bptr0) : make_float4(0.f,0.f,0.f,0.f);
    float4 b1 = bok1 ? *(const float4*)(bptr1) : make_float4(0.f,0.f,0.f,0.f);

    for (int k0 = 0; k0 < K; k0 += 16) {
        As[skk+0][srow]    = a0.x; As[skk+1][srow]    = a0.y;
        As[skk+2][srow]    = a0.z; As[skk+3][srow]    = a0.w;
        As[skk+0][srow+64] = a1.x; As[skk+1][srow+64] = a1.y;
        As[skk+2][srow+64] = a1.z; As[skk+3][srow+64] = a1.w;
        Bs[skk+0][srow]    = b0.x; Bs[skk+1][srow]    = b0.y;
        Bs[skk+2][srow]    = b0.z; Bs[skk+3][srow]    = b0.w;
        Bs[skk+0][srow+64] = b1.x; Bs[skk+1][srow+64] = b1.y;
        Bs[skk+2][srow+64] = b1.z; Bs[skk+3][srow+64] = b1.w;
        __syncthreads();

        if (k0 + 16 < K) {
            a0 = *(const float4*)(aptr0 + k0 + 16);
            a1 = *(const float4*)(aptr1 + k0 + 16);
            if (bok0) b0 = *(const float4*)(bptr0 + k0 + 16);
            if (bok1) b1 = *(const float4*)(bptr1 + k0 + 16);
        }

        #pragma unroll
        for (int kk = 0; kk < 16; ++kk) {
            const float4 va0 = *(const float4*)&As[kk][ty*4];
            const float4 va1 = *(const float4*)&As[kk][ty*4+64];
            const float4 vb0 = *(const float4*)&Bs[kk][tx*4];
            const float4 vb1 = *(const float4*)&Bs[kk][tx*4+64];
            const float am[8] = {va0.x,va0.y,va0.z,va0.w, va1.x,va1.y,va1.z,va1.w};
            const float bn[8] = {vb0.x,vb0.y,vb0.z,vb0.w, vb1.x,vb1.y,vb1.z,vb1.w};
            #pragma unroll
            for (int mi = 0; mi < 8; ++mi)
                #pragma unroll
                for (int nj = 0; nj < 8; ++nj)
                    acc[mi][nj] += am[mi] * bn[nj];
        }
        __syncthreads();
    }

    #pragma unroll
    for (int mi = 0; mi < 8; ++mi) {
        const int r = row0 + ty*4 + ((mi < 4) ? mi : 64 + (mi - 4));
        #pragma unroll
        for (int nj = 0; nj < 8; ++nj) {
            const int c = col0 + tx*4 + ((nj < 4) ? nj : 64 + (nj - 4));
            if (c < N) C[(size_t)r * N + c] = acc[mi][nj] + bias[c];
        }
    }
}

// ---------------- bf16 MFMA GEMM (output projection only) ----------------
__global__ __launch_bounds__(256) void gemm_mfma_f32out(
    const __hip_bfloat16* __restrict__ A,
    const __hip_bfloat16* __restrict__ Bm,
    const float* __restrict__ bias,
    float* __restrict__ C,
    int M, int N, int K)
{
    __shared__ __align__(16) __hip_bfloat16 As[128][40];
    __shared__ __align__(16) __hip_bfloat16 Bs[128][40];

    const int tid  = threadIdx.x;
    const int wave = tid >> 6;
    const int lane = tid & 63;
    const int row0 = blockIdx.y * 128;
    const int col0 = blockIdx.x * 128;

    const int wr = (wave >> 1) * 64;
    const int wc = (wave & 1) * 64;
    const int lr = lane & 15;
    const int lk = (lane >> 4) * 8;
    const int lq = (lane >> 4) * 4;

    const int srow = tid >> 2;
    const int skk  = (tid & 3) * 8;

    f32x4 acc[4][4] = {};

    for (int k0 = 0; k0 < K; k0 += 32) {
        #pragma unroll
        for (int j = 0; j < 2; ++j) {
            const int r = j * 64 + srow;
            bf16x8 va = *reinterpret_cast<const bf16x8*>(A  + (size_t)(row0 + r) * K + k0 + skk);
            bf16x8 vb = *reinterpret_cast<const bf16x8*>(Bm + (size_t)(col0 + r) * K + k0 + skk);
            *reinterpret_cast<bf16x8*>(&As[r][skk]) = va;
            *reinterpret_cast<bf16x8*>(&Bs[r][skk]) = vb;
        }
        __syncthreads();

        bf16x8 af[4], bfr[4];
        #pragma unroll
        for (int i = 0; i < 4; ++i)
            af[i] = *reinterpret_cast<const bf16x8*>(&As[wr + i*16 + lr][lk]);
        #pragma unroll
        for (int j = 0; j < 4; ++j)
            bfr[j] = *reinterpret_cast<const bf16x8*>(&Bs[wc + j*16 + lr][lk]);
        #pragma unroll
        for (int i = 0; i < 4; ++i)
            #pragma unroll
            for (int j = 0; j < 4; ++j)
                acc[i][j] = __builtin_amdgcn_mfma_f32_16x16x32_bf16(af[i], bfr[j], acc[i][j], 0, 0, 0);
        __syncthreads();
    }

    #pragma unroll
    for (int j = 0; j < 4; ++j) {
        const int col = col0 + wc + j*16 + lr;
        const float bs = bias[col];
        #pragma unroll
        for (int i = 0; i < 4; ++i) {
            const int rowb = row0 + wr + i*16 + lq;
            #pragma unroll
            for (int r = 0; r < 4; ++r)
                C[(size_t)(rowb + r) * N + col] = acc[i][j][r] + bs;
        }
    }
}

// ---------------- recurrent scan (512 threads: wave = head) ----------------
// Wave w <-> head h. Lane owns features f = 4*lane..4*lane+3 (d = lane, e = 0..3)
// of (h, :) plus value lane (h = w, d = lane). norm[h] reduces within the wave
// (shuffles only); scores need one LDS combine -> ONE barrier per step.
// Proj reads are coalesced / wave-broadcast directly from global (no staging).
__global__ __launch_bounds__(512)
void agalite_scan(const float* __restrict__ proj,    // (T*B, PROJ) f32
                  const int*   __restrict__ term,
                  const float* __restrict__ tick_in,
                  const float* __restrict__ fk_prev,
                  const float* __restrict__ fv_prev,
                  const float* __restrict__ fs_prev,
                  __hip_bfloat16* __restrict__ attn, // (T*B, H*DH) bf16
                  float* __restrict__ out_fk,
                  float* __restrict__ out_fv,
                  float* __restrict__ out_fs,
                  float* __restrict__ out_tick)
{
    const int b    = blockIdx.x;
    const int tid  = threadIdx.x;
    const int w    = tid >> 6;     // head
    const int lane = tid & 63;     // d
    const int f0   = lane << 2;

    __shared__ float red[2][8][4];
    __shared__ __align__(16) float cos_s[T_LEN][4];

    const float tick_b = tick_in[b];
    {
        const int t = tid >> 2, r = tid & 3;
        const float PI_F = 3.14159265358979323846f;
        const float omega[4] = {-PI_F, -PI_F/3.0f, PI_F/3.0f, PI_F};
        cos_s[t][r] = cosf(((float)(t + 1) + tick_b) * omega[r]);
    }

    // ---- load state ----
    float fk[R_N][4], fsv[4], fv[R_N];
    #pragma unroll
    for (int r = 0; r < R_N; ++r) {
        const float4 kk = *(const float4*)(fk_prev + (((size_t)b * R_N + r) * H_N + w) * FD_N + f0);
        fk[r][0] = kk.x; fk[r][1] = kk.y; fk[r][2] = kk.z; fk[r][3] = kk.w;
        fv[r] = fv_prev[(((size_t)b * R_N + r) * H_N + w) * DH_N + lane];
    }
    {
        const float4 ss = *(const float4*)(fs_prev + ((size_t)b * H_N + w) * FD_N + f0);
        fsv[0] = ss.x; fsv[1] = ss.y; fsv[2] = ss.z; fsv[3] = ss.w;
    }

    // ---- prefetch t = 0 ----
    const int kbase = w * 320;
    const int pbase = 2560 + w * 12;
    const float* P0 = proj + (size_t)b * PROJ_N;   // row (t=0, b)
    float  pk = P0[kbase + lane];
    float  pq = P0[kbase + 64 + lane];
    float  pv = P0[kbase + 128 + lane];
    float  pbt = P0[kbase + 192 + lane];
    float  pg = P0[kbase + 256 + lane];
    float4 pp1 = *(const float4*)(P0 + pbase);
    float4 pp2 = *(const float4*)(P0 + pbase + 4);
    float4 pp3 = *(const float4*)(P0 + pbase + 8);
    int    ptm = term[b];

    __syncthreads();   // cos table ready

    for (int t = 0; t < T_LEN; ++t) {
        const float  kkv = pk, qqv = pq, vvv = pv, btv = pbt, ggv = pg;
        const float4 q1 = pp1, q2 = pp2, q3 = pp3;
        const float  mask = 1.0f - (float)ptm;

        if (t + 1 < T_LEN) {
            const float* P = proj + ((size_t)(t + 1) * B_SZ + b) * PROJ_N;
            pk  = P[kbase + lane];
            pq  = P[kbase + 64 + lane];
            pv  = P[kbase + 128 + lane];
            pbt = P[kbase + 192 + lane];
            pg  = P[kbase + 256 + lane];
            pp1 = *(const float4*)(P + pbase);
            pp2 = *(const float4*)(P + pbase + 4);
            pp3 = *(const float4*)(P + pbase + 8);
            ptm = term[(t + 1) * B_SZ + b];
        }

        const float4 cs = *(const float4*)&cos_s[t][0];
        const float cosr[4] = {cs.x, cs.y, cs.z, cs.w};

        const float rk = fmaxf(kkv, 0.f);
        const float rq = fmaxf(qqv, 0.f);
        const float sg = sigmoidf_(ggv);
        const float p1v[4] = {q1.x, q1.y, q1.z, q1.w};
        const float p2v[4] = {q2.x, q2.y, q2.z, q2.w};
        const float p3v[4] = {q3.x, q3.y, q3.z, q3.w};

        float phi[4], kg[4], dg[4];
        float nrm_p = 0.f;
        #pragma unroll
        for (int e = 0; e < 4; ++e) {
            const float psi = rk * fmaxf(p1v[e], 0.f);
            phi[e] = rq * fmaxf(p2v[e], 0.f);
            const float gf = sg * sigmoidf_(p3v[e]);
            kg[e] = psi * gf;
            dg[e] = (1.f - gf) * mask;
            fsv[e] = dg[e] * fsv[e] + kg[e];
            nrm_p += fsv[e] * phi[e];
        }
        float sc_p[R_N];
        #pragma unroll
        for (int r = 0; r < R_N; ++r) {
            float s = 0.f;
            #pragma unroll
            for (int e = 0; e < 4; ++e) {
                fk[r][e] = dg[e] * fk[r][e] + kg[e] * cosr[r];
                s += fk[r][e] * phi[e];
            }
            sc_p[r] = s;
        }

        // value lane update
        const float bb = sigmoidf_(btv);
        const float vg = vvv * bb;
        const float db = (1.f - bb) * mask;
        #pragma unroll
        for (int r = 0; r < R_N; ++r) fv[r] = db * fv[r] + vg * cosr[r];

        // wave butterfly: scores partial (per wave) + norm (complete: wave == head)
        #pragma unroll
        for (int off = 32; off >= 1; off >>= 1) {
            #pragma unroll
            for (int r = 0; r < R_N; ++r) sc_p[r] += __shfl_xor(sc_p[r], off);
            nrm_p += __shfl_xor(nrm_p, off);
        }
        if (lane == 0) {
            red[t & 1][w][0] = sc_p[0]; red[t & 1][w][1] = sc_p[1];
            red[t & 1][w][2] = sc_p[2]; red[t & 1][w][3] = sc_p[3];
        }
        __syncthreads();    // the ONE barrier per step

        float s0 = 0.f, s1 = 0.f, s2 = 0.f, s3 = 0.f;
        #pragma unroll
        for (int ww = 0; ww < 8; ++ww) {
            const float4 rv = *(const float4*)&red[t & 1][ww][0];
            s0 += rv.x; s1 += rv.y; s2 += rv.z; s3 += rv.w;
        }

        const float kv = fv[0]*s0 + fv[1]*s1 + fv[2]*s2 + fv[3]*s3;
        attn[((size_t)t * B_SZ + b) * (H_N * DH_N) + tid] =
            __float2bfloat16(kv / (2.0f * R_N * nrm_p + EPS_F));
    }

    // ---- final states ----
    #pragma unroll
    for (int r = 0; r < R_N; ++r) {
        float* p = out_fk + (((size_t)b * R_N + r) * H_N + w) * FD_N + f0;
        *(float4*)p = make_float4(fk[r][0], fk[r][1], fk[r][2], fk[r][3]);
        out_fv[(((size_t)b * R_N + r) * H_N + w) * DH_N + lane] = fv[r];
    }
    {
        float* p = out_fs + ((size_t)b * H_N + w) * FD_N + f0;
        *(float4*)p = make_float4(fsv[0], fsv[1], fsv[2], fsv[3]);
    }
    if (tid == 0) out_tick[b] = tick_b + (float)T_LEN;
}

extern "C" void kernel_launch(void* const* d_in, const int* in_sizes, int n_in,
                              void* d_out, int out_size, void* d_ws, size_t ws_size,
                              hipStream_t stream)
{
    const float* inputs  = (const float*)d_in[0];
    const int*   term    = (const int*)  d_in[1];
    const float* fk_prev = (const float*)d_in[2];
    const float* fv_prev = (const float*)d_in[3];
    const float* fs_prev = (const float*)d_in[4];
    const float* tick    = (const float*)d_in[5];
    const float* Wf      = (const float*)d_in[6];
    const float* bf      = (const float*)d_in[7];
    const float* Wp      = (const float*)d_in[8];
    const float* bp      = (const float*)d_in[9];

    float* out      = (float*)d_out;
    float* out_fk   = out    + (size_t)T_LEN * B_SZ * DMODEL;
    float* out_fv   = out_fk + (size_t)B_SZ * R_N * H_N * FD_N;
    float* out_fs   = out_fv + (size_t)B_SZ * R_N * H_N * DH_N;
    float* out_tick = out_fs + (size_t)B_SZ * H_N * FD_N;

    char* ws = (char*)d_ws;
    float* proj = (float*)ws;                                   // 4096*2656*4
    ws += (size_t)T_LEN * B_SZ * PROJ_N * 4;
    __hip_bfloat16* attn_bf = (__hip_bfloat16*)ws;              // 4096*512*2
    ws += (size_t)T_LEN * B_SZ * H_N * DH_N * 2;
    __hip_bfloat16* Wp_bf = (__hip_bfloat16*)ws;                // 1024*512*2
    ws += (size_t)DMODEL * H_N * DH_N * 2;

    const int n_wp_el = DMODEL * H_N * DH_N;

    cvt_bf16<<<512, 256, 0, stream>>>(Wp, Wp_bf, n_wp_el);

    // 1) proj = inputs @ Wf^T + bf   (f32 — precision-critical)
    gemm_f32<<<dim3((PROJ_N + 127) / 128, (T_LEN * B_SZ) / 128), dim3(256), 0, stream>>>(
        inputs, Wf, bf, proj, T_LEN * B_SZ, PROJ_N, DMODEL);

    // 2) recurrent scan + attention
    agalite_scan<<<dim3(B_SZ), dim3(512), 0, stream>>>(
        proj, term, tick, fk_prev, fv_prev, fs_prev,
        attn_bf, out_fk, out_fv, out_fs, out_tick);

    // 3) out = attn @ Wp^T + bp   (bf16 MFMA, f32 out)
    gemm_mfma_f32out<<<dim3(DMODEL / 128, (T_LEN * B_SZ) / 128), dim3(256), 0, stream>>>(
        attn_bf, Wp_bf, bp, out, T_LEN * B_SZ, DMODEL, H_N * DH_N);
}

// Round 5
// 499.902 us; speedup vs baseline: 1.7685x; 1.0082x over previous
//
#include <hip/hip_runtime.h>
#include <hip/hip_bf16.h>
#include <math.h>

#define T_LEN  128
#define B_SZ   32
#define DMODEL 1024
#define H_N    8
#define DH_N   64
#define FD_N   256
#define R_N    4
#define PROJ_N 2656
#define NCRIT  1088
#define NREST  1568
#define NRESTP 1664
#define EPS_F  1e-6f

typedef __attribute__((ext_vector_type(8))) short bf16x8;
typedef __attribute__((ext_vector_type(4))) float f32x4;

__device__ __forceinline__ float sigmoidf_(float x) { return 1.0f / (1.0f + __expf(-x)); }

// column maps: crit j -> Wf row.  crit layout: [k 8x64][q 8x64][p1 8x4][p2 8x4]
__device__ __forceinline__ int map_crit(int j) {
    if (j < 512)  return (j >> 6) * 320 + (j & 63);                                  // k
    if (j < 1024) { int t = j - 512;  return (t >> 6) * 320 + 64 + (t & 63); }       // q
    if (j < 1056) { int t = j - 1024; return 2560 + (t >> 2) * 12 + (t & 3); }       // p1
    { int t = j - 1056; return 2560 + (t >> 2) * 12 + 4 + (t & 3); }                 // p2
}
// rest layout: [v 8x64][beta 8x64][gamma 8x64][p3 8x4]  (j < 1568)
__device__ __forceinline__ int map_rest(int j) {
    if (j < 512)  return (j >> 6) * 320 + 128 + (j & 63);                            // v
    if (j < 1024) { int t = j - 512;  return (t >> 6) * 320 + 192 + (t & 63); }      // beta
    if (j < 1536) { int t = j - 1024; return (t >> 6) * 320 + 256 + (t & 63); }      // gamma
    { int t = j - 1536; return 2560 + (t >> 2) * 12 + 8 + (t & 3); }                 // p3
}

__device__ __forceinline__ bf16x8 pack8(float4 u, float4 v) {
    union { bf16x8 v8; __hip_bfloat16 h[8]; } x;
    x.h[0] = __float2bfloat16(u.x); x.h[1] = __float2bfloat16(u.y);
    x.h[2] = __float2bfloat16(u.z); x.h[3] = __float2bfloat16(u.w);
    x.h[4] = __float2bfloat16(v.x); x.h[5] = __float2bfloat16(v.y);
    x.h[6] = __float2bfloat16(v.z); x.h[7] = __float2bfloat16(v.w);
    return x.v8;
}

__global__ void cvt_bf16(const float* __restrict__ src, __hip_bfloat16* __restrict__ dst, int n)
{
    int i = (blockIdx.x * blockDim.x + threadIdx.x) * 4;
    const int stride = gridDim.x * blockDim.x * 4;
    for (; i < n; i += stride) {
        float4 v = *(const float4*)(src + i);
        dst[i + 0] = __float2bfloat16(v.x);
        dst[i + 1] = __float2bfloat16(v.y);
        dst[i + 2] = __float2bfloat16(v.z);
        dst[i + 3] = __float2bfloat16(v.w);
    }
}

// ---------------- f32 GEMM, precision-critical columns ----------------
// C[4096,1088] = A[4096,1024] @ Wf[map_crit(j),:]^T + bf.  Tile 128Mx64N, BK=32,
// 256 threads, 8x4 micro-tile. LDS transposed [k][m], padded strides.
__global__ __launch_bounds__(256) void gemm_f32_crit(
    const float* __restrict__ A, const float* __restrict__ Wf,
    const float* __restrict__ bias, float* __restrict__ C)
{
    __shared__ __align__(16) float As[32][132];
    __shared__ __align__(16) float Bs[32][68];

    const int tid = threadIdx.x;
    const int tx = tid & 15;
    const int ty = tid >> 4;
    const int row0 = blockIdx.y * 128;
    const int col0 = blockIdx.x * 64;

    // A staging: 128 rows x 32 k = 16 f/thread; row tid>>1, kseg (tid&1)*16
    const int sar = tid >> 1;
    const int sak = (tid & 1) * 16;
    const float* aptr = A + (size_t)(row0 + sar) * 1024 + sak;
    // B staging: 64 rows x 32 k = 8 f/thread; row tid>>2, kseg (tid&3)*8
    const int sbr = tid >> 2;
    const int sbk = (tid & 3) * 8;
    const float* bptr = Wf + (size_t)map_crit(col0 + sbr) * 1024 + sbk;

    float acc[8][4] = {};

    float4 a0 = *(const float4*)(aptr + 0);
    float4 a1 = *(const float4*)(aptr + 4);
    float4 a2 = *(const float4*)(aptr + 8);
    float4 a3 = *(const float4*)(aptr + 12);
    float4 b0 = *(const float4*)(bptr + 0);
    float4 b1 = *(const float4*)(bptr + 4);

    for (int k0 = 0; k0 < 1024; k0 += 32) {
        As[sak+ 0][sar] = a0.x; As[sak+ 1][sar] = a0.y; As[sak+ 2][sar] = a0.z; As[sak+ 3][sar] = a0.w;
        As[sak+ 4][sar] = a1.x; As[sak+ 5][sar] = a1.y; As[sak+ 6][sar] = a1.z; As[sak+ 7][sar] = a1.w;
        As[sak+ 8][sar] = a2.x; As[sak+ 9][sar] = a2.y; As[sak+10][sar] = a2.z; As[sak+11][sar] = a2.w;
        As[sak+12][sar] = a3.x; As[sak+13][sar] = a3.y; As[sak+14][sar] = a3.z; As[sak+15][sar] = a3.w;
        Bs[sbk+0][sbr] = b0.x; Bs[sbk+1][sbr] = b0.y; Bs[sbk+2][sbr] = b0.z; Bs[sbk+3][sbr] = b0.w;
        Bs[sbk+4][sbr] = b1.x; Bs[sbk+5][sbr] = b1.y; Bs[sbk+6][sbr] = b1.z; Bs[sbk+7][sbr] = b1.w;
        __syncthreads();

        if (k0 + 32 < 1024) {
            a0 = *(const float4*)(aptr + k0 + 32);
            a1 = *(const float4*)(aptr + k0 + 36);
            a2 = *(const float4*)(aptr + k0 + 40);
            a3 = *(const float4*)(aptr + k0 + 44);
            b0 = *(const float4*)(bptr + k0 + 32);
            b1 = *(const float4*)(bptr + k0 + 36);
        }

        #pragma unroll
        for (int kk = 0; kk < 32; ++kk) {
            const float4 va0 = *(const float4*)&As[kk][ty*4];
            const float4 va1 = *(const float4*)&As[kk][ty*4+64];
            const float4 vb  = *(const float4*)&Bs[kk][tx*4];
            const float am[8] = {va0.x,va0.y,va0.z,va0.w, va1.x,va1.y,va1.z,va1.w};
            const float bn[4] = {vb.x,vb.y,vb.z,vb.w};
            #pragma unroll
            for (int mi = 0; mi < 8; ++mi)
                #pragma unroll
                for (int nj = 0; nj < 4; ++nj)
                    acc[mi][nj] += am[mi] * bn[nj];
        }
        __syncthreads();
    }

    float bsv[4];
    #pragma unroll
    for (int nj = 0; nj < 4; ++nj) bsv[nj] = bias[map_crit(col0 + tx*4 + nj)];
    #pragma unroll
    for (int mi = 0; mi < 8; ++mi) {
        const int r = row0 + ty*4 + ((mi < 4) ? mi : 64 + (mi - 4));
        #pragma unroll
        for (int nj = 0; nj < 4; ++nj)
            C[(size_t)r * NCRIT + col0 + tx*4 + nj] = acc[mi][nj] + bsv[nj];
    }
}

// ---------------- bf16 MFMA GEMM, rest columns (f32 in-staging convert) ----------------
// C[4096,1664] f32 = bf16(A[4096,1024]) @ bf16(Wf[map_rest(j),:])^T + bf
__global__ __launch_bounds__(256) void gemm_mfma_rest(
    const float* __restrict__ A, const float* __restrict__ Wf,
    const float* __restrict__ bias, float* __restrict__ C)
{
    __shared__ __align__(16) __hip_bfloat16 As[128][40];
    __shared__ __align__(16) __hip_bfloat16 Bs[128][40];

    const int tid  = threadIdx.x;
    const int wave = tid >> 6;
    const int lane = tid & 63;
    const int row0 = blockIdx.y * 128;
    const int col0 = blockIdx.x * 128;

    const int wr = (wave >> 1) * 64;
    const int wc = (wave & 1) * 64;
    const int lr = lane & 15;
    const int lk = (lane >> 4) * 8;
    const int lq = (lane >> 4) * 4;

    const int srow = tid >> 2;
    const int skk  = (tid & 3) * 8;

    const float* aP0 = A + (size_t)(row0 + srow) * 1024 + skk;
    const float* aP1 = aP0 + (size_t)64 * 1024;
    const int br0 = col0 + srow, br1 = br0 + 64;
    const bool ok0 = br0 < NREST, ok1 = br1 < NREST;
    const float* bP0 = Wf + (size_t)(ok0 ? map_rest(br0) : 0) * 1024 + skk;
    const float* bP1 = Wf + (size_t)(ok1 ? map_rest(br1) : 0) * 1024 + skk;

    f32x4 acc[4][4] = {};
    const float4 z = make_float4(0.f, 0.f, 0.f, 0.f);

    for (int k0 = 0; k0 < 1024; k0 += 32) {
        float4 a00 = *(const float4*)(aP0 + k0), a01 = *(const float4*)(aP0 + k0 + 4);
        float4 a10 = *(const float4*)(aP1 + k0), a11 = *(const float4*)(aP1 + k0 + 4);
        float4 b00 = ok0 ? *(const float4*)(bP0 + k0) : z, b01 = ok0 ? *(const float4*)(bP0 + k0 + 4) : z;
        float4 b10 = ok1 ? *(const float4*)(bP1 + k0) : z, b11 = ok1 ? *(const float4*)(bP1 + k0 + 4) : z;
        *reinterpret_cast<bf16x8*>(&As[srow][skk])    = pack8(a00, a01);
        *reinterpret_cast<bf16x8*>(&As[srow+64][skk]) = pack8(a10, a11);
        *reinterpret_cast<bf16x8*>(&Bs[srow][skk])    = pack8(b00, b01);
        *reinterpret_cast<bf16x8*>(&Bs[srow+64][skk]) = pack8(b10, b11);
        __syncthreads();

        bf16x8 af[4], bfr[4];
        #pragma unroll
        for (int i = 0; i < 4; ++i)
            af[i] = *reinterpret_cast<const bf16x8*>(&As[wr + i*16 + lr][lk]);
        #pragma unroll
        for (int j = 0; j < 4; ++j)
            bfr[j] = *reinterpret_cast<const bf16x8*>(&Bs[wc + j*16 + lr][lk]);
        #pragma unroll
        for (int i = 0; i < 4; ++i)
            #pragma unroll
            for (int j = 0; j < 4; ++j)
                acc[i][j] = __builtin_amdgcn_mfma_f32_16x16x32_bf16(af[i], bfr[j], acc[i][j], 0, 0, 0);
        __syncthreads();
    }

    #pragma unroll
    for (int j = 0; j < 4; ++j) {
        const int col = col0 + wc + j*16 + lr;
        const float bs = (col < NREST) ? bias[map_rest(col)] : 0.f;
        #pragma unroll
        for (int i = 0; i < 4; ++i) {
            const int rowb = row0 + wr + i*16 + lq;
            #pragma unroll
            for (int r = 0; r < 4; ++r)
                C[(size_t)(rowb + r) * NRESTP + col] = acc[i][j][r] + bs;
        }
    }
}

// ---------------- bf16 MFMA GEMM (output projection) ----------------
__global__ __launch_bounds__(256) void gemm_mfma_f32out(
    const __hip_bfloat16* __restrict__ A,
    const __hip_bfloat16* __restrict__ Bm,
    const float* __restrict__ bias,
    float* __restrict__ C,
    int M, int N, int K)
{
    __shared__ __align__(16) __hip_bfloat16 As[128][40];
    __shared__ __align__(16) __hip_bfloat16 Bs[128][40];

    const int tid  = threadIdx.x;
    const int wave = tid >> 6;
    const int lane = tid & 63;
    const int row0 = blockIdx.y * 128;
    const int col0 = blockIdx.x * 128;

    const int wr = (wave >> 1) * 64;
    const int wc = (wave & 1) * 64;
    const int lr = lane & 15;
    const int lk = (lane >> 4) * 8;
    const int lq = (lane >> 4) * 4;

    const int srow = tid >> 2;
    const int skk  = (tid & 3) * 8;

    f32x4 acc[4][4] = {};

    for (int k0 = 0; k0 < K; k0 += 32) {
        #pragma unroll
        for (int j = 0; j < 2; ++j) {
            const int r = j * 64 + srow;
            bf16x8 va = *reinterpret_cast<const bf16x8*>(A  + (size_t)(row0 + r) * K + k0 + skk);
            bf16x8 vb = *reinterpret_cast<const bf16x8*>(Bm + (size_t)(col0 + r) * K + k0 + skk);
            *reinterpret_cast<bf16x8*>(&As[r][skk]) = va;
            *reinterpret_cast<bf16x8*>(&Bs[r][skk]) = vb;
        }
        __syncthreads();

        bf16x8 af[4], bfr[4];
        #pragma unroll
        for (int i = 0; i < 4; ++i)
            af[i] = *reinterpret_cast<const bf16x8*>(&As[wr + i*16 + lr][lk]);
        #pragma unroll
        for (int j = 0; j < 4; ++j)
            bfr[j] = *reinterpret_cast<const bf16x8*>(&Bs[wc + j*16 + lr][lk]);
        #pragma unroll
        for (int i = 0; i < 4; ++i)
            #pragma unroll
            for (int j = 0; j < 4; ++j)
                acc[i][j] = __builtin_amdgcn_mfma_f32_16x16x32_bf16(af[i], bfr[j], acc[i][j], 0, 0, 0);
        __syncthreads();
    }

    #pragma unroll
    for (int j = 0; j < 4; ++j) {
        const int col = col0 + wc + j*16 + lr;
        const float bs = bias[col];
        #pragma unroll
        for (int i = 0; i < 4; ++i) {
            const int rowb = row0 + wr + i*16 + lq;
            #pragma unroll
            for (int r = 0; r < 4; ++r)
                C[(size_t)(rowb + r) * N + col] = acc[i][j][r] + bs;
        }
    }
}

// ---------------- recurrent scan: 512 thr (wave=head), 4-step unroll ----------------
struct PF {
    float k[4], q[4], v[4], bt[4], g[4], tm[4];
    float4 p1[4], p2[4], p3[4];
};

__global__ __launch_bounds__(512, 1)
void agalite_scan(const float* __restrict__ pc,      // (T*B, 1088) crit f32
                  const float* __restrict__ pr,      // (T*B, 1664) rest f32
                  const int*   __restrict__ term,
                  const float* __restrict__ tick_in,
                  const float* __restrict__ fk_prev,
                  const float* __restrict__ fv_prev,
                  const float* __restrict__ fs_prev,
                  __hip_bfloat16* __restrict__ attn, // (T*B, 512) bf16
                  float* __restrict__ out_fk,
                  float* __restrict__ out_fv,
                  float* __restrict__ out_fs,
                  float* __restrict__ out_tick)
{
    const int b    = blockIdx.x;
    const int tid  = threadIdx.x;
    const int w    = tid >> 6;     // head
    const int lane = tid & 63;     // d
    const int f0   = lane << 2;

    __shared__ float red[2][4][8][4];
    __shared__ __align__(16) float cos_s[T_LEN][4];

    const float tick_b = tick_in[b];
    {
        const int t = tid >> 2, r = tid & 3;
        const float PI_F = 3.14159265358979323846f;
        const float omega[4] = {-PI_F, -PI_F/3.0f, PI_F/3.0f, PI_F};
        cos_s[t][r] = cosf(((float)(t + 1) + tick_b) * omega[r]);
    }

    float fk[R_N][4], fsv[4], fv[R_N];
    #pragma unroll
    for (int r = 0; r < R_N; ++r) {
        const float4 kk = *(const float4*)(fk_prev + (((size_t)b * R_N + r) * H_N + w) * FD_N + f0);
        fk[r][0] = kk.x; fk[r][1] = kk.y; fk[r][2] = kk.z; fk[r][3] = kk.w;
        fv[r] = fv_prev[(((size_t)b * R_N + r) * H_N + w) * DH_N + lane];
    }
    {
        const float4 ss = *(const float4*)(fs_prev + ((size_t)b * H_N + w) * FD_N + f0);
        fsv[0] = ss.x; fsv[1] = ss.y; fsv[2] = ss.z; fsv[3] = ss.w;
    }

    auto prefetch = [&](PF& dst, int t0) {
        #pragma unroll
        for (int s = 0; s < 4; ++s) {
            int t = t0 + s; t = (t < T_LEN) ? t : T_LEN - 1;
            const float* Pc = pc + (size_t)(t * B_SZ + b) * NCRIT;
            const float* Pr = pr + (size_t)(t * B_SZ + b) * NRESTP;
            dst.k[s]  = Pc[w*64 + lane];
            dst.q[s]  = Pc[512 + w*64 + lane];
            dst.p1[s] = *(const float4*)(Pc + 1024 + w*4);
            dst.p2[s] = *(const float4*)(Pc + 1056 + w*4);
            dst.v[s]  = Pr[w*64 + lane];
            dst.bt[s] = Pr[512 + w*64 + lane];
            dst.g[s]  = Pr[1024 + w*64 + lane];
            dst.p3[s] = *(const float4*)(Pr + 1536 + w*4);
            dst.tm[s] = (float)term[t * B_SZ + b];
        }
    };

    auto round_body = [&](const PF& cur, int t0, int P) {
        float sc[4][4], nr[4], fvs[4][4];
        #pragma unroll
        for (int s = 0; s < 4; ++s) {
            const float mask = 1.f - cur.tm[s];
            const float4 cs = *(const float4*)&cos_s[t0 + s][0];
            const float cosr[4] = {cs.x, cs.y, cs.z, cs.w};
            const float rk = fmaxf(cur.k[s], 0.f);
            const float rq = fmaxf(cur.q[s], 0.f);
            const float sg = sigmoidf_(cur.g[s]);
            const float p1v[4] = {cur.p1[s].x, cur.p1[s].y, cur.p1[s].z, cur.p1[s].w};
            const float p2v[4] = {cur.p2[s].x, cur.p2[s].y, cur.p2[s].z, cur.p2[s].w};
            const float p3v[4] = {cur.p3[s].x, cur.p3[s].y, cur.p3[s].z, cur.p3[s].w};
            float phi[4], kg[4], dgv[4];
            float np = 0.f;
            #pragma unroll
            for (int e = 0; e < 4; ++e) {
                const float psi = rk * fmaxf(p1v[e], 0.f);
                phi[e] = rq * fmaxf(p2v[e], 0.f);
                const float gf = sg * sigmoidf_(p3v[e]);
                kg[e] = psi * gf;
                dgv[e] = (1.f - gf) * mask;
                fsv[e] = dgv[e] * fsv[e] + kg[e];
                np += fsv[e] * phi[e];
            }
            nr[s] = np;
            #pragma unroll
            for (int r = 0; r < R_N; ++r) {
                float ss = 0.f;
                #pragma unroll
                for (int e = 0; e < 4; ++e) {
                    fk[r][e] = dgv[e] * fk[r][e] + kg[e] * cosr[r];
                    ss += fk[r][e] * phi[e];
                }
                sc[s][r] = ss;
            }
            const float bb = sigmoidf_(cur.bt[s]);
            const float vg = cur.v[s] * bb;
            const float db = (1.f - bb) * mask;
            #pragma unroll
            for (int r = 0; r < R_N; ++r) { fv[r] = db * fv[r] + vg * cosr[r]; fvs[s][r] = fv[r]; }
        }
        // batched butterfly: 20 independent values, pipelined through the DS pipe
        #pragma unroll
        for (int off = 32; off >= 1; off >>= 1) {
            #pragma unroll
            for (int s = 0; s < 4; ++s) {
                #pragma unroll
                for (int r = 0; r < 4; ++r) sc[s][r] += __shfl_xor(sc[s][r], off);
                nr[s] += __shfl_xor(nr[s], off);
            }
        }
        if (lane == 0) {
            #pragma unroll
            for (int s = 0; s < 4; ++s)
                *(float4*)&red[P][s][w][0] = make_float4(sc[s][0], sc[s][1], sc[s][2], sc[s][3]);
        }
        __syncthreads();
        #pragma unroll
        for (int s = 0; s < 4; ++s) {
            float s0 = 0.f, s1 = 0.f, s2 = 0.f, s3 = 0.f;
            #pragma unroll
            for (int ww = 0; ww < 8; ++ww) {
                const float4 rv = *(const float4*)&red[P][s][ww][0];
                s0 += rv.x; s1 += rv.y; s2 += rv.z; s3 += rv.w;
            }
            const float kv = fvs[s][0]*s0 + fvs[s][1]*s1 + fvs[s][2]*s2 + fvs[s][3]*s3;
            attn[((size_t)(t0 + s) * B_SZ + b) * (H_N * DH_N) + tid] =
                __float2bfloat16(kv / (2.0f * R_N * nr[s] + EPS_F));
        }
    };

    PF A, B;
    prefetch(A, 0);
    __syncthreads();   // cos table ready

    for (int t0 = 0; t0 < T_LEN; t0 += 8) {
        prefetch(B, t0 + 4);
        round_body(A, t0, 0);
        prefetch(A, t0 + 8);
        round_body(B, t0 + 4, 1);
    }

    #pragma unroll
    for (int r = 0; r < R_N; ++r) {
        float* p = out_fk + (((size_t)b * R_N + r) * H_N + w) * FD_N + f0;
        *(float4*)p = make_float4(fk[r][0], fk[r][1], fk[r][2], fk[r][3]);
        out_fv[(((size_t)b * R_N + r) * H_N + w) * DH_N + lane] = fv[r];
    }
    {
        float* p = out_fs + ((size_t)b * H_N + w) * FD_N + f0;
        *(float4*)p = make_float4(fsv[0], fsv[1], fsv[2], fsv[3]);
    }
    if (tid == 0) out_tick[b] = tick_b + (float)T_LEN;
}

extern "C" void kernel_launch(void* const* d_in, const int* in_sizes, int n_in,
                              void* d_out, int out_size, void* d_ws, size_t ws_size,
                              hipStream_t stream)
{
    const float* inputs  = (const float*)d_in[0];
    const int*   term    = (const int*)  d_in[1];
    const float* fk_prev = (const float*)d_in[2];
    const float* fv_prev = (const float*)d_in[3];
    const float* fs_prev = (const float*)d_in[4];
    const float* tick    = (const float*)d_in[5];
    const float* Wf      = (const float*)d_in[6];
    const float* bf      = (const float*)d_in[7];
    const float* Wp      = (const float*)d_in[8];
    const float* bp      = (const float*)d_in[9];

    float* out      = (float*)d_out;
    float* out_fk   = out    + (size_t)T_LEN * B_SZ * DMODEL;
    float* out_fv   = out_fk + (size_t)B_SZ * R_N * H_N * FD_N;
    float* out_fs   = out_fv + (size_t)B_SZ * R_N * H_N * DH_N;
    float* out_tick = out_fs + (size_t)B_SZ * H_N * FD_N;

    char* ws = (char*)d_ws;
    float* proj_crit = (float*)ws;                       // 4096*1088*4 = 17.8 MB
    ws += (size_t)T_LEN * B_SZ * NCRIT * 4;
    float* proj_rest = (float*)ws;                       // 4096*1664*4 = 27.3 MB
    ws += (size_t)T_LEN * B_SZ * NRESTP * 4;
    __hip_bfloat16* attn_bf = (__hip_bfloat16*)ws;       // 4096*512*2 = 4.2 MB
    ws += (size_t)T_LEN * B_SZ * H_N * DH_N * 2;
    __hip_bfloat16* Wp_bf = (__hip_bfloat16*)ws;         // 1024*512*2 = 1 MB
    ws += (size_t)DMODEL * H_N * DH_N * 2;

    cvt_bf16<<<512, 256, 0, stream>>>(Wp, Wp_bf, DMODEL * H_N * DH_N);

    // 1a) crit columns (k,q,p1,p2) in f32
    gemm_f32_crit<<<dim3(NCRIT / 64, (T_LEN * B_SZ) / 128), dim3(256), 0, stream>>>(
        inputs, Wf, bf, proj_crit);

    // 1b) rest columns (v,beta,gamma,p3) via bf16 MFMA
    gemm_mfma_rest<<<dim3(NRESTP / 128, (T_LEN * B_SZ) / 128), dim3(256), 0, stream>>>(
        inputs, Wf, bf, proj_rest);

    // 2) recurrent scan + attention
    agalite_scan<<<dim3(B_SZ), dim3(512), 0, stream>>>(
        proj_crit, proj_rest, term, tick, fk_prev, fv_prev, fs_prev,
        attn_bf, out_fk, out_fv, out_fs, out_tick);

    // 3) out = attn @ Wp^T + bp
    gemm_mfma_f32out<<<dim3(DMODEL / 128, (T_LEN * B_SZ) / 128), dim3(256), 0, stream>>>(
        attn_bf, Wp_bf, bp, out, T_LEN * B_SZ, DMODEL, H_N * DH_N);
}

// Round 6
// 397.691 us; speedup vs baseline: 2.2231x; 1.2570x over previous
//
#include <hip/hip_runtime.h>
#include <hip/hip_bf16.h>
#include <math.h>

#define T_LEN  128
#define B_SZ   32
#define DMODEL 1024
#define H_N    8
#define DH_N   64
#define FD_N   256
#define R_N    4
#define PROJ_N 2656
#define NCRIT  1088
#define NREST  1568
#define NRESTP 1664
#define EPS_F  1e-6f
#define CH     8      // time chunks
#define CL     16     // chunk length (CH*CL == T_LEN)

typedef __attribute__((ext_vector_type(8))) short bf16x8;
typedef __attribute__((ext_vector_type(4))) float f32x4;

__device__ __forceinline__ float sigmoidf_(float x) { return 1.0f / (1.0f + __expf(-x)); }

// column maps: crit j -> Wf row.  crit layout: [k 8x64][q 8x64][p1 8x4][p2 8x4]
__device__ __forceinline__ int map_crit(int j) {
    if (j < 512)  return (j >> 6) * 320 + (j & 63);                                  // k
    if (j < 1024) { int t = j - 512;  return (t >> 6) * 320 + 64 + (t & 63); }       // q
    if (j < 1056) { int t = j - 1024; return 2560 + (t >> 2) * 12 + (t & 3); }       // p1
    { int t = j - 1056; return 2560 + (t >> 2) * 12 + 4 + (t & 3); }                 // p2
}
// rest layout: [v 8x64][beta 8x64][gamma 8x64][p3 8x4]  (j < 1568)
__device__ __forceinline__ int map_rest(int j) {
    if (j < 512)  return (j >> 6) * 320 + 128 + (j & 63);                            // v
    if (j < 1024) { int t = j - 512;  return (t >> 6) * 320 + 192 + (t & 63); }      // beta
    if (j < 1536) { int t = j - 1024; return (t >> 6) * 320 + 256 + (t & 63); }      // gamma
    { int t = j - 1536; return 2560 + (t >> 2) * 12 + 8 + (t & 3); }                 // p3
}

__device__ __forceinline__ bf16x8 pack8(float4 u, float4 v) {
    union { bf16x8 v8; __hip_bfloat16 h[8]; } x;
    x.h[0] = __float2bfloat16(u.x); x.h[1] = __float2bfloat16(u.y);
    x.h[2] = __float2bfloat16(u.z); x.h[3] = __float2bfloat16(u.w);
    x.h[4] = __float2bfloat16(v.x); x.h[5] = __float2bfloat16(v.y);
    x.h[6] = __float2bfloat16(v.z); x.h[7] = __float2bfloat16(v.w);
    return x.v8;
}

__global__ void cvt_bf16(const float* __restrict__ src, __hip_bfloat16* __restrict__ dst, int n)
{
    int i = (blockIdx.x * blockDim.x + threadIdx.x) * 4;
    const int stride = gridDim.x * blockDim.x * 4;
    for (; i < n; i += stride) {
        float4 v = *(const float4*)(src + i);
        dst[i + 0] = __float2bfloat16(v.x);
        dst[i + 1] = __float2bfloat16(v.y);
        dst[i + 2] = __float2bfloat16(v.z);
        dst[i + 3] = __float2bfloat16(v.w);
    }
}

// ---------------- f32 GEMM, precision-critical columns ----------------
__global__ __launch_bounds__(256) void gemm_f32_crit(
    const float* __restrict__ A, const float* __restrict__ Wf,
    const float* __restrict__ bias, float* __restrict__ C)
{
    __shared__ __align__(16) float As[32][132];
    __shared__ __align__(16) float Bs[32][68];

    const int tid = threadIdx.x;
    const int tx = tid & 15;
    const int ty = tid >> 4;
    const int row0 = blockIdx.y * 128;
    const int col0 = blockIdx.x * 64;

    const int sar = tid >> 1;
    const int sak = (tid & 1) * 16;
    const float* aptr = A + (size_t)(row0 + sar) * 1024 + sak;
    const int sbr = tid >> 2;
    const int sbk = (tid & 3) * 8;
    const float* bptr = Wf + (size_t)map_crit(col0 + sbr) * 1024 + sbk;

    float acc[8][4] = {};

    float4 a0 = *(const float4*)(aptr + 0);
    float4 a1 = *(const float4*)(aptr + 4);
    float4 a2 = *(const float4*)(aptr + 8);
    float4 a3 = *(const float4*)(aptr + 12);
    float4 b0 = *(const float4*)(bptr + 0);
    float4 b1 = *(const float4*)(bptr + 4);

    for (int k0 = 0; k0 < 1024; k0 += 32) {
        As[sak+ 0][sar] = a0.x; As[sak+ 1][sar] = a0.y; As[sak+ 2][sar] = a0.z; As[sak+ 3][sar] = a0.w;
        As[sak+ 4][sar] = a1.x; As[sak+ 5][sar] = a1.y; As[sak+ 6][sar] = a1.z; As[sak+ 7][sar] = a1.w;
        As[sak+ 8][sar] = a2.x; As[sak+ 9][sar] = a2.y; As[sak+10][sar] = a2.z; As[sak+11][sar] = a2.w;
        As[sak+12][sar] = a3.x; As[sak+13][sar] = a3.y; As[sak+14][sar] = a3.z; As[sak+15][sar] = a3.w;
        Bs[sbk+0][sbr] = b0.x; Bs[sbk+1][sbr] = b0.y; Bs[sbk+2][sbr] = b0.z; Bs[sbk+3][sbr] = b0.w;
        Bs[sbk+4][sbr] = b1.x; Bs[sbk+5][sbr] = b1.y; Bs[sbk+6][sbr] = b1.z; Bs[sbk+7][sbr] = b1.w;
        __syncthreads();

        if (k0 + 32 < 1024) {
            a0 = *(const float4*)(aptr + k0 + 32);
            a1 = *(const float4*)(aptr + k0 + 36);
            a2 = *(const float4*)(aptr + k0 + 40);
            a3 = *(const float4*)(aptr + k0 + 44);
            b0 = *(const float4*)(bptr + k0 + 32);
            b1 = *(const float4*)(bptr + k0 + 36);
        }

        #pragma unroll
        for (int kk = 0; kk < 32; ++kk) {
            const float4 va0 = *(const float4*)&As[kk][ty*4];
            const float4 va1 = *(const float4*)&As[kk][ty*4+64];
            const float4 vb  = *(const float4*)&Bs[kk][tx*4];
            const float am[8] = {va0.x,va0.y,va0.z,va0.w, va1.x,va1.y,va1.z,va1.w};
            const float bn[4] = {vb.x,vb.y,vb.z,vb.w};
            #pragma unroll
            for (int mi = 0; mi < 8; ++mi)
                #pragma unroll
                for (int nj = 0; nj < 4; ++nj)
                    acc[mi][nj] += am[mi] * bn[nj];
        }
        __syncthreads();
    }

    float bsv[4];
    #pragma unroll
    for (int nj = 0; nj < 4; ++nj) bsv[nj] = bias[map_crit(col0 + tx*4 + nj)];
    #pragma unroll
    for (int mi = 0; mi < 8; ++mi) {
        const int r = row0 + ty*4 + ((mi < 4) ? mi : 64 + (mi - 4));
        #pragma unroll
        for (int nj = 0; nj < 4; ++nj)
            C[(size_t)r * NCRIT + col0 + tx*4 + nj] = acc[mi][nj] + bsv[nj];
    }
}

// ---------------- bf16 MFMA GEMM, rest columns ----------------
__global__ __launch_bounds__(256) void gemm_mfma_rest(
    const float* __restrict__ A, const float* __restrict__ Wf,
    const float* __restrict__ bias, float* __restrict__ C)
{
    __shared__ __align__(16) __hip_bfloat16 As[128][40];
    __shared__ __align__(16) __hip_bfloat16 Bs[128][40];

    const int tid  = threadIdx.x;
    const int wave = tid >> 6;
    const int lane = tid & 63;
    const int row0 = blockIdx.y * 128;
    const int col0 = blockIdx.x * 128;

    const int wr = (wave >> 1) * 64;
    const int wc = (wave & 1) * 64;
    const int lr = lane & 15;
    const int lk = (lane >> 4) * 8;
    const int lq = (lane >> 4) * 4;

    const int srow = tid >> 2;
    const int skk  = (tid & 3) * 8;

    const float* aP0 = A + (size_t)(row0 + srow) * 1024 + skk;
    const float* aP1 = aP0 + (size_t)64 * 1024;
    const int br0 = col0 + srow, br1 = br0 + 64;
    const bool ok0 = br0 < NREST, ok1 = br1 < NREST;
    const float* bP0 = Wf + (size_t)(ok0 ? map_rest(br0) : 0) * 1024 + skk;
    const float* bP1 = Wf + (size_t)(ok1 ? map_rest(br1) : 0) * 1024 + skk;

    f32x4 acc[4][4] = {};
    const float4 z = make_float4(0.f, 0.f, 0.f, 0.f);

    for (int k0 = 0; k0 < 1024; k0 += 32) {
        float4 a00 = *(const float4*)(aP0 + k0), a01 = *(const float4*)(aP0 + k0 + 4);
        float4 a10 = *(const float4*)(aP1 + k0), a11 = *(const float4*)(aP1 + k0 + 4);
        float4 b00 = ok0 ? *(const float4*)(bP0 + k0) : z, b01 = ok0 ? *(const float4*)(bP0 + k0 + 4) : z;
        float4 b10 = ok1 ? *(const float4*)(bP1 + k0) : z, b11 = ok1 ? *(const float4*)(bP1 + k0 + 4) : z;
        *reinterpret_cast<bf16x8*>(&As[srow][skk])    = pack8(a00, a01);
        *reinterpret_cast<bf16x8*>(&As[srow+64][skk]) = pack8(a10, a11);
        *reinterpret_cast<bf16x8*>(&Bs[srow][skk])    = pack8(b00, b01);
        *reinterpret_cast<bf16x8*>(&Bs[srow+64][skk]) = pack8(b10, b11);
        __syncthreads();

        bf16x8 af[4], bfr[4];
        #pragma unroll
        for (int i = 0; i < 4; ++i)
            af[i] = *reinterpret_cast<const bf16x8*>(&As[wr + i*16 + lr][lk]);
        #pragma unroll
        for (int j = 0; j < 4; ++j)
            bfr[j] = *reinterpret_cast<const bf16x8*>(&Bs[wc + j*16 + lr][lk]);
        #pragma unroll
        for (int i = 0; i < 4; ++i)
            #pragma unroll
            for (int j = 0; j < 4; ++j)
                acc[i][j] = __builtin_amdgcn_mfma_f32_16x16x32_bf16(af[i], bfr[j], acc[i][j], 0, 0, 0);
        __syncthreads();
    }

    #pragma unroll
    for (int j = 0; j < 4; ++j) {
        const int col = col0 + wc + j*16 + lr;
        const float bs = (col < NREST) ? bias[map_rest(col)] : 0.f;
        #pragma unroll
        for (int i = 0; i < 4; ++i) {
            const int rowb = row0 + wr + i*16 + lq;
            #pragma unroll
            for (int r = 0; r < 4; ++r)
                C[(size_t)(rowb + r) * NRESTP + col] = acc[i][j][r] + bs;
        }
    }
}

// ---------------- bf16 MFMA GEMM (output projection) ----------------
__global__ __launch_bounds__(256) void gemm_mfma_f32out(
    const __hip_bfloat16* __restrict__ A,
    const __hip_bfloat16* __restrict__ Bm,
    const float* __restrict__ bias,
    float* __restrict__ C,
    int M, int N, int K)
{
    __shared__ __align__(16) __hip_bfloat16 As[128][40];
    __shared__ __align__(16) __hip_bfloat16 Bs[128][40];

    const int tid  = threadIdx.x;
    const int wave = tid >> 6;
    const int lane = tid & 63;
    const int row0 = blockIdx.y * 128;
    const int col0 = blockIdx.x * 128;

    const int wr = (wave >> 1) * 64;
    const int wc = (wave & 1) * 64;
    const int lr = lane & 15;
    const int lk = (lane >> 4) * 8;
    const int lq = (lane >> 4) * 4;

    const int srow = tid >> 2;
    const int skk  = (tid & 3) * 8;

    f32x4 acc[4][4] = {};

    for (int k0 = 0; k0 < K; k0 += 32) {
        #pragma unroll
        for (int j = 0; j < 2; ++j) {
            const int r = j * 64 + srow;
            bf16x8 va = *reinterpret_cast<const bf16x8*>(A  + (size_t)(row0 + r) * K + k0 + skk);
            bf16x8 vb = *reinterpret_cast<const bf16x8*>(Bm + (size_t)(col0 + r) * K + k0 + skk);
            *reinterpret_cast<bf16x8*>(&As[r][skk]) = va;
            *reinterpret_cast<bf16x8*>(&Bs[r][skk]) = vb;
        }
        __syncthreads();

        bf16x8 af[4], bfr[4];
        #pragma unroll
        for (int i = 0; i < 4; ++i)
            af[i] = *reinterpret_cast<const bf16x8*>(&As[wr + i*16 + lr][lk]);
        #pragma unroll
        for (int j = 0; j < 4; ++j)
            bfr[j] = *reinterpret_cast<const bf16x8*>(&Bs[wc + j*16 + lr][lk]);
        #pragma unroll
        for (int i = 0; i < 4; ++i)
            #pragma unroll
            for (int j = 0; j < 4; ++j)
                acc[i][j] = __builtin_amdgcn_mfma_f32_16x16x32_bf16(af[i], bfr[j], acc[i][j], 0, 0, 0);
        __syncthreads();
    }

    #pragma unroll
    for (int j = 0; j < 4; ++j) {
        const int col = col0 + wc + j*16 + lr;
        const float bs = bias[col];
        #pragma unroll
        for (int i = 0; i < 4; ++i) {
            const int rowb = row0 + wr + i*16 + lq;
            #pragma unroll
            for (int r = 0; r < 4; ++r)
                C[(size_t)(rowb + r) * N + col] = acc[i][j][r] + bs;
        }
    }
}

// ============ parallel scan: pass A (chunk-local S,P), B (combine), C (emit) ============
// Feature mapping (all passes): wave w = head, lane = d, e = 0..3 -> f = 4*lane+e.
// SPk per (b,c,lane): [0..15] Sk[r][e] (r-major float4 of e), [16..19] Pd[e], [20..23] Ss[e].
// Pass B overwrites those slots with carry-in: fk[r][e], (stale), fs[e]; SPv4 with fv[r].

__global__ __launch_bounds__(512, 1)
void scan_passA(const float* __restrict__ pc, const float* __restrict__ pr,
                const int* __restrict__ term, const float* __restrict__ tick_in,
                float* __restrict__ SPk, float* __restrict__ SPv4, float* __restrict__ SPv1)
{
    const int b = blockIdx.x, c = blockIdx.y;
    const int tid = threadIdx.x, w = tid >> 6, lane = tid & 63;
    const int t0 = c * CL;

    __shared__ __align__(16) float cos_s[CL][4];
    const float tick_b = tick_in[b];
    if (tid < CL * 4) {
        const int lt = tid >> 2, r = tid & 3;
        const float PI_F = 3.14159265358979323846f;
        const float omega[4] = {-PI_F, -PI_F/3.0f, PI_F/3.0f, PI_F};
        cos_s[lt][r] = cosf(((float)(t0 + lt + 1) + tick_b) * omega[r]);
    }
    __syncthreads();

    float Sk[4][4] = {}, Ss[4] = {}, Sv[4] = {};
    float Pd[4] = {1.f, 1.f, 1.f, 1.f};
    float Pv = 1.f;

    float ck, cv, cbt, cg, ctm; float4 cp1, cp3;
    auto loadA = [&](int lt, float& k, float& v, float& bt, float& g,
                     float4& p1, float4& p3, float& tm) {
        const int t = t0 + ((lt < CL) ? lt : CL - 1);
        const float* Pc = pc + (size_t)(t * B_SZ + b) * NCRIT;
        const float* Pr = pr + (size_t)(t * B_SZ + b) * NRESTP;
        k  = Pc[w*64 + lane];
        p1 = *(const float4*)(Pc + 1024 + w*4);
        v  = Pr[w*64 + lane];
        bt = Pr[512 + w*64 + lane];
        g  = Pr[1024 + w*64 + lane];
        p3 = *(const float4*)(Pr + 1536 + w*4);
        tm = (float)term[t * B_SZ + b];
    };
    loadA(0, ck, cv, cbt, cg, cp1, cp3, ctm);

    for (int lt = 0; lt < CL; ++lt) {
        float nk, nv, nbt, ng, ntm; float4 np1, np3;
        loadA(lt + 1, nk, nv, nbt, ng, np1, np3, ntm);

        const float mask = 1.f - ctm;
        const float4 cs4 = *(const float4*)&cos_s[lt][0];
        const float cosr[4] = {cs4.x, cs4.y, cs4.z, cs4.w};
        const float rk = fmaxf(ck, 0.f);
        const float sg = sigmoidf_(cg);
        const float p1v[4] = {cp1.x, cp1.y, cp1.z, cp1.w};
        const float p3v[4] = {cp3.x, cp3.y, cp3.z, cp3.w};

        #pragma unroll
        for (int e = 0; e < 4; ++e) {
            const float psi = rk * fmaxf(p1v[e], 0.f);
            const float gf  = sg * sigmoidf_(p3v[e]);
            const float kg  = psi * gf;
            const float dg  = (1.f - gf) * mask;
            #pragma unroll
            for (int r = 0; r < 4; ++r)
                Sk[r][e] = dg * Sk[r][e] + kg * cosr[r];
            Ss[e] = dg * Ss[e] + kg;
            Pd[e] *= dg;
        }
        const float bb = sigmoidf_(cbt);
        const float vg = cv * bb;
        const float db = (1.f - bb) * mask;
        #pragma unroll
        for (int r = 0; r < 4; ++r) Sv[r] = db * Sv[r] + vg * cosr[r];
        Pv *= db;

        ck = nk; cv = nv; cbt = nbt; cg = ng; cp1 = np1; cp3 = np3; ctm = ntm;
    }

    float* K = SPk + ((size_t)(b * CH + c) * 512 + tid) * 24;
    #pragma unroll
    for (int r = 0; r < 4; ++r)
        *(float4*)(K + r*4) = make_float4(Sk[r][0], Sk[r][1], Sk[r][2], Sk[r][3]);
    *(float4*)(K + 16) = make_float4(Pd[0], Pd[1], Pd[2], Pd[3]);
    *(float4*)(K + 20) = make_float4(Ss[0], Ss[1], Ss[2], Ss[3]);
    *(float4*)(SPv4 + ((size_t)(b * CH + c) * 512 + tid) * 4) =
        make_float4(Sv[0], Sv[1], Sv[2], Sv[3]);
    SPv1[(size_t)(b * CH + c) * 512 + tid] = Pv;
}

__global__ __launch_bounds__(512, 1)
void scan_passB(float* __restrict__ SPk, float* __restrict__ SPv4,
                const float* __restrict__ SPv1,
                const float* __restrict__ fk_prev, const float* __restrict__ fv_prev,
                const float* __restrict__ fs_prev, const float* __restrict__ tick_in,
                float* __restrict__ out_fk, float* __restrict__ out_fv,
                float* __restrict__ out_fs, float* __restrict__ out_tick)
{
    const int b = blockIdx.x;
    const int tid = threadIdx.x, w = tid >> 6, lane = tid & 63;
    const int f0 = lane << 2;

    float yk[4][4], ys[4], yv[4];
    #pragma unroll
    for (int r = 0; r < 4; ++r) {
        const float4 kk = *(const float4*)(fk_prev + (((size_t)b * R_N + r) * H_N + w) * FD_N + f0);
        yk[r][0] = kk.x; yk[r][1] = kk.y; yk[r][2] = kk.z; yk[r][3] = kk.w;
        yv[r] = fv_prev[(((size_t)b * R_N + r) * H_N + w) * DH_N + lane];
    }
    {
        const float4 ss = *(const float4*)(fs_prev + ((size_t)b * H_N + w) * FD_N + f0);
        ys[0] = ss.x; ys[1] = ss.y; ys[2] = ss.z; ys[3] = ss.w;
    }

    for (int c = 0; c < CH; ++c) {
        float* K = SPk + ((size_t)(b * CH + c) * 512 + tid) * 24;
        float4 S0 = *(float4*)(K + 0),  S1 = *(float4*)(K + 4);
        float4 S2 = *(float4*)(K + 8),  S3 = *(float4*)(K + 12);
        float4 P4 = *(float4*)(K + 16), Q4 = *(float4*)(K + 20);
        float* V = SPv4 + ((size_t)(b * CH + c) * 512 + tid) * 4;
        float4 Sv4 = *(float4*)V;
        const float Pv = SPv1[(size_t)(b * CH + c) * 512 + tid];

        // write carry-in (state BEFORE this chunk) over the S slots
        *(float4*)(K + 0)  = make_float4(yk[0][0], yk[0][1], yk[0][2], yk[0][3]);
        *(float4*)(K + 4)  = make_float4(yk[1][0], yk[1][1], yk[1][2], yk[1][3]);
        *(float4*)(K + 8)  = make_float4(yk[2][0], yk[2][1], yk[2][2], yk[2][3]);
        *(float4*)(K + 12) = make_float4(yk[3][0], yk[3][1], yk[3][2], yk[3][3]);
        *(float4*)(K + 20) = make_float4(ys[0], ys[1], ys[2], ys[3]);
        *(float4*)V        = make_float4(yv[0], yv[1], yv[2], yv[3]);

        const float S[4][4] = {{S0.x,S0.y,S0.z,S0.w}, {S1.x,S1.y,S1.z,S1.w},
                               {S2.x,S2.y,S2.z,S2.w}, {S3.x,S3.y,S3.z,S3.w}};
        const float Pd[4] = {P4.x, P4.y, P4.z, P4.w};
        const float Ssv[4] = {Q4.x, Q4.y, Q4.z, Q4.w};
        const float Svv[4] = {Sv4.x, Sv4.y, Sv4.z, Sv4.w};
        #pragma unroll
        for (int e = 0; e < 4; ++e) {
            #pragma unroll
            for (int r = 0; r < 4; ++r)
                yk[r][e] = S[r][e] + Pd[e] * yk[r][e];
            ys[e] = Ssv[e] + Pd[e] * ys[e];
        }
        #pragma unroll
        for (int r = 0; r < 4; ++r)
            yv[r] = Svv[r] + Pv * yv[r];
    }

    #pragma unroll
    for (int r = 0; r < 4; ++r) {
        *(float4*)(out_fk + (((size_t)b * R_N + r) * H_N + w) * FD_N + f0) =
            make_float4(yk[r][0], yk[r][1], yk[r][2], yk[r][3]);
        out_fv[(((size_t)b * R_N + r) * H_N + w) * DH_N + lane] = yv[r];
    }
    *(float4*)(out_fs + ((size_t)b * H_N + w) * FD_N + f0) =
        make_float4(ys[0], ys[1], ys[2], ys[3]);
    if (tid == 0) out_tick[b] = tick_in[b] + (float)T_LEN;
}

struct PF {
    float k[4], q[4], v[4], bt[4], g[4], tm[4];
    float4 p1[4], p2[4], p3[4];
};

__global__ __launch_bounds__(512, 1)
void scan_passC(const float* __restrict__ pc, const float* __restrict__ pr,
                const int* __restrict__ term, const float* __restrict__ tick_in,
                const float* __restrict__ SPk, const float* __restrict__ SPv4,
                __hip_bfloat16* __restrict__ attn)
{
    const int b = blockIdx.x, c = blockIdx.y;
    const int tid = threadIdx.x, w = tid >> 6, lane = tid & 63;
    const int tc0 = c * CL;

    __shared__ float red[2][4][8][4];
    __shared__ __align__(16) float cos_s[CL][4];

    const float tick_b = tick_in[b];
    if (tid < CL * 4) {
        const int lt = tid >> 2, r = tid & 3;
        const float PI_F = 3.14159265358979323846f;
        const float omega[4] = {-PI_F, -PI_F/3.0f, PI_F/3.0f, PI_F};
        cos_s[lt][r] = cosf(((float)(tc0 + lt + 1) + tick_b) * omega[r]);
    }

    // carry-in state for this chunk
    float fk[4][4], fsv[4], fv[4];
    {
        const float* K = SPk + ((size_t)(b * CH + c) * 512 + tid) * 24;
        #pragma unroll
        for (int r = 0; r < 4; ++r) {
            const float4 kk = *(const float4*)(K + r*4);
            fk[r][0] = kk.x; fk[r][1] = kk.y; fk[r][2] = kk.z; fk[r][3] = kk.w;
        }
        const float4 s4 = *(const float4*)(K + 20);
        fsv[0] = s4.x; fsv[1] = s4.y; fsv[2] = s4.z; fsv[3] = s4.w;
        const float4 v4 = *(const float4*)(SPv4 + ((size_t)(b * CH + c) * 512 + tid) * 4);
        fv[0] = v4.x; fv[1] = v4.y; fv[2] = v4.z; fv[3] = v4.w;
    }

    auto prefetch = [&](PF& dst, int lt0) {
        #pragma unroll
        for (int s = 0; s < 4; ++s) {
            int lt = lt0 + s; lt = (lt < CL) ? lt : CL - 1;
            const int t = tc0 + lt;
            const float* Pc = pc + (size_t)(t * B_SZ + b) * NCRIT;
            const float* Pr = pr + (size_t)(t * B_SZ + b) * NRESTP;
            dst.k[s]  = Pc[w*64 + lane];
            dst.q[s]  = Pc[512 + w*64 + lane];
            dst.p1[s] = *(const float4*)(Pc + 1024 + w*4);
            dst.p2[s] = *(const float4*)(Pc + 1056 + w*4);
            dst.v[s]  = Pr[w*64 + lane];
            dst.bt[s] = Pr[512 + w*64 + lane];
            dst.g[s]  = Pr[1024 + w*64 + lane];
            dst.p3[s] = *(const float4*)(Pr + 1536 + w*4);
            dst.tm[s] = (float)term[t * B_SZ + b];
        }
    };

    auto round_body = [&](const PF& cur, int lt0, int P) {
        float sc[4][4], nr[4], fvs[4][4];
        #pragma unroll
        for (int s = 0; s < 4; ++s) {
            const float mask = 1.f - cur.tm[s];
            const float4 cs = *(const float4*)&cos_s[lt0 + s][0];
            const float cosr[4] = {cs.x, cs.y, cs.z, cs.w};
            const float rk = fmaxf(cur.k[s], 0.f);
            const float rq = fmaxf(cur.q[s], 0.f);
            const float sg = sigmoidf_(cur.g[s]);
            const float p1v[4] = {cur.p1[s].x, cur.p1[s].y, cur.p1[s].z, cur.p1[s].w};
            const float p2v[4] = {cur.p2[s].x, cur.p2[s].y, cur.p2[s].z, cur.p2[s].w};
            const float p3v[4] = {cur.p3[s].x, cur.p3[s].y, cur.p3[s].z, cur.p3[s].w};
            float phi[4], kg[4], dgv[4];
            float np = 0.f;
            #pragma unroll
            for (int e = 0; e < 4; ++e) {
                const float psi = rk * fmaxf(p1v[e], 0.f);
                phi[e] = rq * fmaxf(p2v[e], 0.f);
                const float gf = sg * sigmoidf_(p3v[e]);
                kg[e] = psi * gf;
                dgv[e] = (1.f - gf) * mask;
                fsv[e] = dgv[e] * fsv[e] + kg[e];
                np += fsv[e] * phi[e];
            }
            nr[s] = np;
            #pragma unroll
            for (int r = 0; r < R_N; ++r) {
                float ss = 0.f;
                #pragma unroll
                for (int e = 0; e < 4; ++e) {
                    fk[r][e] = dgv[e] * fk[r][e] + kg[e] * cosr[r];
                    ss += fk[r][e] * phi[e];
                }
                sc[s][r] = ss;
            }
            const float bb = sigmoidf_(cur.bt[s]);
            const float vg = cur.v[s] * bb;
            const float db = (1.f - bb) * mask;
            #pragma unroll
            for (int r = 0; r < R_N; ++r) { fv[r] = db * fv[r] + vg * cosr[r]; fvs[s][r] = fv[r]; }
        }
        #pragma unroll
        for (int off = 32; off >= 1; off >>= 1) {
            #pragma unroll
            for (int s = 0; s < 4; ++s) {
                #pragma unroll
                for (int r = 0; r < 4; ++r) sc[s][r] += __shfl_xor(sc[s][r], off);
                nr[s] += __shfl_xor(nr[s], off);
            }
        }
        if (lane == 0) {
            #pragma unroll
            for (int s = 0; s < 4; ++s)
                *(float4*)&red[P][s][w][0] = make_float4(sc[s][0], sc[s][1], sc[s][2], sc[s][3]);
        }
        __syncthreads();
        #pragma unroll
        for (int s = 0; s < 4; ++s) {
            float s0 = 0.f, s1 = 0.f, s2 = 0.f, s3 = 0.f;
            #pragma unroll
            for (int ww = 0; ww < 8; ++ww) {
                const float4 rv = *(const float4*)&red[P][s][ww][0];
                s0 += rv.x; s1 += rv.y; s2 += rv.z; s3 += rv.w;
            }
            const float kv = fvs[s][0]*s0 + fvs[s][1]*s1 + fvs[s][2]*s2 + fvs[s][3]*s3;
            attn[((size_t)(tc0 + lt0 + s) * B_SZ + b) * (H_N * DH_N) + tid] =
                __float2bfloat16(kv / (2.0f * R_N * nr[s] + EPS_F));
        }
    };

    PF Abuf, Bbuf;
    prefetch(Abuf, 0);
    __syncthreads();   // cos table (and carry loads) ready

    for (int lt0 = 0; lt0 < CL; lt0 += 8) {
        prefetch(Bbuf, lt0 + 4);
        round_body(Abuf, lt0, 0);
        prefetch(Abuf, lt0 + 8);
        round_body(Bbuf, lt0 + 4, 1);
    }
}

extern "C" void kernel_launch(void* const* d_in, const int* in_sizes, int n_in,
                              void* d_out, int out_size, void* d_ws, size_t ws_size,
                              hipStream_t stream)
{
    const float* inputs  = (const float*)d_in[0];
    const int*   term    = (const int*)  d_in[1];
    const float* fk_prev = (const float*)d_in[2];
    const float* fv_prev = (const float*)d_in[3];
    const float* fs_prev = (const float*)d_in[4];
    const float* tick    = (const float*)d_in[5];
    const float* Wf      = (const float*)d_in[6];
    const float* bf      = (const float*)d_in[7];
    const float* Wp      = (const float*)d_in[8];
    const float* bp      = (const float*)d_in[9];

    float* out      = (float*)d_out;
    float* out_fk   = out    + (size_t)T_LEN * B_SZ * DMODEL;
    float* out_fv   = out_fk + (size_t)B_SZ * R_N * H_N * FD_N;
    float* out_fs   = out_fv + (size_t)B_SZ * R_N * H_N * DH_N;
    float* out_tick = out_fs + (size_t)B_SZ * H_N * FD_N;

    char* ws = (char*)d_ws;
    float* proj_crit = (float*)ws;                       // 17.8 MB
    ws += (size_t)T_LEN * B_SZ * NCRIT * 4;
    float* proj_rest = (float*)ws;                       // 27.3 MB
    ws += (size_t)T_LEN * B_SZ * NRESTP * 4;
    __hip_bfloat16* attn_bf = (__hip_bfloat16*)ws;       // 4.2 MB
    ws += (size_t)T_LEN * B_SZ * H_N * DH_N * 2;
    __hip_bfloat16* Wp_bf = (__hip_bfloat16*)ws;         // 1 MB
    ws += (size_t)DMODEL * H_N * DH_N * 2;
    float* SPk = (float*)ws;                             // 32*8*512*24*4 = 12.6 MB
    ws += (size_t)B_SZ * CH * 512 * 24 * 4;
    float* SPv4 = (float*)ws;                            // 2.1 MB
    ws += (size_t)B_SZ * CH * 512 * 4 * 4;
    float* SPv1 = (float*)ws;                            // 0.5 MB
    ws += (size_t)B_SZ * CH * 512 * 4;

    cvt_bf16<<<512, 256, 0, stream>>>(Wp, Wp_bf, DMODEL * H_N * DH_N);

    // 1a) crit columns (k,q,p1,p2) in f32
    gemm_f32_crit<<<dim3(NCRIT / 64, (T_LEN * B_SZ) / 128), dim3(256), 0, stream>>>(
        inputs, Wf, bf, proj_crit);

    // 1b) rest columns (v,beta,gamma,p3) via bf16 MFMA
    gemm_mfma_rest<<<dim3(NRESTP / 128, (T_LEN * B_SZ) / 128), dim3(256), 0, stream>>>(
        inputs, Wf, bf, proj_rest);

    // 2) parallel scan: chunk-local S/P -> carry combine -> emit attn
    scan_passA<<<dim3(B_SZ, CH), dim3(512), 0, stream>>>(
        proj_crit, proj_rest, term, tick, SPk, SPv4, SPv1);
    scan_passB<<<dim3(B_SZ), dim3(512), 0, stream>>>(
        SPk, SPv4, SPv1, fk_prev, fv_prev, fs_prev, tick,
        out_fk, out_fv, out_fs, out_tick);
    scan_passC<<<dim3(B_SZ, CH), dim3(512), 0, stream>>>(
        proj_crit, proj_rest, term, tick, SPk, SPv4, attn_bf);

    // 3) out = attn @ Wp^T + bp
    gemm_mfma_f32out<<<dim3(DMODEL / 128, (T_LEN * B_SZ) / 128), dim3(256), 0, stream>>>(
        attn_bf, Wp_bf, bp, out, T_LEN * B_SZ, DMODEL, H_N * DH_N);
}

// Round 8
// 393.033 us; speedup vs baseline: 2.2494x; 1.0119x over previous
//
#include <hip/hip_runtime.h>
#include <hip/hip_bf16.h>
#include <math.h>

#define T_LEN  128
#define B_SZ   32
#define DMODEL 1024
#define H_N    8
#define DH_N   64
#define FD_N   256
#define R_N    4
#define PROJ_N 2656
#define NCRIT  1088
#define NREST  1568
#define NRESTP 1664
#define EPS_F  1e-6f
#define CH     8      // time chunks
#define CL     16     // chunk length (CH*CL == T_LEN)

typedef __attribute__((ext_vector_type(8))) short bf16x8;
typedef __attribute__((ext_vector_type(4))) float f32x4;

__device__ __forceinline__ float sigmoidf_(float x) { return 1.0f / (1.0f + __expf(-x)); }

// column maps: crit j -> Wf row.  crit layout: [k 8x64][q 8x64][p1 8x4][p2 8x4]
__device__ __forceinline__ int map_crit(int j) {
    if (j < 512)  return (j >> 6) * 320 + (j & 63);                                  // k
    if (j < 1024) { int t = j - 512;  return (t >> 6) * 320 + 64 + (t & 63); }       // q
    if (j < 1056) { int t = j - 1024; return 2560 + (t >> 2) * 12 + (t & 3); }       // p1
    { int t = j - 1056; return 2560 + (t >> 2) * 12 + 4 + (t & 3); }                 // p2
}
// rest layout: [v 8x64][beta 8x64][gamma 8x64][p3 8x4]  (j < 1568)
__device__ __forceinline__ int map_rest(int j) {
    if (j < 512)  return (j >> 6) * 320 + 128 + (j & 63);                            // v
    if (j < 1024) { int t = j - 512;  return (t >> 6) * 320 + 192 + (t & 63); }      // beta
    if (j < 1536) { int t = j - 1024; return (t >> 6) * 320 + 256 + (t & 63); }      // gamma
    { int t = j - 1536; return 2560 + (t >> 2) * 12 + 8 + (t & 3); }                 // p3
}

__device__ __forceinline__ bf16x8 pack8(float4 u, float4 v) {
    union { bf16x8 v8; __hip_bfloat16 h[8]; } x;
    x.h[0] = __float2bfloat16(u.x); x.h[1] = __float2bfloat16(u.y);
    x.h[2] = __float2bfloat16(u.z); x.h[3] = __float2bfloat16(u.w);
    x.h[4] = __float2bfloat16(v.x); x.h[5] = __float2bfloat16(v.y);
    x.h[6] = __float2bfloat16(v.z); x.h[7] = __float2bfloat16(v.w);
    return x.v8;
}

__global__ void cvt_bf16(const float* __restrict__ src, __hip_bfloat16* __restrict__ dst, int n)
{
    int i = (blockIdx.x * blockDim.x + threadIdx.x) * 4;
    const int stride = gridDim.x * blockDim.x * 4;
    for (; i < n; i += stride) {
        float4 v = *(const float4*)(src + i);
        dst[i + 0] = __float2bfloat16(v.x);
        dst[i + 1] = __float2bfloat16(v.y);
        dst[i + 2] = __float2bfloat16(v.z);
        dst[i + 3] = __float2bfloat16(v.w);
    }
}

// ---------------- f32 GEMM, precision-critical columns ----------------
// 64x64 tile, BK=32, 256 threads, 4x4 micro-tile. Grid 17x64 = 1088 blocks
// (~4.25/CU) for latency hiding; A-reads are 16-lane broadcasts, B-reads 2-way.
__global__ __launch_bounds__(256) void gemm_f32_crit(
    const float* __restrict__ A, const float* __restrict__ Wf,
    const float* __restrict__ bias, float* __restrict__ C)
{
    __shared__ __align__(16) float As[32][68];   // [k][m], 16B-aligned rows
    __shared__ __align__(16) float Bs[32][68];

    const int tid = threadIdx.x;
    const int tx = tid & 15;
    const int ty = tid >> 4;
    const int row0 = blockIdx.y * 64;
    const int col0 = blockIdx.x * 64;

    const int srow = tid >> 2;         // 0..63
    const int skk  = (tid & 3) * 8;    // 0,8,16,24

    const float* aptr = A + (size_t)(row0 + srow) * 1024 + skk;
    const float* bptr = Wf + (size_t)map_crit(col0 + srow) * 1024 + skk;

    float acc[4][4] = {};

    float4 a0 = *(const float4*)(aptr);
    float4 a1 = *(const float4*)(aptr + 4);
    float4 b0 = *(const float4*)(bptr);
    float4 b1 = *(const float4*)(bptr + 4);

    for (int k0 = 0; k0 < 1024; k0 += 32) {
        As[skk+0][srow] = a0.x; As[skk+1][srow] = a0.y;
        As[skk+2][srow] = a0.z; As[skk+3][srow] = a0.w;
        As[skk+4][srow] = a1.x; As[skk+5][srow] = a1.y;
        As[skk+6][srow] = a1.z; As[skk+7][srow] = a1.w;
        Bs[skk+0][srow] = b0.x; Bs[skk+1][srow] = b0.y;
        Bs[skk+2][srow] = b0.z; Bs[skk+3][srow] = b0.w;
        Bs[skk+4][srow] = b1.x; Bs[skk+5][srow] = b1.y;
        Bs[skk+6][srow] = b1.z; Bs[skk+7][srow] = b1.w;
        __syncthreads();

        if (k0 + 32 < 1024) {
            a0 = *(const float4*)(aptr + k0 + 32);
            a1 = *(const float4*)(aptr + k0 + 36);
            b0 = *(const float4*)(bptr + k0 + 32);
            b1 = *(const float4*)(bptr + k0 + 36);
        }

        #pragma unroll
        for (int kk = 0; kk < 32; ++kk) {
            const float4 va = *(const float4*)&As[kk][ty*4];
            const float4 vb = *(const float4*)&Bs[kk][tx*4];
            const float am[4] = {va.x, va.y, va.z, va.w};
            const float bn[4] = {vb.x, vb.y, vb.z, vb.w};
            #pragma unroll
            for (int mi = 0; mi < 4; ++mi)
                #pragma unroll
                for (int nj = 0; nj < 4; ++nj)
                    acc[mi][nj] += am[mi] * bn[nj];
        }
        __syncthreads();
    }

    float bsv[4];
    #pragma unroll
    for (int nj = 0; nj < 4; ++nj) bsv[nj] = bias[map_crit(col0 + tx*4 + nj)];
    #pragma unroll
    for (int mi = 0; mi < 4; ++mi) {
        const int r = row0 + ty*4 + mi;
        #pragma unroll
        for (int nj = 0; nj < 4; ++nj)
            C[(size_t)r * NCRIT + col0 + tx*4 + nj] = acc[mi][nj] + bsv[nj];
    }
}

// ---------------- bf16 MFMA GEMM, rest columns ----------------
__global__ __launch_bounds__(256) void gemm_mfma_rest(
    const float* __restrict__ A, const float* __restrict__ Wf,
    const float* __restrict__ bias, float* __restrict__ C)
{
    __shared__ __align__(16) __hip_bfloat16 As[128][40];
    __shared__ __align__(16) __hip_bfloat16 Bs[128][40];

    const int tid  = threadIdx.x;
    const int wave = tid >> 6;
    const int lane = tid & 63;
    const int row0 = blockIdx.y * 128;
    const int col0 = blockIdx.x * 128;

    const int wr = (wave >> 1) * 64;
    const int wc = (wave & 1) * 64;
    const int lr = lane & 15;
    const int lk = (lane >> 4) * 8;
    const int lq = (lane >> 4) * 4;

    const int srow = tid >> 2;
    const int skk  = (tid & 3) * 8;

    const float* aP0 = A + (size_t)(row0 + srow) * 1024 + skk;
    const float* aP1 = aP0 + (size_t)64 * 1024;
    const int br0 = col0 + srow, br1 = br0 + 64;
    const bool ok0 = br0 < NREST, ok1 = br1 < NREST;
    const float* bP0 = Wf + (size_t)(ok0 ? map_rest(br0) : 0) * 1024 + skk;
    const float* bP1 = Wf + (size_t)(ok1 ? map_rest(br1) : 0) * 1024 + skk;

    f32x4 acc[4][4] = {};
    const float4 z = make_float4(0.f, 0.f, 0.f, 0.f);

    for (int k0 = 0; k0 < 1024; k0 += 32) {
        float4 a00 = *(const float4*)(aP0 + k0), a01 = *(const float4*)(aP0 + k0 + 4);
        float4 a10 = *(const float4*)(aP1 + k0), a11 = *(const float4*)(aP1 + k0 + 4);
        float4 b00 = ok0 ? *(const float4*)(bP0 + k0) : z, b01 = ok0 ? *(const float4*)(bP0 + k0 + 4) : z;
        float4 b10 = ok1 ? *(const float4*)(bP1 + k0) : z, b11 = ok1 ? *(const float4*)(bP1 + k0 + 4) : z;
        *reinterpret_cast<bf16x8*>(&As[srow][skk])    = pack8(a00, a01);
        *reinterpret_cast<bf16x8*>(&As[srow+64][skk]) = pack8(a10, a11);
        *reinterpret_cast<bf16x8*>(&Bs[srow][skk])    = pack8(b00, b01);
        *reinterpret_cast<bf16x8*>(&Bs[srow+64][skk]) = pack8(b10, b11);
        __syncthreads();

        bf16x8 af[4], bfr[4];
        #pragma unroll
        for (int i = 0; i < 4; ++i)
            af[i] = *reinterpret_cast<const bf16x8*>(&As[wr + i*16 + lr][lk]);
        #pragma unroll
        for (int j = 0; j < 4; ++j)
            bfr[j] = *reinterpret_cast<const bf16x8*>(&Bs[wc + j*16 + lr][lk]);
        #pragma unroll
        for (int i = 0; i < 4; ++i)
            #pragma unroll
            for (int j = 0; j < 4; ++j)
                acc[i][j] = __builtin_amdgcn_mfma_f32_16x16x32_bf16(af[i], bfr[j], acc[i][j], 0, 0, 0);
        __syncthreads();
    }

    #pragma unroll
    for (int j = 0; j < 4; ++j) {
        const int col = col0 + wc + j*16 + lr;
        const float bs = (col < NREST) ? bias[map_rest(col)] : 0.f;
        #pragma unroll
        for (int i = 0; i < 4; ++i) {
            const int rowb = row0 + wr + i*16 + lq;
            #pragma unroll
            for (int r = 0; r < 4; ++r)
                C[(size_t)(rowb + r) * NRESTP + col] = acc[i][j][r] + bs;
        }
    }
}

// ---------------- bf16 MFMA GEMM (output projection) ----------------
__global__ __launch_bounds__(256) void gemm_mfma_f32out(
    const __hip_bfloat16* __restrict__ A,
    const __hip_bfloat16* __restrict__ Bm,
    const float* __restrict__ bias,
    float* __restrict__ C,
    int M, int N, int K)
{
    __shared__ __align__(16) __hip_bfloat16 As[128][40];
    __shared__ __align__(16) __hip_bfloat16 Bs[128][40];

    const int tid  = threadIdx.x;
    const int wave = tid >> 6;
    const int lane = tid & 63;
    const int row0 = blockIdx.y * 128;
    const int col0 = blockIdx.x * 128;

    const int wr = (wave >> 1) * 64;
    const int wc = (wave & 1) * 64;
    const int lr = lane & 15;
    const int lk = (lane >> 4) * 8;
    const int lq = (lane >> 4) * 4;

    const int srow = tid >> 2;
    const int skk  = (tid & 3) * 8;

    f32x4 acc[4][4] = {};

    for (int k0 = 0; k0 < K; k0 += 32) {
        #pragma unroll
        for (int j = 0; j < 2; ++j) {
            const int r = j * 64 + srow;
            bf16x8 va = *reinterpret_cast<const bf16x8*>(A  + (size_t)(row0 + r) * K + k0 + skk);
            bf16x8 vb = *reinterpret_cast<const bf16x8*>(Bm + (size_t)(col0 + r) * K + k0 + skk);
            *reinterpret_cast<bf16x8*>(&As[r][skk]) = va;
            *reinterpret_cast<bf16x8*>(&Bs[r][skk]) = vb;
        }
        __syncthreads();

        bf16x8 af[4], bfr[4];
        #pragma unroll
        for (int i = 0; i < 4; ++i)
            af[i] = *reinterpret_cast<const bf16x8*>(&As[wr + i*16 + lr][lk]);
        #pragma unroll
        for (int j = 0; j < 4; ++j)
            bfr[j] = *reinterpret_cast<const bf16x8*>(&Bs[wc + j*16 + lr][lk]);
        #pragma unroll
        for (int i = 0; i < 4; ++i)
            #pragma unroll
            for (int j = 0; j < 4; ++j)
                acc[i][j] = __builtin_amdgcn_mfma_f32_16x16x32_bf16(af[i], bfr[j], acc[i][j], 0, 0, 0);
        __syncthreads();
    }

    #pragma unroll
    for (int j = 0; j < 4; ++j) {
        const int col = col0 + wc + j*16 + lr;
        const float bs = bias[col];
        #pragma unroll
        for (int i = 0; i < 4; ++i) {
            const int rowb = row0 + wr + i*16 + lq;
            #pragma unroll
            for (int r = 0; r < 4; ++r)
                C[(size_t)(rowb + r) * N + col] = acc[i][j][r] + bs;
        }
    }
}

// ============ parallel scan: pass A (chunk-local S,P), B (combine), C (emit) ============
__global__ __launch_bounds__(512, 1)
void scan_passA(const float* __restrict__ pc, const float* __restrict__ pr,
                const int* __restrict__ term, const float* __restrict__ tick_in,
                float* __restrict__ SPk, float* __restrict__ SPv4, float* __restrict__ SPv1)
{
    const int b = blockIdx.x, c = blockIdx.y;
    const int tid = threadIdx.x, w = tid >> 6, lane = tid & 63;
    const int t0 = c * CL;

    __shared__ __align__(16) float cos_s[CL][4];
    const float tick_b = tick_in[b];
    if (tid < CL * 4) {
        const int lt = tid >> 2, r = tid & 3;
        const float PI_F = 3.14159265358979323846f;
        const float omega[4] = {-PI_F, -PI_F/3.0f, PI_F/3.0f, PI_F};
        cos_s[lt][r] = cosf(((float)(t0 + lt + 1) + tick_b) * omega[r]);
    }
    __syncthreads();

    float Sk[4][4] = {}, Ss[4] = {}, Sv[4] = {};
    float Pd[4] = {1.f, 1.f, 1.f, 1.f};
    float Pv = 1.f;

    float ck, cv, cbt, cg, ctm; float4 cp1, cp3;
    auto loadA = [&](int lt, float& k, float& v, float& bt, float& g,
                     float4& p1, float4& p3, float& tm) {
        const int t = t0 + ((lt < CL) ? lt : CL - 1);
        const float* Pc = pc + (size_t)(t * B_SZ + b) * NCRIT;
        const float* Pr = pr + (size_t)(t * B_SZ + b) * NRESTP;
        k  = Pc[w*64 + lane];
        p1 = *(const float4*)(Pc + 1024 + w*4);
        v  = Pr[w*64 + lane];
        bt = Pr[512 + w*64 + lane];
        g  = Pr[1024 + w*64 + lane];
        p3 = *(const float4*)(Pr + 1536 + w*4);
        tm = (float)term[t * B_SZ + b];
    };
    loadA(0, ck, cv, cbt, cg, cp1, cp3, ctm);

    for (int lt = 0; lt < CL; ++lt) {
        float nk, nv, nbt, ng, ntm; float4 np1, np3;
        loadA(lt + 1, nk, nv, nbt, ng, np1, np3, ntm);

        const float mask = 1.f - ctm;
        const float4 cs4 = *(const float4*)&cos_s[lt][0];
        const float cosr[4] = {cs4.x, cs4.y, cs4.z, cs4.w};
        const float rk = fmaxf(ck, 0.f);
        const float sg = sigmoidf_(cg);
        const float p1v[4] = {cp1.x, cp1.y, cp1.z, cp1.w};
        const float p3v[4] = {cp3.x, cp3.y, cp3.z, cp3.w};

        #pragma unroll
        for (int e = 0; e < 4; ++e) {
            const float psi = rk * fmaxf(p1v[e], 0.f);
            const float gf  = sg * sigmoidf_(p3v[e]);
            const float kg  = psi * gf;
            const float dg  = (1.f - gf) * mask;
            #pragma unroll
            for (int r = 0; r < 4; ++r)
                Sk[r][e] = dg * Sk[r][e] + kg * cosr[r];
            Ss[e] = dg * Ss[e] + kg;
            Pd[e] *= dg;
        }
        const float bb = sigmoidf_(cbt);
        const float vg = cv * bb;
        const float db = (1.f - bb) * mask;
        #pragma unroll
        for (int r = 0; r < 4; ++r) Sv[r] = db * Sv[r] + vg * cosr[r];
        Pv *= db;

        ck = nk; cv = nv; cbt = nbt; cg = ng; cp1 = np1; cp3 = np3; ctm = ntm;
    }

    float* K = SPk + ((size_t)(b * CH + c) * 512 + tid) * 24;
    #pragma unroll
    for (int r = 0; r < 4; ++r)
        *(float4*)(K + r*4) = make_float4(Sk[r][0], Sk[r][1], Sk[r][2], Sk[r][3]);
    *(float4*)(K + 16) = make_float4(Pd[0], Pd[1], Pd[2], Pd[3]);
    *(float4*)(K + 20) = make_float4(Ss[0], Ss[1], Ss[2], Ss[3]);
    *(float4*)(SPv4 + ((size_t)(b * CH + c) * 512 + tid) * 4) =
        make_float4(Sv[0], Sv[1], Sv[2], Sv[3]);
    SPv1[(size_t)(b * CH + c) * 512 + tid] = Pv;
}

__global__ __launch_bounds__(512, 1)
void scan_passB(float* __restrict__ SPk, float* __restrict__ SPv4,
                const float* __restrict__ SPv1,
                const float* __restrict__ fk_prev, const float* __restrict__ fv_prev,
                const float* __restrict__ fs_prev, const float* __restrict__ tick_in,
                float* __restrict__ out_fk, float* __restrict__ out_fv,
                float* __restrict__ out_fs, float* __restrict__ out_tick)
{
    const int b = blockIdx.x;
    const int tid = threadIdx.x, w = tid >> 6, lane = tid & 63;
    const int f0 = lane << 2;

    float yk[4][4], ys[4], yv[4];
    #pragma unroll
    for (int r = 0; r < 4; ++r) {
        const float4 kk = *(const float4*)(fk_prev + (((size_t)b * R_N + r) * H_N + w) * FD_N + f0);
        yk[r][0] = kk.x; yk[r][1] = kk.y; yk[r][2] = kk.z; yk[r][3] = kk.w;
        yv[r] = fv_prev[(((size_t)b * R_N + r) * H_N + w) * DH_N + lane];
    }
    {
        const float4 ss = *(const float4*)(fs_prev + ((size_t)b * H_N + w) * FD_N + f0);
        ys[0] = ss.x; ys[1] = ss.y; ys[2] = ss.z; ys[3] = ss.w;
    }

    for (int c = 0; c < CH; ++c) {
        float* K = SPk + ((size_t)(b * CH + c) * 512 + tid) * 24;
        float4 S0 = *(float4*)(K + 0),  S1 = *(float4*)(K + 4);
        float4 S2 = *(float4*)(K + 8),  S3 = *(float4*)(K + 12);
        float4 P4 = *(float4*)(K + 16), Q4 = *(float4*)(K + 20);
        float* V = SPv4 + ((size_t)(b * CH + c) * 512 + tid) * 4;
        float4 Sv4 = *(float4*)V;
        const float Pv = SPv1[(size_t)(b * CH + c) * 512 + tid];

        *(float4*)(K + 0)  = make_float4(yk[0][0], yk[0][1], yk[0][2], yk[0][3]);
        *(float4*)(K + 4)  = make_float4(yk[1][0], yk[1][1], yk[1][2], yk[1][3]);
        *(float4*)(K + 8)  = make_float4(yk[2][0], yk[2][1], yk[2][2], yk[2][3]);
        *(float4*)(K + 12) = make_float4(yk[3][0], yk[3][1], yk[3][2], yk[3][3]);
        *(float4*)(K + 20) = make_float4(ys[0], ys[1], ys[2], ys[3]);
        *(float4*)V        = make_float4(yv[0], yv[1], yv[2], yv[3]);

        const float S[4][4] = {{S0.x,S0.y,S0.z,S0.w}, {S1.x,S1.y,S1.z,S1.w},
                               {S2.x,S2.y,S2.z,S2.w}, {S3.x,S3.y,S3.z,S3.w}};
        const float Pd[4] = {P4.x, P4.y, P4.z, P4.w};
        const float Ssv[4] = {Q4.x, Q4.y, Q4.z, Q4.w};
        const float Svv[4] = {Sv4.x, Sv4.y, Sv4.z, Sv4.w};
        #pragma unroll
        for (int e = 0; e < 4; ++e) {
            #pragma unroll
            for (int r = 0; r < 4; ++r)
                yk[r][e] = S[r][e] + Pd[e] * yk[r][e];
            ys[e] = Ssv[e] + Pd[e] * ys[e];
        }
        #pragma unroll
        for (int r = 0; r < 4; ++r)
            yv[r] = Svv[r] + Pv * yv[r];
    }

    #pragma unroll
    for (int r = 0; r < 4; ++r) {
        *(float4*)(out_fk + (((size_t)b * R_N + r) * H_N + w) * FD_N + f0) =
            make_float4(yk[r][0], yk[r][1], yk[r][2], yk[r][3]);
        out_fv[(((size_t)b * R_N + r) * H_N + w) * DH_N + lane] = yv[r];
    }
    *(float4*)(out_fs + ((size_t)b * H_N + w) * FD_N + f0) =
        make_float4(ys[0], ys[1], ys[2], ys[3]);
    if (tid == 0) out_tick[b] = tick_in[b] + (float)T_LEN;
}

struct PF {
    float k[4], q[4], v[4], bt[4], g[4], tm[4];
    float4 p1[4], p2[4], p3[4];
};

__global__ __launch_bounds__(512, 1)
void scan_passC(const float* __restrict__ pc, const float* __restrict__ pr,
                const int* __restrict__ term, const float* __restrict__ tick_in,
                const float* __restrict__ SPk, const float* __restrict__ SPv4,
                __hip_bfloat16* __restrict__ attn)
{
    const int b = blockIdx.x, c = blockIdx.y;
    const int tid = threadIdx.x, w = tid >> 6, lane = tid & 63;
    const int tc0 = c * CL;

    __shared__ float red[2][4][8][4];
    __shared__ __align__(16) float cos_s[CL][4];

    const float tick_b = tick_in[b];
    if (tid < CL * 4) {
        const int lt = tid >> 2, r = tid & 3;
        const float PI_F = 3.14159265358979323846f;
        const float omega[4] = {-PI_F, -PI_F/3.0f, PI_F/3.0f, PI_F};
        cos_s[lt][r] = cosf(((float)(tc0 + lt + 1) + tick_b) * omega[r]);
    }

    float fk[4][4], fsv[4], fv[4];
    {
        const float* K = SPk + ((size_t)(b * CH + c) * 512 + tid) * 24;
        #pragma unroll
        for (int r = 0; r < 4; ++r) {
            const float4 kk = *(const float4*)(K + r*4);
            fk[r][0] = kk.x; fk[r][1] = kk.y; fk[r][2] = kk.z; fk[r][3] = kk.w;
        }
        const float4 s4 = *(const float4*)(K + 20);
        fsv[0] = s4.x; fsv[1] = s4.y; fsv[2] = s4.z; fsv[3] = s4.w;
        const float4 v4 = *(const float4*)(SPv4 + ((size_t)(b * CH + c) * 512 + tid) * 4);
        fv[0] = v4.x; fv[1] = v4.y; fv[2] = v4.z; fv[3] = v4.w;
    }

    auto prefetch = [&](PF& dst, int lt0) {
        #pragma unroll
        for (int s = 0; s < 4; ++s) {
            int lt = lt0 + s; lt = (lt < CL) ? lt : CL - 1;
            const int t = tc0 + lt;
            const float* Pc = pc + (size_t)(t * B_SZ + b) * NCRIT;
            const float* Pr = pr + (size_t)(t * B_SZ + b) * NRESTP;
            dst.k[s]  = Pc[w*64 + lane];
            dst.q[s]  = Pc[512 + w*64 + lane];
            dst.p1[s] = *(const float4*)(Pc + 1024 + w*4);
            dst.p2[s] = *(const float4*)(Pc + 1056 + w*4);
            dst.v[s]  = Pr[w*64 + lane];
            dst.bt[s] = Pr[512 + w*64 + lane];
            dst.g[s]  = Pr[1024 + w*64 + lane];
            dst.p3[s] = *(const float4*)(Pr + 1536 + w*4);
            dst.tm[s] = (float)term[t * B_SZ + b];
        }
    };

    auto round_body = [&](const PF& cur, int lt0, int P) {
        float sc[4][4], nr[4], fvs[4][4];
        #pragma unroll
        for (int s = 0; s < 4; ++s) {
            const float mask = 1.f - cur.tm[s];
            const float4 cs = *(const float4*)&cos_s[lt0 + s][0];
            const float cosr[4] = {cs.x, cs.y, cs.z, cs.w};
            const float rk = fmaxf(cur.k[s], 0.f);
            const float rq = fmaxf(cur.q[s], 0.f);
            const float sg = sigmoidf_(cur.g[s]);
            const float p1v[4] = {cur.p1[s].x, cur.p1[s].y, cur.p1[s].z, cur.p1[s].w};
            const float p2v[4] = {cur.p2[s].x, cur.p2[s].y, cur.p2[s].z, cur.p2[s].w};
            const float p3v[4] = {cur.p3[s].x, cur.p3[s].y, cur.p3[s].z, cur.p3[s].w};
            float phi[4], kg[4], dgv[4];
            float np = 0.f;
            #pragma unroll
            for (int e = 0; e < 4; ++e) {
                const float psi = rk * fmaxf(p1v[e], 0.f);
                phi[e] = rq * fmaxf(p2v[e], 0.f);
                const float gf = sg * sigmoidf_(p3v[e]);
                kg[e] = psi * gf;
                dgv[e] = (1.f - gf) * mask;
                fsv[e] = dgv[e] * fsv[e] + kg[e];
                np += fsv[e] * phi[e];
            }
            nr[s] = np;
            #pragma unroll
            for (int r = 0; r < R_N; ++r) {
                float ss = 0.f;
                #pragma unroll
                for (int e = 0; e < 4; ++e) {
                    fk[r][e] = dgv[e] * fk[r][e] + kg[e] * cosr[r];
                    ss += fk[r][e] * phi[e];
                }
                sc[s][r] = ss;
            }
            const float bb = sigmoidf_(cur.bt[s]);
            const float vg = cur.v[s] * bb;
            const float db = (1.f - bb) * mask;
            #pragma unroll
            for (int r = 0; r < R_N; ++r) { fv[r] = db * fv[r] + vg * cosr[r]; fvs[s][r] = fv[r]; }
        }
        #pragma unroll
        for (int off = 32; off >= 1; off >>= 1) {
            #pragma unroll
            for (int s = 0; s < 4; ++s) {
                #pragma unroll
                for (int r = 0; r < 4; ++r) sc[s][r] += __shfl_xor(sc[s][r], off);
                nr[s] += __shfl_xor(nr[s], off);
            }
        }
        if (lane == 0) {
            #pragma unroll
            for (int s = 0; s < 4; ++s)
                *(float4*)&red[P][s][w][0] = make_float4(sc[s][0], sc[s][1], sc[s][2], sc[s][3]);
        }
        __syncthreads();
        #pragma unroll
        for (int s = 0; s < 4; ++s) {
            float s0 = 0.f, s1 = 0.f, s2 = 0.f, s3 = 0.f;
            #pragma unroll
            for (int ww = 0; ww < 8; ++ww) {
                const float4 rv = *(const float4*)&red[P][s][ww][0];
                s0 += rv.x; s1 += rv.y; s2 += rv.z; s3 += rv.w;
            }
            const float kv = fvs[s][0]*s0 + fvs[s][1]*s1 + fvs[s][2]*s2 + fvs[s][3]*s3;
            attn[((size_t)(tc0 + lt0 + s) * B_SZ + b) * (H_N * DH_N) + tid] =
                __float2bfloat16(kv / (2.0f * R_N * nr[s] + EPS_F));
        }
    };

    PF Abuf, Bbuf;
    prefetch(Abuf, 0);
    __syncthreads();

    for (int lt0 = 0; lt0 < CL; lt0 += 8) {
        prefetch(Bbuf, lt0 + 4);
        round_body(Abuf, lt0, 0);
        prefetch(Abuf, lt0 + 8);
        round_body(Bbuf, lt0 + 4, 1);
    }
}

extern "C" void kernel_launch(void* const* d_in, const int* in_sizes, int n_in,
                              void* d_out, int out_size, void* d_ws, size_t ws_size,
                              hipStream_t stream)
{
    const float* inputs  = (const float*)d_in[0];
    const int*   term    = (const int*)  d_in[1];
    const float* fk_prev = (const float*)d_in[2];
    const float* fv_prev = (const float*)d_in[3];
    const float* fs_prev = (const float*)d_in[4];
    const float* tick    = (const float*)d_in[5];
    const float* Wf      = (const float*)d_in[6];
    const float* bf      = (const float*)d_in[7];
    const float* Wp      = (const float*)d_in[8];
    const float* bp      = (const float*)d_in[9];

    float* out      = (float*)d_out;
    float* out_fk   = out    + (size_t)T_LEN * B_SZ * DMODEL;
    float* out_fv   = out_fk + (size_t)B_SZ * R_N * H_N * FD_N;
    float* out_fs   = out_fv + (size_t)B_SZ * R_N * H_N * DH_N;
    float* out_tick = out_fs + (size_t)B_SZ * H_N * FD_N;

    char* ws = (char*)d_ws;
    float* proj_crit = (float*)ws;                       // 17.8 MB
    ws += (size_t)T_LEN * B_SZ * NCRIT * 4;
    float* proj_rest = (float*)ws;                       // 27.3 MB
    ws += (size_t)T_LEN * B_SZ * NRESTP * 4;
    __hip_bfloat16* attn_bf = (__hip_bfloat16*)ws;       // 4.2 MB
    ws += (size_t)T_LEN * B_SZ * H_N * DH_N * 2;
    __hip_bfloat16* Wp_bf = (__hip_bfloat16*)ws;         // 1 MB
    ws += (size_t)DMODEL * H_N * DH_N * 2;
    float* SPk = (float*)ws;                             // 12.6 MB
    ws += (size_t)B_SZ * CH * 512 * 24 * 4;
    float* SPv4 = (float*)ws;                            // 2.1 MB
    ws += (size_t)B_SZ * CH * 512 * 4 * 4;
    float* SPv1 = (float*)ws;                            // 0.5 MB
    ws += (size_t)B_SZ * CH * 512 * 4;

    cvt_bf16<<<512, 256, 0, stream>>>(Wp, Wp_bf, DMODEL * H_N * DH_N);

    // 1a) crit columns (k,q,p1,p2) in f32 — 64x64 tiles, 1088 blocks
    gemm_f32_crit<<<dim3(NCRIT / 64, (T_LEN * B_SZ) / 64), dim3(256), 0, stream>>>(
        inputs, Wf, bf, proj_crit);

    // 1b) rest columns (v,beta,gamma,p3) via bf16 MFMA
    gemm_mfma_rest<<<dim3(NRESTP / 128, (T_LEN * B_SZ) / 128), dim3(256), 0, stream>>>(
        inputs, Wf, bf, proj_rest);

    // 2) parallel scan: chunk-local S/P -> carry combine -> emit attn
    scan_passA<<<dim3(B_SZ, CH), dim3(512), 0, stream>>>(
        proj_crit, proj_rest, term, tick, SPk, SPv4, SPv1);
    scan_passB<<<dim3(B_SZ), dim3(512), 0, stream>>>(
        SPk, SPv4, SPv1, fk_prev, fv_prev, fs_prev, tick,
        out_fk, out_fv, out_fs, out_tick);
    scan_passC<<<dim3(B_SZ, CH), dim3(512), 0, stream>>>(
        proj_crit, proj_rest, term, tick, SPk, SPv4, attn_bf);

    // 3) out = attn @ Wp^T + bp
    gemm_mfma_f32out<<<dim3(DMODEL / 128, (T_LEN * B_SZ) / 128), dim3(256), 0, stream>>>(
        attn_bf, Wp_bf, bp, out, T_LEN * B_SZ, DMODEL, H_N * DH_N);
}

// Round 9
// 383.940 us; speedup vs baseline: 2.3027x; 1.0237x over previous
//
#include <hip/hip_runtime.h>
#include <hip/hip_bf16.h>
#include <math.h>

#define T_LEN  128
#define B_SZ   32
#define DMODEL 1024
#define H_N    8
#define DH_N   64
#define FD_N   256
#define R_N    4
#define PROJ_N 2656
#define NCRIT  1088
#define NSPLIT 1056    // split-f16 cols (k,q,p1); p2 = cols 1056..1087 via f32 kernel
#define NSPLITP 1152   // padded to 64-col tiles
#define NREST  1568
#define NRESTP 1664
#define EPS_F  1e-6f
#define CH     8
#define CL     16

typedef __attribute__((ext_vector_type(8))) short bf16x8;
typedef __attribute__((ext_vector_type(8))) _Float16 f16x8;
typedef __attribute__((ext_vector_type(4))) float f32x4;

#define LO_SCALE 2048.0f
#define W_SCALE  32.0f

__device__ __forceinline__ float sigmoidf_(float x) { return 1.0f / (1.0f + __expf(-x)); }

// crit layout: [k 8x64][q 8x64][p1 8x4][p2 8x4]
__device__ __forceinline__ int map_crit(int j) {
    if (j < 512)  return (j >> 6) * 320 + (j & 63);                                  // k
    if (j < 1024) { int t = j - 512;  return (t >> 6) * 320 + 64 + (t & 63); }       // q
    if (j < 1056) { int t = j - 1024; return 2560 + (t >> 2) * 12 + (t & 3); }       // p1
    { int t = j - 1056; return 2560 + (t >> 2) * 12 + 4 + (t & 3); }                 // p2
}
// rest layout: [v 8x64][beta 8x64][gamma 8x64][p3 8x4]
__device__ __forceinline__ int map_rest(int j) {
    if (j < 512)  return (j >> 6) * 320 + 128 + (j & 63);                            // v
    if (j < 1024) { int t = j - 512;  return (t >> 6) * 320 + 192 + (t & 63); }      // beta
    if (j < 1536) { int t = j - 1024; return (t >> 6) * 320 + 256 + (t & 63); }      // gamma
    { int t = j - 1536; return 2560 + (t >> 2) * 12 + 8 + (t & 3); }                 // p3
}

__device__ __forceinline__ bf16x8 pack8(float4 u, float4 v) {
    union { bf16x8 v8; __hip_bfloat16 h[8]; } x;
    x.h[0] = __float2bfloat16(u.x); x.h[1] = __float2bfloat16(u.y);
    x.h[2] = __float2bfloat16(u.z); x.h[3] = __float2bfloat16(u.w);
    x.h[4] = __float2bfloat16(v.x); x.h[5] = __float2bfloat16(v.y);
    x.h[6] = __float2bfloat16(v.z); x.h[7] = __float2bfloat16(v.w);
    return x.v8;
}

__global__ void cvt_bf16(const float* __restrict__ src, __hip_bfloat16* __restrict__ dst, int n)
{
    int i = (blockIdx.x * blockDim.x + threadIdx.x) * 4;
    const int stride = gridDim.x * blockDim.x * 4;
    for (; i < n; i += stride) {
        float4 v = *(const float4*)(src + i);
        dst[i + 0] = __float2bfloat16(v.x);
        dst[i + 1] = __float2bfloat16(v.y);
        dst[i + 2] = __float2bfloat16(v.z);
        dst[i + 3] = __float2bfloat16(v.w);
    }
}

// split inputs x -> (hi f16, lo f16 scaled by 2048)
__global__ void cvt_split_x(const float* __restrict__ src,
                            _Float16* __restrict__ hi, _Float16* __restrict__ lo, int n)
{
    int i = (blockIdx.x * blockDim.x + threadIdx.x) * 4;
    const int stride = gridDim.x * blockDim.x * 4;
    for (; i < n; i += stride) {
        float4 v = *(const float4*)(src + i);
        const float a[4] = {v.x, v.y, v.z, v.w};
        #pragma unroll
        for (int c = 0; c < 4; ++c) {
            const _Float16 h = (_Float16)a[c];
            hi[i + c] = h;
            lo[i + c] = (_Float16)((a[c] - (float)h) * LO_SCALE);
        }
    }
}

// gather crit Wf rows, scale x32, split -> hi/lo f16
__global__ __launch_bounds__(256) void cvt_split_w(
    const float* __restrict__ Wf, _Float16* __restrict__ hi, _Float16* __restrict__ lo)
{
    const int j = blockIdx.x;            // 0..NSPLITP-1
    const int i = threadIdx.x * 4;
    _Float16* dh = hi + (size_t)j * 1024 + i;
    _Float16* dl = lo + (size_t)j * 1024 + i;
    if (j < NCRIT) {
        const float* src = Wf + (size_t)map_crit(j) * 1024 + i;
        float4 v = *(const float4*)src;
        const float a[4] = {v.x * W_SCALE, v.y * W_SCALE, v.z * W_SCALE, v.w * W_SCALE};
        #pragma unroll
        for (int c = 0; c < 4; ++c) {
            const _Float16 h = (_Float16)a[c];
            dh[c] = h;
            dl[c] = (_Float16)((a[c] - (float)h) * LO_SCALE);
        }
    } else {
        #pragma unroll
        for (int c = 0; c < 4; ++c) { dh[c] = (_Float16)0.f; dl[c] = (_Float16)0.f; }
    }
}

// ---------------- split-f16 MFMA GEMM: crit cols 0..1055 (k,q,p1) ----------------
// C[r*1088 + j] = [acc_hh + (acc_hl + acc_lh)/2048]/32 + bias.  BM=128, BN=64, BK=32.
__global__ __launch_bounds__(256) void gemm_mfma_crit(
    const _Float16* __restrict__ Xh, const _Float16* __restrict__ Xl,
    const _Float16* __restrict__ Wh, const _Float16* __restrict__ Wl,
    const float* __restrict__ bias, float* __restrict__ C)
{
    __shared__ __align__(16) _Float16 Ah[128][40];
    __shared__ __align__(16) _Float16 Al[128][40];
    __shared__ __align__(16) _Float16 Bh[64][40];
    __shared__ __align__(16) _Float16 Bl[64][40];

    const int tid  = threadIdx.x;
    const int wave = tid >> 6;
    const int lane = tid & 63;
    const int row0 = blockIdx.y * 128;
    const int col0 = blockIdx.x * 64;

    const int wr = (wave >> 1) * 64;     // wave rows: 0 or 64
    const int wc = (wave & 1) * 32;      // wave cols: 0 or 32
    const int lr = lane & 15;
    const int lk = (lane >> 4) * 8;
    const int lq = (lane >> 4) * 4;

    const int sar = tid >> 1;            // 0..127
    const int sak = (tid & 1) * 16;      // 0 or 16
    const int sbr = tid >> 2;            // 0..63
    const int sbk = (tid & 3) * 8;       // 0,8,16,24

    const _Float16* xh = Xh + (size_t)(row0 + sar) * 1024 + sak;
    const _Float16* xl = Xl + (size_t)(row0 + sar) * 1024 + sak;
    const _Float16* wh = Wh + (size_t)(col0 + sbr) * 1024 + sbk;
    const _Float16* wl = Wl + (size_t)(col0 + sbr) * 1024 + sbk;

    f32x4 accm[4][2] = {};
    f32x4 accc[4][2] = {};

    for (int k0 = 0; k0 < 1024; k0 += 32) {
        *reinterpret_cast<f16x8*>(&Ah[sar][sak])     = *reinterpret_cast<const f16x8*>(xh + k0);
        *reinterpret_cast<f16x8*>(&Ah[sar][sak + 8]) = *reinterpret_cast<const f16x8*>(xh + k0 + 8);
        *reinterpret_cast<f16x8*>(&Al[sar][sak])     = *reinterpret_cast<const f16x8*>(xl + k0);
        *reinterpret_cast<f16x8*>(&Al[sar][sak + 8]) = *reinterpret_cast<const f16x8*>(xl + k0 + 8);
        *reinterpret_cast<f16x8*>(&Bh[sbr][sbk])     = *reinterpret_cast<const f16x8*>(wh + k0);
        *reinterpret_cast<f16x8*>(&Bl[sbr][sbk])     = *reinterpret_cast<const f16x8*>(wl + k0);
        __syncthreads();

        f16x8 ah[4], al[4], bh[2], bl[2];
        #pragma unroll
        for (int i = 0; i < 4; ++i) {
            ah[i] = *reinterpret_cast<const f16x8*>(&Ah[wr + i*16 + lr][lk]);
            al[i] = *reinterpret_cast<const f16x8*>(&Al[wr + i*16 + lr][lk]);
        }
        #pragma unroll
        for (int j = 0; j < 2; ++j) {
            bh[j] = *reinterpret_cast<const f16x8*>(&Bh[wc + j*16 + lr][lk]);
            bl[j] = *reinterpret_cast<const f16x8*>(&Bl[wc + j*16 + lr][lk]);
        }
        #pragma unroll
        for (int i = 0; i < 4; ++i)
            #pragma unroll
            for (int j = 0; j < 2; ++j) {
                accm[i][j] = __builtin_amdgcn_mfma_f32_16x16x32_f16(ah[i], bh[j], accm[i][j], 0, 0, 0);
                accc[i][j] = __builtin_amdgcn_mfma_f32_16x16x32_f16(ah[i], bl[j], accc[i][j], 0, 0, 0);
                accc[i][j] = __builtin_amdgcn_mfma_f32_16x16x32_f16(al[i], bh[j], accc[i][j], 0, 0, 0);
            }
        __syncthreads();
    }

    #pragma unroll
    for (int j = 0; j < 2; ++j) {
        const int col = col0 + wc + j*16 + lr;
        if (col >= NSPLIT) continue;
        const float bs = bias[map_crit(col)];
        #pragma unroll
        for (int i = 0; i < 4; ++i) {
            const int rowb = row0 + wr + i*16 + lq;
            #pragma unroll
            for (int r = 0; r < 4; ++r) {
                const float v = (accm[i][j][r] + accc[i][j][r] * (1.0f/LO_SCALE)) * (1.0f/W_SCALE) + bs;
                C[(size_t)(rowb + r) * NCRIT + col] = v;
            }
        }
    }
}

// ---------------- tiny f32 GEMM: the 32 p2 columns -> proj_crit[.., 1056..1087] ----------------
__global__ __launch_bounds__(256) void gemm_p2_f32(
    const float* __restrict__ A, const float* __restrict__ Wf,
    const float* __restrict__ bias, float* __restrict__ C)
{
    __shared__ __align__(16) float As[8][1024];
    const int tid = threadIdx.x;
    const int row0 = blockIdx.x * 8;
    #pragma unroll
    for (int i = 0; i < 8; ++i) {
        const int idx = tid + i * 256;
        const int r = idx >> 8, c4 = (idx & 255) << 2;
        *(float4*)&As[r][c4] = *(const float4*)(A + (size_t)(row0 + r) * 1024 + c4);
    }
    __syncthreads();
    const int r = tid >> 5, j = tid & 31;
    const int wfrow = 2560 + (j >> 2) * 12 + 4 + (j & 3);
    const float* W = Wf + (size_t)wfrow * 1024;
    float acc = 0.f;
    #pragma unroll 8
    for (int k = 0; k < 1024; k += 4) {
        const float4 a  = *(const float4*)&As[r][k];
        const float4 w4 = *(const float4*)(W + k);
        acc += a.x*w4.x + a.y*w4.y + a.z*w4.z + a.w*w4.w;
    }
    C[(size_t)(row0 + r) * NCRIT + 1056 + j] = acc + bias[wfrow];
}

// ---------------- bf16 MFMA GEMM, rest columns ----------------
__global__ __launch_bounds__(256) void gemm_mfma_rest(
    const float* __restrict__ A, const float* __restrict__ Wf,
    const float* __restrict__ bias, float* __restrict__ C)
{
    __shared__ __align__(16) __hip_bfloat16 As[128][40];
    __shared__ __align__(16) __hip_bfloat16 Bs[128][40];

    const int tid  = threadIdx.x;
    const int wave = tid >> 6;
    const int lane = tid & 63;
    const int row0 = blockIdx.y * 128;
    const int col0 = blockIdx.x * 128;

    const int wr = (wave >> 1) * 64;
    const int wc = (wave & 1) * 64;
    const int lr = lane & 15;
    const int lk = (lane >> 4) * 8;
    const int lq = (lane >> 4) * 4;

    const int srow = tid >> 2;
    const int skk  = (tid & 3) * 8;

    const float* aP0 = A + (size_t)(row0 + srow) * 1024 + skk;
    const float* aP1 = aP0 + (size_t)64 * 1024;
    const int br0 = col0 + srow, br1 = br0 + 64;
    const bool ok0 = br0 < NREST, ok1 = br1 < NREST;
    const float* bP0 = Wf + (size_t)(ok0 ? map_rest(br0) : 0) * 1024 + skk;
    const float* bP1 = Wf + (size_t)(ok1 ? map_rest(br1) : 0) * 1024 + skk;

    f32x4 acc[4][4] = {};
    const float4 z = make_float4(0.f, 0.f, 0.f, 0.f);

    for (int k0 = 0; k0 < 1024; k0 += 32) {
        float4 a00 = *(const float4*)(aP0 + k0), a01 = *(const float4*)(aP0 + k0 + 4);
        float4 a10 = *(const float4*)(aP1 + k0), a11 = *(const float4*)(aP1 + k0 + 4);
        float4 b00 = ok0 ? *(const float4*)(bP0 + k0) : z, b01 = ok0 ? *(const float4*)(bP0 + k0 + 4) : z;
        float4 b10 = ok1 ? *(const float4*)(bP1 + k0) : z, b11 = ok1 ? *(const float4*)(bP1 + k0 + 4) : z;
        *reinterpret_cast<bf16x8*>(&As[srow][skk])    = pack8(a00, a01);
        *reinterpret_cast<bf16x8*>(&As[srow+64][skk]) = pack8(a10, a11);
        *reinterpret_cast<bf16x8*>(&Bs[srow][skk])    = pack8(b00, b01);
        *reinterpret_cast<bf16x8*>(&Bs[srow+64][skk]) = pack8(b10, b11);
        __syncthreads();

        bf16x8 af[4], bfr[4];
        #pragma unroll
        for (int i = 0; i < 4; ++i)
            af[i] = *reinterpret_cast<const bf16x8*>(&As[wr + i*16 + lr][lk]);
        #pragma unroll
        for (int j = 0; j < 4; ++j)
            bfr[j] = *reinterpret_cast<const bf16x8*>(&Bs[wc + j*16 + lr][lk]);
        #pragma unroll
        for (int i = 0; i < 4; ++i)
            #pragma unroll
            for (int j = 0; j < 4; ++j)
                acc[i][j] = __builtin_amdgcn_mfma_f32_16x16x32_bf16(af[i], bfr[j], acc[i][j], 0, 0, 0);
        __syncthreads();
    }

    #pragma unroll
    for (int j = 0; j < 4; ++j) {
        const int col = col0 + wc + j*16 + lr;
        const float bs = (col < NREST) ? bias[map_rest(col)] : 0.f;
        #pragma unroll
        for (int i = 0; i < 4; ++i) {
            const int rowb = row0 + wr + i*16 + lq;
            #pragma unroll
            for (int r = 0; r < 4; ++r)
                C[(size_t)(rowb + r) * NRESTP + col] = acc[i][j][r] + bs;
        }
    }
}

// ---------------- bf16 MFMA GEMM (output projection) ----------------
__global__ __launch_bounds__(256) void gemm_mfma_f32out(
    const __hip_bfloat16* __restrict__ A,
    const __hip_bfloat16* __restrict__ Bm,
    const float* __restrict__ bias,
    float* __restrict__ C,
    int M, int N, int K)
{
    __shared__ __align__(16) __hip_bfloat16 As[128][40];
    __shared__ __align__(16) __hip_bfloat16 Bs[128][40];

    const int tid  = threadIdx.x;
    const int wave = tid >> 6;
    const int lane = tid & 63;
    const int row0 = blockIdx.y * 128;
    const int col0 = blockIdx.x * 128;

    const int wr = (wave >> 1) * 64;
    const int wc = (wave & 1) * 64;
    const int lr = lane & 15;
    const int lk = (lane >> 4) * 8;
    const int lq = (lane >> 4) * 4;

    const int srow = tid >> 2;
    const int skk  = (tid & 3) * 8;

    f32x4 acc[4][4] = {};

    for (int k0 = 0; k0 < K; k0 += 32) {
        #pragma unroll
        for (int j = 0; j < 2; ++j) {
            const int r = j * 64 + srow;
            bf16x8 va = *reinterpret_cast<const bf16x8*>(A  + (size_t)(row0 + r) * K + k0 + skk);
            bf16x8 vb = *reinterpret_cast<const bf16x8*>(Bm + (size_t)(col0 + r) * K + k0 + skk);
            *reinterpret_cast<bf16x8*>(&As[r][skk]) = va;
            *reinterpret_cast<bf16x8*>(&Bs[r][skk]) = vb;
        }
        __syncthreads();

        bf16x8 af[4], bfr[4];
        #pragma unroll
        for (int i = 0; i < 4; ++i)
            af[i] = *reinterpret_cast<const bf16x8*>(&As[wr + i*16 + lr][lk]);
        #pragma unroll
        for (int j = 0; j < 4; ++j)
            bfr[j] = *reinterpret_cast<const bf16x8*>(&Bs[wc + j*16 + lr][lk]);
        #pragma unroll
        for (int i = 0; i < 4; ++i)
            #pragma unroll
            for (int j = 0; j < 4; ++j)
                acc[i][j] = __builtin_amdgcn_mfma_f32_16x16x32_bf16(af[i], bfr[j], acc[i][j], 0, 0, 0);
        __syncthreads();
    }

    #pragma unroll
    for (int j = 0; j < 4; ++j) {
        const int col = col0 + wc + j*16 + lr;
        const float bs = bias[col];
        #pragma unroll
        for (int i = 0; i < 4; ++i) {
            const int rowb = row0 + wr + i*16 + lq;
            #pragma unroll
            for (int r = 0; r < 4; ++r)
                C[(size_t)(rowb + r) * N + col] = acc[i][j][r] + bs;
        }
    }
}

// ============ parallel scan (unchanged from round 8) ============
__global__ __launch_bounds__(512, 1)
void scan_passA(const float* __restrict__ pc, const float* __restrict__ pr,
                const int* __restrict__ term, const float* __restrict__ tick_in,
                float* __restrict__ SPk, float* __restrict__ SPv4, float* __restrict__ SPv1)
{
    const int b = blockIdx.x, c = blockIdx.y;
    const int tid = threadIdx.x, w = tid >> 6, lane = tid & 63;
    const int t0 = c * CL;

    __shared__ __align__(16) float cos_s[CL][4];
    const float tick_b = tick_in[b];
    if (tid < CL * 4) {
        const int lt = tid >> 2, r = tid & 3;
        const float PI_F = 3.14159265358979323846f;
        const float omega[4] = {-PI_F, -PI_F/3.0f, PI_F/3.0f, PI_F};
        cos_s[lt][r] = cosf(((float)(t0 + lt + 1) + tick_b) * omega[r]);
    }
    __syncthreads();

    float Sk[4][4] = {}, Ss[4] = {}, Sv[4] = {};
    float Pd[4] = {1.f, 1.f, 1.f, 1.f};
    float Pv = 1.f;

    float ck, cv, cbt, cg, ctm; float4 cp1, cp3;
    auto loadA = [&](int lt, float& k, float& v, float& bt, float& g,
                     float4& p1, float4& p3, float& tm) {
        const int t = t0 + ((lt < CL) ? lt : CL - 1);
        const float* Pc = pc + (size_t)(t * B_SZ + b) * NCRIT;
        const float* Pr = pr + (size_t)(t * B_SZ + b) * NRESTP;
        k  = Pc[w*64 + lane];
        p1 = *(const float4*)(Pc + 1024 + w*4);
        v  = Pr[w*64 + lane];
        bt = Pr[512 + w*64 + lane];
        g  = Pr[1024 + w*64 + lane];
        p3 = *(const float4*)(Pr + 1536 + w*4);
        tm = (float)term[t * B_SZ + b];
    };
    loadA(0, ck, cv, cbt, cg, cp1, cp3, ctm);

    for (int lt = 0; lt < CL; ++lt) {
        float nk, nv, nbt, ng, ntm; float4 np1, np3;
        loadA(lt + 1, nk, nv, nbt, ng, np1, np3, ntm);

        const float mask = 1.f - ctm;
        const float4 cs4 = *(const float4*)&cos_s[lt][0];
        const float cosr[4] = {cs4.x, cs4.y, cs4.z, cs4.w};
        const float rk = fmaxf(ck, 0.f);
        const float sg = sigmoidf_(cg);
        const float p1v[4] = {cp1.x, cp1.y, cp1.z, cp1.w};
        const float p3v[4] = {cp3.x, cp3.y, cp3.z, cp3.w};

        #pragma unroll
        for (int e = 0; e < 4; ++e) {
            const float psi = rk * fmaxf(p1v[e], 0.f);
            const float gf  = sg * sigmoidf_(p3v[e]);
            const float kg  = psi * gf;
            const float dg  = (1.f - gf) * mask;
            #pragma unroll
            for (int r = 0; r < 4; ++r)
                Sk[r][e] = dg * Sk[r][e] + kg * cosr[r];
            Ss[e] = dg * Ss[e] + kg;
            Pd[e] *= dg;
        }
        const float bb = sigmoidf_(cbt);
        const float vg = cv * bb;
        const float db = (1.f - bb) * mask;
        #pragma unroll
        for (int r = 0; r < 4; ++r) Sv[r] = db * Sv[r] + vg * cosr[r];
        Pv *= db;

        ck = nk; cv = nv; cbt = nbt; cg = ng; cp1 = np1; cp3 = np3; ctm = ntm;
    }

    float* K = SPk + ((size_t)(b * CH + c) * 512 + tid) * 24;
    #pragma unroll
    for (int r = 0; r < 4; ++r)
        *(float4*)(K + r*4) = make_float4(Sk[r][0], Sk[r][1], Sk[r][2], Sk[r][3]);
    *(float4*)(K + 16) = make_float4(Pd[0], Pd[1], Pd[2], Pd[3]);
    *(float4*)(K + 20) = make_float4(Ss[0], Ss[1], Ss[2], Ss[3]);
    *(float4*)(SPv4 + ((size_t)(b * CH + c) * 512 + tid) * 4) =
        make_float4(Sv[0], Sv[1], Sv[2], Sv[3]);
    SPv1[(size_t)(b * CH + c) * 512 + tid] = Pv;
}

__global__ __launch_bounds__(512, 1)
void scan_passB(float* __restrict__ SPk, float* __restrict__ SPv4,
                const float* __restrict__ SPv1,
                const float* __restrict__ fk_prev, const float* __restrict__ fv_prev,
                const float* __restrict__ fs_prev, const float* __restrict__ tick_in,
                float* __restrict__ out_fk, float* __restrict__ out_fv,
                float* __restrict__ out_fs, float* __restrict__ out_tick)
{
    const int b = blockIdx.x;
    const int tid = threadIdx.x, w = tid >> 6, lane = tid & 63;
    const int f0 = lane << 2;

    float yk[4][4], ys[4], yv[4];
    #pragma unroll
    for (int r = 0; r < 4; ++r) {
        const float4 kk = *(const float4*)(fk_prev + (((size_t)b * R_N + r) * H_N + w) * FD_N + f0);
        yk[r][0] = kk.x; yk[r][1] = kk.y; yk[r][2] = kk.z; yk[r][3] = kk.w;
        yv[r] = fv_prev[(((size_t)b * R_N + r) * H_N + w) * DH_N + lane];
    }
    {
        const float4 ss = *(const float4*)(fs_prev + ((size_t)b * H_N + w) * FD_N + f0);
        ys[0] = ss.x; ys[1] = ss.y; ys[2] = ss.z; ys[3] = ss.w;
    }

    for (int c = 0; c < CH; ++c) {
        float* K = SPk + ((size_t)(b * CH + c) * 512 + tid) * 24;
        float4 S0 = *(float4*)(K + 0),  S1 = *(float4*)(K + 4);
        float4 S2 = *(float4*)(K + 8),  S3 = *(float4*)(K + 12);
        float4 P4 = *(float4*)(K + 16), Q4 = *(float4*)(K + 20);
        float* V = SPv4 + ((size_t)(b * CH + c) * 512 + tid) * 4;
        float4 Sv4 = *(float4*)V;
        const float Pv = SPv1[(size_t)(b * CH + c) * 512 + tid];

        *(float4*)(K + 0)  = make_float4(yk[0][0], yk[0][1], yk[0][2], yk[0][3]);
        *(float4*)(K + 4)  = make_float4(yk[1][0], yk[1][1], yk[1][2], yk[1][3]);
        *(float4*)(K + 8)  = make_float4(yk[2][0], yk[2][1], yk[2][2], yk[2][3]);
        *(float4*)(K + 12) = make_float4(yk[3][0], yk[3][1], yk[3][2], yk[3][3]);
        *(float4*)(K + 20) = make_float4(ys[0], ys[1], ys[2], ys[3]);
        *(float4*)V        = make_float4(yv[0], yv[1], yv[2], yv[3]);

        const float S[4][4] = {{S0.x,S0.y,S0.z,S0.w}, {S1.x,S1.y,S1.z,S1.w},
                               {S2.x,S2.y,S2.z,S2.w}, {S3.x,S3.y,S3.z,S3.w}};
        const float Pd[4] = {P4.x, P4.y, P4.z, P4.w};
        const float Ssv[4] = {Q4.x, Q4.y, Q4.z, Q4.w};
        const float Svv[4] = {Sv4.x, Sv4.y, Sv4.z, Sv4.w};
        #pragma unroll
        for (int e = 0; e < 4; ++e) {
            #pragma unroll
            for (int r = 0; r < 4; ++r)
                yk[r][e] = S[r][e] + Pd[e] * yk[r][e];
            ys[e] = Ssv[e] + Pd[e] * ys[e];
        }
        #pragma unroll
        for (int r = 0; r < 4; ++r)
            yv[r] = Svv[r] + Pv * yv[r];
    }

    #pragma unroll
    for (int r = 0; r < 4; ++r) {
        *(float4*)(out_fk + (((size_t)b * R_N + r) * H_N + w) * FD_N + f0) =
            make_float4(yk[r][0], yk[r][1], yk[r][2], yk[r][3]);
        out_fv[(((size_t)b * R_N + r) * H_N + w) * DH_N + lane] = yv[r];
    }
    *(float4*)(out_fs + ((size_t)b * H_N + w) * FD_N + f0) =
        make_float4(ys[0], ys[1], ys[2], ys[3]);
    if (tid == 0) out_tick[b] = tick_in[b] + (float)T_LEN;
}

struct PF {
    float k[4], q[4], v[4], bt[4], g[4], tm[4];
    float4 p1[4], p2[4], p3[4];
};

__global__ __launch_bounds__(512, 1)
void scan_passC(const float* __restrict__ pc, const float* __restrict__ pr,
                const int* __restrict__ term, const float* __restrict__ tick_in,
                const float* __restrict__ SPk, const float* __restrict__ SPv4,
                __hip_bfloat16* __restrict__ attn)
{
    const int b = blockIdx.x, c = blockIdx.y;
    const int tid = threadIdx.x, w = tid >> 6, lane = tid & 63;
    const int tc0 = c * CL;

    __shared__ float red[2][4][8][4];
    __shared__ __align__(16) float cos_s[CL][4];

    const float tick_b = tick_in[b];
    if (tid < CL * 4) {
        const int lt = tid >> 2, r = tid & 3;
        const float PI_F = 3.14159265358979323846f;
        const float omega[4] = {-PI_F, -PI_F/3.0f, PI_F/3.0f, PI_F};
        cos_s[lt][r] = cosf(((float)(tc0 + lt + 1) + tick_b) * omega[r]);
    }

    float fk[4][4], fsv[4], fv[4];
    {
        const float* K = SPk + ((size_t)(b * CH + c) * 512 + tid) * 24;
        #pragma unroll
        for (int r = 0; r < 4; ++r) {
            const float4 kk = *(const float4*)(K + r*4);
            fk[r][0] = kk.x; fk[r][1] = kk.y; fk[r][2] = kk.z; fk[r][3] = kk.w;
        }
        const float4 s4 = *(const float4*)(K + 20);
        fsv[0] = s4.x; fsv[1] = s4.y; fsv[2] = s4.z; fsv[3] = s4.w;
        const float4 v4 = *(const float4*)(SPv4 + ((size_t)(b * CH + c) * 512 + tid) * 4);
        fv[0] = v4.x; fv[1] = v4.y; fv[2] = v4.z; fv[3] = v4.w;
    }

    auto prefetch = [&](PF& dst, int lt0) {
        #pragma unroll
        for (int s = 0; s < 4; ++s) {
            int lt = lt0 + s; lt = (lt < CL) ? lt : CL - 1;
            const int t = tc0 + lt;
            const float* Pc = pc + (size_t)(t * B_SZ + b) * NCRIT;
            const float* Pr = pr + (size_t)(t * B_SZ + b) * NRESTP;
            dst.k[s]  = Pc[w*64 + lane];
            dst.q[s]  = Pc[512 + w*64 + lane];
            dst.p1[s] = *(const float4*)(Pc + 1024 + w*4);
            dst.p2[s] = *(const float4*)(Pc + 1056 + w*4);
            dst.v[s]  = Pr[w*64 + lane];
            dst.bt[s] = Pr[512 + w*64 + lane];
            dst.g[s]  = Pr[1024 + w*64 + lane];
            dst.p3[s] = *(const float4*)(Pr + 1536 + w*4);
            dst.tm[s] = (float)term[t * B_SZ + b];
        }
    };

    auto round_body = [&](const PF& cur, int lt0, int P) {
        float sc[4][4], nr[4], fvs[4][4];
        #pragma unroll
        for (int s = 0; s < 4; ++s) {
            const float mask = 1.f - cur.tm[s];
            const float4 cs = *(const float4*)&cos_s[lt0 + s][0];
            const float cosr[4] = {cs.x, cs.y, cs.z, cs.w};
            const float rk = fmaxf(cur.k[s], 0.f);
            const float rq = fmaxf(cur.q[s], 0.f);
            const float sg = sigmoidf_(cur.g[s]);
            const float p1v[4] = {cur.p1[s].x, cur.p1[s].y, cur.p1[s].z, cur.p1[s].w};
            const float p2v[4] = {cur.p2[s].x, cur.p2[s].y, cur.p2[s].z, cur.p2[s].w};
            const float p3v[4] = {cur.p3[s].x, cur.p3[s].y, cur.p3[s].z, cur.p3[s].w};
            float phi[4], kg[4], dgv[4];
            float np = 0.f;
            #pragma unroll
            for (int e = 0; e < 4; ++e) {
                const float psi = rk * fmaxf(p1v[e], 0.f);
                phi[e] = rq * fmaxf(p2v[e], 0.f);
                const float gf = sg * sigmoidf_(p3v[e]);
                kg[e] = psi * gf;
                dgv[e] = (1.f - gf) * mask;
                fsv[e] = dgv[e] * fsv[e] + kg[e];
                np += fsv[e] * phi[e];
            }
            nr[s] = np;
            #pragma unroll
            for (int r = 0; r < R_N; ++r) {
                float ss = 0.f;
                #pragma unroll
                for (int e = 0; e < 4; ++e) {
                    fk[r][e] = dgv[e] * fk[r][e] + kg[e] * cosr[r];
                    ss += fk[r][e] * phi[e];
                }
                sc[s][r] = ss;
            }
            const float bb = sigmoidf_(cur.bt[s]);
            const float vg = cur.v[s] * bb;
            const float db = (1.f - bb) * mask;
            #pragma unroll
            for (int r = 0; r < R_N; ++r) { fv[r] = db * fv[r] + vg * cosr[r]; fvs[s][r] = fv[r]; }
        }
        #pragma unroll
        for (int off = 32; off >= 1; off >>= 1) {
            #pragma unroll
            for (int s = 0; s < 4; ++s) {
                #pragma unroll
                for (int r = 0; r < 4; ++r) sc[s][r] += __shfl_xor(sc[s][r], off);
                nr[s] += __shfl_xor(nr[s], off);
            }
        }
        if (lane == 0) {
            #pragma unroll
            for (int s = 0; s < 4; ++s)
                *(float4*)&red[P][s][w][0] = make_float4(sc[s][0], sc[s][1], sc[s][2], sc[s][3]);
        }
        __syncthreads();
        #pragma unroll
        for (int s = 0; s < 4; ++s) {
            float s0 = 0.f, s1 = 0.f, s2 = 0.f, s3 = 0.f;
            #pragma unroll
            for (int ww = 0; ww < 8; ++ww) {
                const float4 rv = *(const float4*)&red[P][s][ww][0];
                s0 += rv.x; s1 += rv.y; s2 += rv.z; s3 += rv.w;
            }
            const float kv = fvs[s][0]*s0 + fvs[s][1]*s1 + fvs[s][2]*s2 + fvs[s][3]*s3;
            attn[((size_t)(tc0 + lt0 + s) * B_SZ + b) * (H_N * DH_N) + tid] =
                __float2bfloat16(kv / (2.0f * R_N * nr[s] + EPS_F));
        }
    };

    PF Abuf, Bbuf;
    prefetch(Abuf, 0);
    __syncthreads();

    for (int lt0 = 0; lt0 < CL; lt0 += 8) {
        prefetch(Bbuf, lt0 + 4);
        round_body(Abuf, lt0, 0);
        prefetch(Abuf, lt0 + 8);
        round_body(Bbuf, lt0 + 4, 1);
    }
}

extern "C" void kernel_launch(void* const* d_in, const int* in_sizes, int n_in,
                              void* d_out, int out_size, void* d_ws, size_t ws_size,
                              hipStream_t stream)
{
    const float* inputs  = (const float*)d_in[0];
    const int*   term    = (const int*)  d_in[1];
    const float* fk_prev = (const float*)d_in[2];
    const float* fv_prev = (const float*)d_in[3];
    const float* fs_prev = (const float*)d_in[4];
    const float* tick    = (const float*)d_in[5];
    const float* Wf      = (const float*)d_in[6];
    const float* bf      = (const float*)d_in[7];
    const float* Wp      = (const float*)d_in[8];
    const float* bp      = (const float*)d_in[9];

    float* out      = (float*)d_out;
    float* out_fk   = out    + (size_t)T_LEN * B_SZ * DMODEL;
    float* out_fv   = out_fk + (size_t)B_SZ * R_N * H_N * FD_N;
    float* out_fs   = out_fv + (size_t)B_SZ * R_N * H_N * DH_N;
    float* out_tick = out_fs + (size_t)B_SZ * H_N * FD_N;

    char* ws = (char*)d_ws;
    float* proj_crit = (float*)ws;                       // 17.8 MB
    ws += (size_t)T_LEN * B_SZ * NCRIT * 4;
    float* proj_rest = (float*)ws;                       // 27.3 MB
    ws += (size_t)T_LEN * B_SZ * NRESTP * 4;
    __hip_bfloat16* attn_bf = (__hip_bfloat16*)ws;       // 4.2 MB
    ws += (size_t)T_LEN * B_SZ * H_N * DH_N * 2;
    __hip_bfloat16* Wp_bf = (__hip_bfloat16*)ws;         // 1 MB
    ws += (size_t)DMODEL * H_N * DH_N * 2;
    _Float16* Wch = (_Float16*)ws;                       // 2.36 MB
    ws += (size_t)NSPLITP * DMODEL * 2;
    _Float16* Wcl = (_Float16*)ws;                       // 2.36 MB
    ws += (size_t)NSPLITP * DMODEL * 2;
    // union region: {Xh, Xl} (GEMM phase, 16.8 MB) overlaps {SPk, SPv4, SPv1} (scan, 15.2 MB)
    char* uni = ws;
    _Float16* Xh = (_Float16*)uni;                                          // 8.4 MB
    _Float16* Xl = (_Float16*)(uni + (size_t)T_LEN * B_SZ * DMODEL * 2);    // 8.4 MB
    float* SPk  = (float*)uni;                                              // 12.6 MB
    float* SPv4 = (float*)(uni + (size_t)B_SZ * CH * 512 * 24 * 4);         // 2.1 MB
    float* SPv1 = (float*)(uni + (size_t)B_SZ * CH * 512 * 28 * 4);         // 0.5 MB

    // conversions
    cvt_split_x<<<2048, 256, 0, stream>>>(inputs, Xh, Xl, T_LEN * B_SZ * DMODEL);
    cvt_split_w<<<NSPLITP, 256, 0, stream>>>(Wf, Wch, Wcl);
    cvt_bf16<<<512, 256, 0, stream>>>(Wp, Wp_bf, DMODEL * H_N * DH_N);

    // 1a) crit cols 0..1055 (k,q,p1) via split-f16 MFMA (f32-class precision)
    gemm_mfma_crit<<<dim3(NSPLITP / 64, (T_LEN * B_SZ) / 128), dim3(256), 0, stream>>>(
        Xh, Xl, Wch, Wcl, bf, proj_crit);

    // 1b) p2 cols 1056..1087 in true f32
    gemm_p2_f32<<<dim3((T_LEN * B_SZ) / 8), dim3(256), 0, stream>>>(
        inputs, Wf, bf, proj_crit);

    // 1c) rest columns (v,beta,gamma,p3) via bf16 MFMA
    gemm_mfma_rest<<<dim3(NRESTP / 128, (T_LEN * B_SZ) / 128), dim3(256), 0, stream>>>(
        inputs, Wf, bf, proj_rest);

    // 2) parallel scan
    scan_passA<<<dim3(B_SZ, CH), dim3(512), 0, stream>>>(
        proj_crit, proj_rest, term, tick, SPk, SPv4, SPv1);
    scan_passB<<<dim3(B_SZ), dim3(512), 0, stream>>>(
        SPk, SPv4, SPv1, fk_prev, fv_prev, fs_prev, tick,
        out_fk, out_fv, out_fs, out_tick);
    scan_passC<<<dim3(B_SZ, CH), dim3(512), 0, stream>>>(
        proj_crit, proj_rest, term, tick, SPk, SPv4, attn_bf);

    // 3) out = attn @ Wp^T + bp
    gemm_mfma_f32out<<<dim3(DMODEL / 128, (T_LEN * B_SZ) / 128), dim3(256), 0, stream>>>(
        attn_bf, Wp_bf, bp, out, T_LEN * B_SZ, DMODEL, H_N * DH_N);
}

// Round 10
// 253.800 us; speedup vs baseline: 3.4834x; 1.5128x over previous
//
#include <hip/hip_runtime.h>
#include <hip/hip_bf16.h>
#include <math.h>

#define T_LEN  128
#define B_SZ   32
#define DMODEL 1024
#define H_N    8
#define DH_N   64
#define FD_N   256
#define R_N    4
#define PROJ_N 2656
#define NCRIT  1088
#define NSPLIT 1056    // split-f16 cols (k,q,p1); p2 = cols 1056..1087 via f32 kernel
#define NSPLITP 1152
#define NREST  1568
#define NRESTP 1664
#define EPS_F  1e-6f
#define CH     8
#define CL     16

typedef __attribute__((ext_vector_type(8))) short bf16x8;
typedef __attribute__((ext_vector_type(8))) _Float16 f16x8;
typedef __attribute__((ext_vector_type(4))) float f32x4;

#define LO_SCALE 2048.0f
#define W_SCALE  32.0f

__device__ __forceinline__ float sigmoidf_(float x) { return 1.0f / (1.0f + __expf(-x)); }

__device__ __forceinline__ f16x8 as_f16(bf16x8 v) { union { bf16x8 s; f16x8 h; } u; u.s = v; return u.h; }

// crit layout: [k 8x64][q 8x64][p1 8x4][p2 8x4]
__device__ __forceinline__ int map_crit(int j) {
    if (j < 512)  return (j >> 6) * 320 + (j & 63);
    if (j < 1024) { int t = j - 512;  return (t >> 6) * 320 + 64 + (t & 63); }
    if (j < 1056) { int t = j - 1024; return 2560 + (t >> 2) * 12 + (t & 3); }
    { int t = j - 1056; return 2560 + (t >> 2) * 12 + 4 + (t & 3); }
}
// rest layout: [v 8x64][beta 8x64][gamma 8x64][p3 8x4]
__device__ __forceinline__ int map_rest(int j) {
    if (j < 512)  return (j >> 6) * 320 + 128 + (j & 63);
    if (j < 1024) { int t = j - 512;  return (t >> 6) * 320 + 192 + (t & 63); }
    if (j < 1536) { int t = j - 1024; return (t >> 6) * 320 + 256 + (t & 63); }
    { int t = j - 1536; return 2560 + (t >> 2) * 12 + 8 + (t & 3); }
}

__global__ void cvt_bf16(const float* __restrict__ src, __hip_bfloat16* __restrict__ dst, int n)
{
    int i = (blockIdx.x * blockDim.x + threadIdx.x) * 4;
    const int stride = gridDim.x * blockDim.x * 4;
    for (; i < n; i += stride) {
        float4 v = *(const float4*)(src + i);
        dst[i + 0] = __float2bfloat16(v.x);
        dst[i + 1] = __float2bfloat16(v.y);
        dst[i + 2] = __float2bfloat16(v.z);
        dst[i + 3] = __float2bfloat16(v.w);
    }
}

// split inputs x -> (hi f16, lo f16 scaled by 2048)
__global__ void cvt_split_x(const float* __restrict__ src,
                            _Float16* __restrict__ hi, _Float16* __restrict__ lo, int n)
{
    int i = (blockIdx.x * blockDim.x + threadIdx.x) * 4;
    const int stride = gridDim.x * blockDim.x * 4;
    for (; i < n; i += stride) {
        float4 v = *(const float4*)(src + i);
        const float a[4] = {v.x, v.y, v.z, v.w};
        #pragma unroll
        for (int c = 0; c < 4; ++c) {
            const _Float16 h = (_Float16)a[c];
            hi[i + c] = h;
            lo[i + c] = (_Float16)((a[c] - (float)h) * LO_SCALE);
        }
    }
}

// gather crit Wf rows, scale x32, split -> hi/lo f16
__global__ __launch_bounds__(256) void cvt_split_w(
    const float* __restrict__ Wf, _Float16* __restrict__ hi, _Float16* __restrict__ lo)
{
    const int j = blockIdx.x;
    const int i = threadIdx.x * 4;
    _Float16* dh = hi + (size_t)j * 1024 + i;
    _Float16* dl = lo + (size_t)j * 1024 + i;
    if (j < NCRIT) {
        float4 v = *(const float4*)(Wf + (size_t)map_crit(j) * 1024 + i);
        const float a[4] = {v.x * W_SCALE, v.y * W_SCALE, v.z * W_SCALE, v.w * W_SCALE};
        #pragma unroll
        for (int c = 0; c < 4; ++c) {
            const _Float16 h = (_Float16)a[c];
            dh[c] = h;
            dl[c] = (_Float16)((a[c] - (float)h) * LO_SCALE);
        }
    } else {
        #pragma unroll
        for (int c = 0; c < 4; ++c) { dh[c] = (_Float16)0.f; dl[c] = (_Float16)0.f; }
    }
}

// gather rest Wf rows -> f16 (hi only, unscaled) + bias
__global__ __launch_bounds__(256) void cvt_wrest_h(
    const float* __restrict__ Wf, const float* __restrict__ bf,
    _Float16* __restrict__ Wh, float* __restrict__ bias_r)
{
    const int j = blockIdx.x;            // 0..NRESTP-1
    const int i = threadIdx.x * 4;
    _Float16* dst = Wh + (size_t)j * 1024 + i;
    if (j < NREST) {
        const int wr = map_rest(j);
        float4 v = *(const float4*)(Wf + (size_t)wr * 1024 + i);
        dst[0] = (_Float16)v.x; dst[1] = (_Float16)v.y;
        dst[2] = (_Float16)v.z; dst[3] = (_Float16)v.w;
        if (threadIdx.x == 0) bias_r[j] = bf[wr];
    } else {
        dst[0] = dst[1] = dst[2] = dst[3] = (_Float16)0.f;
        if (threadIdx.x == 0) bias_r[j] = 0.f;
    }
}

// ---------------- generic 2-byte MFMA GEMM, dbuf reg-prefetch ----------------
// C[M][NP] f32 = A[M][K] @ B[NP][K]^T + bias.  BM=64, BN=128, BK=32, 256 thr.
// F16=1: operands f16 (mfma_f32_16x16x32_f16); F16=0: bf16.
template<int F16>
__global__ __launch_bounds__(256) void gemm_nt_dbuf(
    const void* __restrict__ Ap, const void* __restrict__ Bp,
    const float* __restrict__ bias, float* __restrict__ C, int NP, int K)
{
    __shared__ __align__(16) short As[64][40];
    __shared__ __align__(16) short Bs[128][40];

    const short* A = (const short*)Ap;
    const short* B = (const short*)Bp;

    const int tid  = threadIdx.x;
    const int wave = tid >> 6, lane = tid & 63;
    const int row0 = blockIdx.y * 64;
    const int col0 = blockIdx.x * 128;

    const int wr = (wave >> 1) * 32;
    const int wc = (wave & 1) * 64;
    const int lr = lane & 15;
    const int lk = (lane >> 4) * 8;
    const int lq = (lane >> 4) * 4;

    const int sr = tid >> 2;
    const int sk = (tid & 3) * 8;

    const short* aptr  = A + (size_t)(row0 + sr) * K + sk;
    const short* bptr0 = B + (size_t)(col0 + sr) * K + sk;
    const short* bptr1 = B + (size_t)(col0 + 64 + sr) * K + sk;

    f32x4 acc[2][4] = {};

    bf16x8 ra  = *(const bf16x8*)(aptr);
    bf16x8 rb0 = *(const bf16x8*)(bptr0);
    bf16x8 rb1 = *(const bf16x8*)(bptr1);

    for (int k0 = 0; k0 < K; k0 += 32) {
        *(bf16x8*)&As[sr][sk]      = ra;
        *(bf16x8*)&Bs[sr][sk]      = rb0;
        *(bf16x8*)&Bs[64 + sr][sk] = rb1;
        __syncthreads();
        if (k0 + 32 < K) {
            ra  = *(const bf16x8*)(aptr + k0 + 32);
            rb0 = *(const bf16x8*)(bptr0 + k0 + 32);
            rb1 = *(const bf16x8*)(bptr1 + k0 + 32);
        }
        bf16x8 af[2], bfr[4];
        #pragma unroll
        for (int i = 0; i < 2; ++i)
            af[i] = *(const bf16x8*)&As[wr + i*16 + lr][lk];
        #pragma unroll
        for (int j = 0; j < 4; ++j)
            bfr[j] = *(const bf16x8*)&Bs[wc + j*16 + lr][lk];
        #pragma unroll
        for (int i = 0; i < 2; ++i)
            #pragma unroll
            for (int j = 0; j < 4; ++j) {
                if (F16)
                    acc[i][j] = __builtin_amdgcn_mfma_f32_16x16x32_f16(as_f16(af[i]), as_f16(bfr[j]), acc[i][j], 0, 0, 0);
                else
                    acc[i][j] = __builtin_amdgcn_mfma_f32_16x16x32_bf16(af[i], bfr[j], acc[i][j], 0, 0, 0);
            }
        __syncthreads();
    }

    #pragma unroll
    for (int j = 0; j < 4; ++j) {
        const int col = col0 + wc + j*16 + lr;
        const float bs = bias[col];
        #pragma unroll
        for (int i = 0; i < 2; ++i) {
            const int rowb = row0 + wr + i*16 + lq;
            #pragma unroll
            for (int r = 0; r < 4; ++r)
                C[(size_t)(rowb + r) * NP + col] = acc[i][j][r] + bs;
        }
    }
}

// ---------------- split-f16 MFMA GEMM, dbuf: crit cols 0..1055 ----------------
// BM=64, BN=64, BK=32; grid 18x64 = 1152 blocks.
__global__ __launch_bounds__(256) void gemm_crit_dbuf(
    const _Float16* __restrict__ Xh, const _Float16* __restrict__ Xl,
    const _Float16* __restrict__ Wh, const _Float16* __restrict__ Wl,
    const float* __restrict__ bias, float* __restrict__ C)
{
    __shared__ __align__(16) _Float16 Ah[64][40];
    __shared__ __align__(16) _Float16 Al[64][40];
    __shared__ __align__(16) _Float16 Bh[64][40];
    __shared__ __align__(16) _Float16 Bl[64][40];

    const int tid  = threadIdx.x;
    const int wave = tid >> 6, lane = tid & 63;
    const int row0 = blockIdx.y * 64;
    const int col0 = blockIdx.x * 64;

    const int wr = (wave >> 1) * 32;
    const int wc = (wave & 1) * 32;
    const int lr = lane & 15;
    const int lk = (lane >> 4) * 8;
    const int lq = (lane >> 4) * 4;

    const int sr = tid >> 2;
    const int sk = (tid & 3) * 8;

    const _Float16* xh = Xh + (size_t)(row0 + sr) * 1024 + sk;
    const _Float16* xl = Xl + (size_t)(row0 + sr) * 1024 + sk;
    const _Float16* wh = Wh + (size_t)(col0 + sr) * 1024 + sk;
    const _Float16* wl = Wl + (size_t)(col0 + sr) * 1024 + sk;

    f32x4 accm[2][2] = {};
    f32x4 accc[2][2] = {};

    f16x8 rah = *(const f16x8*)(xh);
    f16x8 ral = *(const f16x8*)(xl);
    f16x8 rbh = *(const f16x8*)(wh);
    f16x8 rbl = *(const f16x8*)(wl);

    for (int k0 = 0; k0 < 1024; k0 += 32) {
        *(f16x8*)&Ah[sr][sk] = rah;
        *(f16x8*)&Al[sr][sk] = ral;
        *(f16x8*)&Bh[sr][sk] = rbh;
        *(f16x8*)&Bl[sr][sk] = rbl;
        __syncthreads();
        if (k0 + 32 < 1024) {
            rah = *(const f16x8*)(xh + k0 + 32);
            ral = *(const f16x8*)(xl + k0 + 32);
            rbh = *(const f16x8*)(wh + k0 + 32);
            rbl = *(const f16x8*)(wl + k0 + 32);
        }
        f16x8 ah[2], al[2], bh[2], bl[2];
        #pragma unroll
        for (int i = 0; i < 2; ++i) {
            ah[i] = *(const f16x8*)&Ah[wr + i*16 + lr][lk];
            al[i] = *(const f16x8*)&Al[wr + i*16 + lr][lk];
        }
        #pragma unroll
        for (int j = 0; j < 2; ++j) {
            bh[j] = *(const f16x8*)&Bh[wc + j*16 + lr][lk];
            bl[j] = *(const f16x8*)&Bl[wc + j*16 + lr][lk];
        }
        #pragma unroll
        for (int i = 0; i < 2; ++i)
            #pragma unroll
            for (int j = 0; j < 2; ++j) {
                accm[i][j] = __builtin_amdgcn_mfma_f32_16x16x32_f16(ah[i], bh[j], accm[i][j], 0, 0, 0);
                accc[i][j] = __builtin_amdgcn_mfma_f32_16x16x32_f16(ah[i], bl[j], accc[i][j], 0, 0, 0);
                accc[i][j] = __builtin_amdgcn_mfma_f32_16x16x32_f16(al[i], bh[j], accc[i][j], 0, 0, 0);
            }
        __syncthreads();
    }

    #pragma unroll
    for (int j = 0; j < 2; ++j) {
        const int col = col0 + wc + j*16 + lr;
        if (col >= NSPLIT) continue;
        const float bs = bias[map_crit(col)];
        #pragma unroll
        for (int i = 0; i < 2; ++i) {
            const int rowb = row0 + wr + i*16 + lq;
            #pragma unroll
            for (int r = 0; r < 4; ++r) {
                const float v = (accm[i][j][r] + accc[i][j][r] * (1.0f/LO_SCALE)) * (1.0f/W_SCALE) + bs;
                C[(size_t)(rowb + r) * NCRIT + col] = v;
            }
        }
    }
}

// ---------------- tiny f32 GEMM: 32 p2 columns -> proj_crit[.., 1056..1087] ----------------
__global__ __launch_bounds__(256) void gemm_p2_f32(
    const float* __restrict__ A, const float* __restrict__ Wf,
    const float* __restrict__ bias, float* __restrict__ C)
{
    __shared__ __align__(16) float As[8][1024];
    const int tid = threadIdx.x;
    const int row0 = blockIdx.x * 8;
    #pragma unroll
    for (int i = 0; i < 8; ++i) {
        const int idx = tid + i * 256;
        const int r = idx >> 8, c4 = (idx & 255) << 2;
        *(float4*)&As[r][c4] = *(const float4*)(A + (size_t)(row0 + r) * 1024 + c4);
    }
    __syncthreads();
    const int r = tid >> 5, j = tid & 31;
    const int wfrow = 2560 + (j >> 2) * 12 + 4 + (j & 3);
    const float* W = Wf + (size_t)wfrow * 1024;
    float acc = 0.f;
    #pragma unroll 8
    for (int k = 0; k < 1024; k += 4) {
        const float4 a  = *(const float4*)&As[r][k];
        const float4 w4 = *(const float4*)(W + k);
        acc += a.x*w4.x + a.y*w4.y + a.z*w4.z + a.w*w4.w;
    }
    C[(size_t)(row0 + r) * NCRIT + 1056 + j] = acc + bias[wfrow];
}

// ============ parallel scan (unchanged, proven) ============
__global__ __launch_bounds__(512, 1)
void scan_passA(const float* __restrict__ pc, const float* __restrict__ pr,
                const int* __restrict__ term, const float* __restrict__ tick_in,
                float* __restrict__ SPk, float* __restrict__ SPv4, float* __restrict__ SPv1)
{
    const int b = blockIdx.x, c = blockIdx.y;
    const int tid = threadIdx.x, w = tid >> 6, lane = tid & 63;
    const int t0 = c * CL;

    __shared__ __align__(16) float cos_s[CL][4];
    const float tick_b = tick_in[b];
    if (tid < CL * 4) {
        const int lt = tid >> 2, r = tid & 3;
        const float PI_F = 3.14159265358979323846f;
        const float omega[4] = {-PI_F, -PI_F/3.0f, PI_F/3.0f, PI_F};
        cos_s[lt][r] = cosf(((float)(t0 + lt + 1) + tick_b) * omega[r]);
    }
    __syncthreads();

    float Sk[4][4] = {}, Ss[4] = {}, Sv[4] = {};
    float Pd[4] = {1.f, 1.f, 1.f, 1.f};
    float Pv = 1.f;

    float ck, cv, cbt, cg, ctm; float4 cp1, cp3;
    auto loadA = [&](int lt, float& k, float& v, float& bt, float& g,
                     float4& p1, float4& p3, float& tm) {
        const int t = t0 + ((lt < CL) ? lt : CL - 1);
        const float* Pc = pc + (size_t)(t * B_SZ + b) * NCRIT;
        const float* Pr = pr + (size_t)(t * B_SZ + b) * NRESTP;
        k  = Pc[w*64 + lane];
        p1 = *(const float4*)(Pc + 1024 + w*4);
        v  = Pr[w*64 + lane];
        bt = Pr[512 + w*64 + lane];
        g  = Pr[1024 + w*64 + lane];
        p3 = *(const float4*)(Pr + 1536 + w*4);
        tm = (float)term[t * B_SZ + b];
    };
    loadA(0, ck, cv, cbt, cg, cp1, cp3, ctm);

    for (int lt = 0; lt < CL; ++lt) {
        float nk, nv, nbt, ng, ntm; float4 np1, np3;
        loadA(lt + 1, nk, nv, nbt, ng, np1, np3, ntm);

        const float mask = 1.f - ctm;
        const float4 cs4 = *(const float4*)&cos_s[lt][0];
        const float cosr[4] = {cs4.x, cs4.y, cs4.z, cs4.w};
        const float rk = fmaxf(ck, 0.f);
        const float sg = sigmoidf_(cg);
        const float p1v[4] = {cp1.x, cp1.y, cp1.z, cp1.w};
        const float p3v[4] = {cp3.x, cp3.y, cp3.z, cp3.w};

        #pragma unroll
        for (int e = 0; e < 4; ++e) {
            const float psi = rk * fmaxf(p1v[e], 0.f);
            const float gf  = sg * sigmoidf_(p3v[e]);
            const float kg  = psi * gf;
            const float dg  = (1.f - gf) * mask;
            #pragma unroll
            for (int r = 0; r < 4; ++r)
                Sk[r][e] = dg * Sk[r][e] + kg * cosr[r];
            Ss[e] = dg * Ss[e] + kg;
            Pd[e] *= dg;
        }
        const float bb = sigmoidf_(cbt);
        const float vg = cv * bb;
        const float db = (1.f - bb) * mask;
        #pragma unroll
        for (int r = 0; r < 4; ++r) Sv[r] = db * Sv[r] + vg * cosr[r];
        Pv *= db;

        ck = nk; cv = nv; cbt = nbt; cg = ng; cp1 = np1; cp3 = np3; ctm = ntm;
    }

    float* K = SPk + ((size_t)(b * CH + c) * 512 + tid) * 24;
    #pragma unroll
    for (int r = 0; r < 4; ++r)
        *(float4*)(K + r*4) = make_float4(Sk[r][0], Sk[r][1], Sk[r][2], Sk[r][3]);
    *(float4*)(K + 16) = make_float4(Pd[0], Pd[1], Pd[2], Pd[3]);
    *(float4*)(K + 20) = make_float4(Ss[0], Ss[1], Ss[2], Ss[3]);
    *(float4*)(SPv4 + ((size_t)(b * CH + c) * 512 + tid) * 4) =
        make_float4(Sv[0], Sv[1], Sv[2], Sv[3]);
    SPv1[(size_t)(b * CH + c) * 512 + tid] = Pv;
}

__global__ __launch_bounds__(512, 1)
void scan_passB(float* __restrict__ SPk, float* __restrict__ SPv4,
                const float* __restrict__ SPv1,
                const float* __restrict__ fk_prev, const float* __restrict__ fv_prev,
                const float* __restrict__ fs_prev, const float* __restrict__ tick_in,
                float* __restrict__ out_fk, float* __restrict__ out_fv,
                float* __restrict__ out_fs, float* __restrict__ out_tick)
{
    const int b = blockIdx.x;
    const int tid = threadIdx.x, w = tid >> 6, lane = tid & 63;
    const int f0 = lane << 2;

    float yk[4][4], ys[4], yv[4];
    #pragma unroll
    for (int r = 0; r < 4; ++r) {
        const float4 kk = *(const float4*)(fk_prev + (((size_t)b * R_N + r) * H_N + w) * FD_N + f0);
        yk[r][0] = kk.x; yk[r][1] = kk.y; yk[r][2] = kk.z; yk[r][3] = kk.w;
        yv[r] = fv_prev[(((size_t)b * R_N + r) * H_N + w) * DH_N + lane];
    }
    {
        const float4 ss = *(const float4*)(fs_prev + ((size_t)b * H_N + w) * FD_N + f0);
        ys[0] = ss.x; ys[1] = ss.y; ys[2] = ss.z; ys[3] = ss.w;
    }

    for (int c = 0; c < CH; ++c) {
        float* K = SPk + ((size_t)(b * CH + c) * 512 + tid) * 24;
        float4 S0 = *(float4*)(K + 0),  S1 = *(float4*)(K + 4);
        float4 S2 = *(float4*)(K + 8),  S3 = *(float4*)(K + 12);
        float4 P4 = *(float4*)(K + 16), Q4 = *(float4*)(K + 20);
        float* V = SPv4 + ((size_t)(b * CH + c) * 512 + tid) * 4;
        float4 Sv4 = *(float4*)V;
        const float Pv = SPv1[(size_t)(b * CH + c) * 512 + tid];

        *(float4*)(K + 0)  = make_float4(yk[0][0], yk[0][1], yk[0][2], yk[0][3]);
        *(float4*)(K + 4)  = make_float4(yk[1][0], yk[1][1], yk[1][2], yk[1][3]);
        *(float4*)(K + 8)  = make_float4(yk[2][0], yk[2][1], yk[2][2], yk[2][3]);
        *(float4*)(K + 12) = make_float4(yk[3][0], yk[3][1], yk[3][2], yk[3][3]);
        *(float4*)(K + 20) = make_float4(ys[0], ys[1], ys[2], ys[3]);
        *(float4*)V        = make_float4(yv[0], yv[1], yv[2], yv[3]);

        const float S[4][4] = {{S0.x,S0.y,S0.z,S0.w}, {S1.x,S1.y,S1.z,S1.w},
                               {S2.x,S2.y,S2.z,S2.w}, {S3.x,S3.y,S3.z,S3.w}};
        const float Pd[4] = {P4.x, P4.y, P4.z, P4.w};
        const float Ssv[4] = {Q4.x, Q4.y, Q4.z, Q4.w};
        const float Svv[4] = {Sv4.x, Sv4.y, Sv4.z, Sv4.w};
        #pragma unroll
        for (int e = 0; e < 4; ++e) {
            #pragma unroll
            for (int r = 0; r < 4; ++r)
                yk[r][e] = S[r][e] + Pd[e] * yk[r][e];
            ys[e] = Ssv[e] + Pd[e] * ys[e];
        }
        #pragma unroll
        for (int r = 0; r < 4; ++r)
            yv[r] = Svv[r] + Pv * yv[r];
    }

    #pragma unroll
    for (int r = 0; r < 4; ++r) {
        *(float4*)(out_fk + (((size_t)b * R_N + r) * H_N + w) * FD_N + f0) =
            make_float4(yk[r][0], yk[r][1], yk[r][2], yk[r][3]);
        out_fv[(((size_t)b * R_N + r) * H_N + w) * DH_N + lane] = yv[r];
    }
    *(float4*)(out_fs + ((size_t)b * H_N + w) * FD_N + f0) =
        make_float4(ys[0], ys[1], ys[2], ys[3]);
    if (tid == 0) out_tick[b] = tick_in[b] + (float)T_LEN;
}

struct PF {
    float k[4], q[4], v[4], bt[4], g[4], tm[4];
    float4 p1[4], p2[4], p3[4];
};

__global__ __launch_bounds__(512, 1)
void scan_passC(const float* __restrict__ pc, const float* __restrict__ pr,
                const int* __restrict__ term, const float* __restrict__ tick_in,
                const float* __restrict__ SPk, const float* __restrict__ SPv4,
                __hip_bfloat16* __restrict__ attn)
{
    const int b = blockIdx.x, c = blockIdx.y;
    const int tid = threadIdx.x, w = tid >> 6, lane = tid & 63;
    const int tc0 = c * CL;

    __shared__ float red[2][4][8][4];
    __shared__ __align__(16) float cos_s[CL][4];

    const float tick_b = tick_in[b];
    if (tid < CL * 4) {
        const int lt = tid >> 2, r = tid & 3;
        const float PI_F = 3.14159265358979323846f;
        const float omega[4] = {-PI_F, -PI_F/3.0f, PI_F/3.0f, PI_F};
        cos_s[lt][r] = cosf(((float)(tc0 + lt + 1) + tick_b) * omega[r]);
    }

    float fk[4][4], fsv[4], fv[4];
    {
        const float* K = SPk + ((size_t)(b * CH + c) * 512 + tid) * 24;
        #pragma unroll
        for (int r = 0; r < 4; ++r) {
            const float4 kk = *(const float4*)(K + r*4);
            fk[r][0] = kk.x; fk[r][1] = kk.y; fk[r][2] = kk.z; fk[r][3] = kk.w;
        }
        const float4 s4 = *(const float4*)(K + 20);
        fsv[0] = s4.x; fsv[1] = s4.y; fsv[2] = s4.z; fsv[3] = s4.w;
        const float4 v4 = *(const float4*)(SPv4 + ((size_t)(b * CH + c) * 512 + tid) * 4);
        fv[0] = v4.x; fv[1] = v4.y; fv[2] = v4.z; fv[3] = v4.w;
    }

    auto prefetch = [&](PF& dst, int lt0) {
        #pragma unroll
        for (int s = 0; s < 4; ++s) {
            int lt = lt0 + s; lt = (lt < CL) ? lt : CL - 1;
            const int t = tc0 + lt;
            const float* Pc = pc + (size_t)(t * B_SZ + b) * NCRIT;
            const float* Pr = pr + (size_t)(t * B_SZ + b) * NRESTP;
            dst.k[s]  = Pc[w*64 + lane];
            dst.q[s]  = Pc[512 + w*64 + lane];
            dst.p1[s] = *(const float4*)(Pc + 1024 + w*4);
            dst.p2[s] = *(const float4*)(Pc + 1056 + w*4);
            dst.v[s]  = Pr[w*64 + lane];
            dst.bt[s] = Pr[512 + w*64 + lane];
            dst.g[s]  = Pr[1024 + w*64 + lane];
            dst.p3[s] = *(const float4*)(Pr + 1536 + w*4);
            dst.tm[s] = (float)term[t * B_SZ + b];
        }
    };

    auto round_body = [&](const PF& cur, int lt0, int P) {
        float sc[4][4], nr[4], fvs[4][4];
        #pragma unroll
        for (int s = 0; s < 4; ++s) {
            const float mask = 1.f - cur.tm[s];
            const float4 cs = *(const float4*)&cos_s[lt0 + s][0];
            const float cosr[4] = {cs.x, cs.y, cs.z, cs.w};
            const float rk = fmaxf(cur.k[s], 0.f);
            const float rq = fmaxf(cur.q[s], 0.f);
            const float sg = sigmoidf_(cur.g[s]);
            const float p1v[4] = {cur.p1[s].x, cur.p1[s].y, cur.p1[s].z, cur.p1[s].w};
            const float p2v[4] = {cur.p2[s].x, cur.p2[s].y, cur.p2[s].z, cur.p2[s].w};
            const float p3v[4] = {cur.p3[s].x, cur.p3[s].y, cur.p3[s].z, cur.p3[s].w};
            float phi[4], kg[4], dgv[4];
            float np = 0.f;
            #pragma unroll
            for (int e = 0; e < 4; ++e) {
                const float psi = rk * fmaxf(p1v[e], 0.f);
                phi[e] = rq * fmaxf(p2v[e], 0.f);
                const float gf = sg * sigmoidf_(p3v[e]);
                kg[e] = psi * gf;
                dgv[e] = (1.f - gf) * mask;
                fsv[e] = dgv[e] * fsv[e] + kg[e];
                np += fsv[e] * phi[e];
            }
            nr[s] = np;
            #pragma unroll
            for (int r = 0; r < R_N; ++r) {
                float ss = 0.f;
                #pragma unroll
                for (int e = 0; e < 4; ++e) {
                    fk[r][e] = dgv[e] * fk[r][e] + kg[e] * cosr[r];
                    ss += fk[r][e] * phi[e];
                }
                sc[s][r] = ss;
            }
            const float bb = sigmoidf_(cur.bt[s]);
            const float vg = cur.v[s] * bb;
            const float db = (1.f - bb) * mask;
            #pragma unroll
            for (int r = 0; r < R_N; ++r) { fv[r] = db * fv[r] + vg * cosr[r]; fvs[s][r] = fv[r]; }
        }
        #pragma unroll
        for (int off = 32; off >= 1; off >>= 1) {
            #pragma unroll
            for (int s = 0; s < 4; ++s) {
                #pragma unroll
                for (int r = 0; r < 4; ++r) sc[s][r] += __shfl_xor(sc[s][r], off);
                nr[s] += __shfl_xor(nr[s], off);
            }
        }
        if (lane == 0) {
            #pragma unroll
            for (int s = 0; s < 4; ++s)
                *(float4*)&red[P][s][w][0] = make_float4(sc[s][0], sc[s][1], sc[s][2], sc[s][3]);
        }
        __syncthreads();
        #pragma unroll
        for (int s = 0; s < 4; ++s) {
            float s0 = 0.f, s1 = 0.f, s2 = 0.f, s3 = 0.f;
            #pragma unroll
            for (int ww = 0; ww < 8; ++ww) {
                const float4 rv = *(const float4*)&red[P][s][ww][0];
                s0 += rv.x; s1 += rv.y; s2 += rv.z; s3 += rv.w;
            }
            const float kv = fvs[s][0]*s0 + fvs[s][1]*s1 + fvs[s][2]*s2 + fvs[s][3]*s3;
            attn[((size_t)(tc0 + lt0 + s) * B_SZ + b) * (H_N * DH_N) + tid] =
                __float2bfloat16(kv / (2.0f * R_N * nr[s] + EPS_F));
        }
    };

    PF Abuf, Bbuf;
    prefetch(Abuf, 0);
    __syncthreads();

    for (int lt0 = 0; lt0 < CL; lt0 += 8) {
        prefetch(Bbuf, lt0 + 4);
        round_body(Abuf, lt0, 0);
        prefetch(Abuf, lt0 + 8);
        round_body(Bbuf, lt0 + 4, 1);
    }
}

extern "C" void kernel_launch(void* const* d_in, const int* in_sizes, int n_in,
                              void* d_out, int out_size, void* d_ws, size_t ws_size,
                              hipStream_t stream)
{
    const float* inputs  = (const float*)d_in[0];
    const int*   term    = (const int*)  d_in[1];
    const float* fk_prev = (const float*)d_in[2];
    const float* fv_prev = (const float*)d_in[3];
    const float* fs_prev = (const float*)d_in[4];
    const float* tick    = (const float*)d_in[5];
    const float* Wf      = (const float*)d_in[6];
    const float* bf      = (const float*)d_in[7];
    const float* Wp      = (const float*)d_in[8];
    const float* bp      = (const float*)d_in[9];

    float* out      = (float*)d_out;
    float* out_fk   = out    + (size_t)T_LEN * B_SZ * DMODEL;
    float* out_fv   = out_fk + (size_t)B_SZ * R_N * H_N * FD_N;
    float* out_fs   = out_fv + (size_t)B_SZ * R_N * H_N * DH_N;
    float* out_tick = out_fs + (size_t)B_SZ * H_N * FD_N;

    char* ws = (char*)d_ws;
    float* proj_crit = (float*)ws;                       // 17.8 MB
    ws += (size_t)T_LEN * B_SZ * NCRIT * 4;
    float* proj_rest = (float*)ws;                       // 27.3 MB
    ws += (size_t)T_LEN * B_SZ * NRESTP * 4;
    __hip_bfloat16* attn_bf = (__hip_bfloat16*)ws;       // 4.2 MB
    ws += (size_t)T_LEN * B_SZ * H_N * DH_N * 2;
    __hip_bfloat16* Wp_bf = (__hip_bfloat16*)ws;         // 1 MB
    ws += (size_t)DMODEL * H_N * DH_N * 2;
    _Float16* Wch = (_Float16*)ws;                       // 2.36 MB
    ws += (size_t)NSPLITP * DMODEL * 2;
    _Float16* Wcl = (_Float16*)ws;                       // 2.36 MB
    ws += (size_t)NSPLITP * DMODEL * 2;
    float* bias_rest = (float*)ws;                       // 6.7 KB
    ws += (size_t)NRESTP * 4;
    // union region: GEMM phase {Xh 8.4, Xl 8.4, Wrest_h 3.4} vs scan phase {SPk, SPv4, SPv1}
    char* uni = ws;
    _Float16* Xh      = (_Float16*)uni;
    _Float16* Xl      = (_Float16*)(uni + (size_t)T_LEN * B_SZ * DMODEL * 2);
    _Float16* Wrest_h = (_Float16*)(uni + (size_t)T_LEN * B_SZ * DMODEL * 4);
    float* SPk  = (float*)uni;
    float* SPv4 = (float*)(uni + (size_t)B_SZ * CH * 512 * 24 * 4);
    float* SPv1 = (float*)(uni + (size_t)B_SZ * CH * 512 * 28 * 4);

    // conversions
    cvt_split_x<<<2048, 256, 0, stream>>>(inputs, Xh, Xl, T_LEN * B_SZ * DMODEL);
    cvt_split_w<<<NSPLITP, 256, 0, stream>>>(Wf, Wch, Wcl);
    cvt_wrest_h<<<NRESTP, 256, 0, stream>>>(Wf, bf, Wrest_h, bias_rest);
    cvt_bf16<<<512, 256, 0, stream>>>(Wp, Wp_bf, DMODEL * H_N * DH_N);

    // 1a) crit cols 0..1055 (k,q,p1) via split-f16 MFMA, dbuf
    gemm_crit_dbuf<<<dim3(NSPLITP / 64, (T_LEN * B_SZ) / 64), dim3(256), 0, stream>>>(
        Xh, Xl, Wch, Wcl, bf, proj_crit);

    // 1b) p2 cols 1056..1087 in true f32
    gemm_p2_f32<<<dim3((T_LEN * B_SZ) / 8), dim3(256), 0, stream>>>(
        inputs, Wf, bf, proj_crit);

    // 1c) rest cols via f16-hi MFMA, dbuf
    gemm_nt_dbuf<1><<<dim3(NRESTP / 128, (T_LEN * B_SZ) / 64), dim3(256), 0, stream>>>(
        Xh, Wrest_h, bias_rest, proj_rest, NRESTP, DMODEL);

    // 2) parallel scan
    scan_passA<<<dim3(B_SZ, CH), dim3(512), 0, stream>>>(
        proj_crit, proj_rest, term, tick, SPk, SPv4, SPv1);
    scan_passB<<<dim3(B_SZ), dim3(512), 0, stream>>>(
        SPk, SPv4, SPv1, fk_prev, fv_prev, fs_prev, tick,
        out_fk, out_fv, out_fs, out_tick);
    scan_passC<<<dim3(B_SZ, CH), dim3(512), 0, stream>>>(
        proj_crit, proj_rest, term, tick, SPk, SPv4, attn_bf);

    // 3) out = attn @ Wp^T + bp (bf16 MFMA, dbuf)
    gemm_nt_dbuf<0><<<dim3(DMODEL / 128, (T_LEN * B_SZ) / 64), dim3(256), 0, stream>>>(
        attn_bf, Wp_bf, bp, out, DMODEL, H_N * DH_N);
}